// Round 13
// baseline (167.677 us; speedup 1.0000x reference)
//
#include <hip/hip_runtime.h>
#include <hip/hip_bf16.h>
#include <math.h>

// Problem constants
constexpr int Bn     = 16;    // batch
constexpr int Cc     = 384;   // channels
constexpr int Nn     = 1024;  // tokens (32*32)
constexpr int NHEADS = 8;
constexpr int HD     = 48;    // head dim
constexpr float SCALE = 0.14433756729740643f; // 48^-0.5
constexpr float SCL2  = 0.14433756729740643f * 1.4426950408889634f; // SCALE*log2(e)

using bf16x8 = __attribute__((ext_vector_type(8))) short;
using bf16x4 = __attribute__((ext_vector_type(4))) short;
using f32x4  = __attribute__((ext_vector_type(4))) float;

__device__ inline short f2b(float f) {
    __hip_bfloat16 h = __float2bfloat16(f);
    return *reinterpret_cast<short*>(&h);
}
__device__ inline float b2f(short s) {
    __hip_bfloat16 h = *reinterpret_cast<__hip_bfloat16*>(&s);
    return __bfloat162float(h);
}

// async global->LDS, 16B per lane; LDS dest = wave-uniform base + lane*16B
__device__ __forceinline__ void gload16(const short* g, short* l) {
    __builtin_amdgcn_global_load_lds(
        (const __attribute__((address_space(1))) void*)(g),
        (__attribute__((address_space(3))) void*)(l),
        16, 0, 0);
}

// ---------------------------------------------------------------------------
// Elementwise fp32 -> (hi, lo) bf16 split.
// ---------------------------------------------------------------------------
__global__ __launch_bounds__(256) void conv_split(const float* __restrict__ in,
                                                  short* __restrict__ hi,
                                                  short* __restrict__ lo, int n)
{
    int i = (blockIdx.x * 256 + threadIdx.x) * 4;
    if (i >= n) return;
    float4 v = *reinterpret_cast<const float4*>(&in[i]);
    float vs[4] = {v.x, v.y, v.z, v.w};
    bf16x4 h, l;
#pragma unroll
    for (int j = 0; j < 4; ++j) {
        h[j] = f2b(vs[j]);
        l[j] = f2b(vs[j] - b2f(h[j]));
    }
    *reinterpret_cast<bf16x4*>(&hi[i]) = h;
    *reinterpret_cast<bf16x4*>(&lo[i]) = l;
}

// ---------------------------------------------------------------------------
// x (B, C, N) fp32 -> x^T (B, N, C) bf16 hi/lo.  64x64 tile via LDS.
// ---------------------------------------------------------------------------
__global__ __launch_bounds__(256) void prep_xt(const float* __restrict__ x,
                                               short* __restrict__ xt_hi,
                                               short* __restrict__ xt_lo)
{
    const int b  = blockIdx.z;
    const int c0 = blockIdx.y * 64;
    const int n0 = blockIdx.x * 64;
    __shared__ float T[64 * 68];

    const int tid = threadIdx.x;
    const int r   = tid >> 2;
    const int seg = tid & 3;

    const float* xb = x + ((size_t)b * Cc + c0) * Nn;
#pragma unroll
    for (int i = 0; i < 4; ++i) {
        float4 v = *reinterpret_cast<const float4*>(&xb[(size_t)r * Nn + n0 + seg * 16 + i * 4]);
        *reinterpret_cast<float4*>(&T[r * 68 + seg * 16 + i * 4]) = v;
    }
    __syncthreads();

    short* oh = xt_hi + ((size_t)b * Nn + n0 + r) * Cc + c0;
    short* ol = xt_lo + ((size_t)b * Nn + n0 + r) * Cc + c0;
#pragma unroll
    for (int i = 0; i < 4; ++i) {
        bf16x4 hv, lv;
#pragma unroll
        for (int j = 0; j < 4; ++j) {
            float v = T[(seg * 16 + i * 4 + j) * 68 + r];
            hv[j] = f2b(v);
            lv[j] = f2b(v - b2f(hv[j]));
        }
        *reinterpret_cast<bf16x4*>(&oh[seg * 16 + i * 4]) = hv;
        *reinterpret_cast<bf16x4*>(&ol[seg * 16 + i * 4]) = lv;
    }
}

// ---------------------------------------------------------------------------
// Split-bf16 MFMA GEMM: Y[b][m][n] = sum_k W[m][k] * X[b][n][k]
// Staging via global_load_lds (16B/lane) into linear [128][32]-short tiles.
// Bank-conflict-free via source-side swizzle: LDS slot s at row r holds global
// k-chunk s ^ ((r>>1)&3); frag read at slot h4 ^ ((c>>1)&3)  -> 2 lanes/bank.
// MODE 0 (QKV): m<768 -> Yqk token-major (B,N,768) bf16 (Q rows pre-scaled by
//               SCL2); m>=768 -> Yv (B,384,N) bf16
// MODE 1 (PROJ): Yf fp32 (B,384,N) + bias
// ---------------------------------------------------------------------------
template <int MODE>
__global__ __launch_bounds__(256) void gemm_split(const short* __restrict__ Whi,
                                                  const short* __restrict__ Wlo,
                                                  const short* __restrict__ Xhi,
                                                  const short* __restrict__ Xlo,
                                                  short* __restrict__ Yqk,
                                                  short* __restrict__ Yv,
                                                  float* __restrict__ Yf,
                                                  const float* __restrict__ bias,
                                                  int M, int K, int NN)
{
    const int b  = blockIdx.z;
    const int m0 = blockIdx.y * 128;
    const int n0 = blockIdx.x * 128;
    const short* Xb_hi = Xhi + (size_t)b * NN * K;
    const short* Xb_lo = Xlo + (size_t)b * NN * K;

    // 4 linear staging tiles [128][32] shorts (4096 each) + epilogue overlay
    __shared__ __align__(16) short smem[17408];   // 34816 B
    short* As_hi = smem;
    short* As_lo = smem + 4096;
    short* Bs_hi = smem + 8192;
    short* Bs_lo = smem + 12288;

    const int tid  = threadIdx.x;
    const int lane = tid & 63;
    const int wave = tid >> 6;
    const int c    = lane & 15;
    const int h4   = lane >> 4;
    const int wr   = wave >> 1;
    const int wc   = wave & 1;

    // staging: thread tid handles chunk u=tid (rows 0..63 x 4 slots) and
    // u+256 (rows 64..127); source k-chunk swizzled.
    const int sr = tid >> 2;                               // 0..63
    const int sq = ((tid & 3) ^ ((tid >> 3) & 3)) * 8;     // swizzled k-chunk (shorts)
    const int lds0 = wave * 512;                            // shorts
    const int lds1 = 2048 + wave * 512;

    const short* gWhi = Whi + (size_t)(m0 + sr) * K + sq;
    const short* gWlo = Wlo + (size_t)(m0 + sr) * K + sq;
    const short* gXhi = Xb_hi + (size_t)(n0 + sr) * K + sq;
    const short* gXlo = Xb_lo + (size_t)(n0 + sr) * K + sq;
    const size_t rowskip = (size_t)64 * K;

    // frag-read swizzle (lane-constant)
    const int sw = (h4 ^ ((c >> 1) & 3)) * 8;              // shorts

    f32x4 acc[4][4];
#pragma unroll
    for (int mi = 0; mi < 4; ++mi)
#pragma unroll
        for (int ni = 0; ni < 4; ++ni) acc[mi][ni] = 0.0f;

    for (int k0 = 0; k0 < K; k0 += 32) {
        __syncthreads();   // prior reads done before overwrite
        gload16(gWhi + k0,           As_hi + lds0);
        gload16(gWhi + rowskip + k0, As_hi + lds1);
        gload16(gWlo + k0,           As_lo + lds0);
        gload16(gWlo + rowskip + k0, As_lo + lds1);
        gload16(gXhi + k0,           Bs_hi + lds0);
        gload16(gXhi + rowskip + k0, Bs_hi + lds1);
        gload16(gXlo + k0,           Bs_lo + lds0);
        gload16(gXlo + rowskip + k0, Bs_lo + lds1);
        __syncthreads();   // compiler drains vmcnt before barrier -> data ready

        bf16x8 a_hi[4], a_lo[4], b_hi[4], b_lo[4];
#pragma unroll
        for (int mi = 0; mi < 4; ++mi) {
            int row = wr * 64 + mi * 16 + c;
            a_hi[mi] = *reinterpret_cast<const bf16x8*>(&As_hi[row * 32 + sw]);
            a_lo[mi] = *reinterpret_cast<const bf16x8*>(&As_lo[row * 32 + sw]);
        }
#pragma unroll
        for (int ni = 0; ni < 4; ++ni) {
            int row = wc * 64 + ni * 16 + c;
            b_hi[ni] = *reinterpret_cast<const bf16x8*>(&Bs_hi[row * 32 + sw]);
            b_lo[ni] = *reinterpret_cast<const bf16x8*>(&Bs_lo[row * 32 + sw]);
        }
#pragma unroll
        for (int mi = 0; mi < 4; ++mi)
#pragma unroll
            for (int ni = 0; ni < 4; ++ni) {
                acc[mi][ni] = __builtin_amdgcn_mfma_f32_16x16x32_bf16(a_hi[mi], b_hi[ni], acc[mi][ni], 0, 0, 0);
                acc[mi][ni] = __builtin_amdgcn_mfma_f32_16x16x32_bf16(a_hi[mi], b_lo[ni], acc[mi][ni], 0, 0, 0);
                acc[mi][ni] = __builtin_amdgcn_mfma_f32_16x16x32_bf16(a_lo[mi], b_hi[ni], acc[mi][ni], 0, 0, 0);
            }
    }

    if (MODE == 0) {
        if (m0 < 768) {
            // Q/K: token-major bf16 out; Q rows pre-scaled by SCL2
            const float qscale = (m0 < 384) ? SCL2 : 1.0f;
            __syncthreads();
            short* Cs = smem;  // [128 n][136]
#pragma unroll
            for (int mi = 0; mi < 4; ++mi)
#pragma unroll
                for (int ni = 0; ni < 4; ++ni) {
                    int nl = wc * 64 + ni * 16 + c;
                    int cl = wr * 64 + mi * 16 + 4 * h4;
                    bf16x4 pk;
#pragma unroll
                    for (int r = 0; r < 4; ++r) pk[r] = f2b(acc[mi][ni][r] * qscale);
                    *reinterpret_cast<bf16x4*>(&Cs[nl * 136 + cl]) = pk;
                }
            __syncthreads();
            // full 128x128 tile: 2048 b128 units, 8 per thread
#pragma unroll
            for (int l = 0; l < 8; ++l) {
                int u  = tid + l * 256;        // 0..2047
                int nl = u >> 4, ch = u & 15;  // nl 0..127, ch 0..15
                *reinterpret_cast<bf16x8*>(&Yqk[((size_t)b * NN + n0 + nl) * 768 + m0 + ch * 8]) =
                    *reinterpret_cast<const bf16x8*>(&Cs[nl * 136 + ch * 8]);
            }
        } else {
            // V: channel-major bf16 out (d, n)
            __syncthreads();
            short* Cs = smem;  // [128 ch][136]
#pragma unroll
            for (int mi = 0; mi < 4; ++mi)
#pragma unroll
                for (int ni = 0; ni < 4; ++ni)
#pragma unroll
                    for (int r = 0; r < 4; ++r) {
                        int ml = wr * 64 + mi * 16 + h4 * 4 + r;
                        int nl = wc * 64 + ni * 16 + c;
                        Cs[ml * 136 + nl] = f2b(acc[mi][ni][r]);
                    }
            __syncthreads();
            short* Yb = Yv + (size_t)b * Cc * NN;
            const int srow2 = tid >> 1;
            const int cseg  = (tid & 1) * 64;
#pragma unroll
            for (int i = 0; i < 8; ++i)
                *reinterpret_cast<bf16x8*>(&Yb[(size_t)(m0 - 768 + srow2) * NN + n0 + cseg + i * 8]) =
                    *reinterpret_cast<const bf16x8*>(&Cs[srow2 * 136 + cseg + i * 8]);
        }
    } else {
        // PROJ: fp32 out + bias
        float* Yb = Yf + (size_t)b * M * NN;
        float* Cf = reinterpret_cast<float*>(smem);
        const int mr2 = tid >> 2;
        const int seg = tid & 3;
#pragma unroll
        for (int half = 0; half < 2; ++half) {
            __syncthreads();
            if (wr == half) {
#pragma unroll
                for (int mi = 0; mi < 4; ++mi)
#pragma unroll
                    for (int ni = 0; ni < 4; ++ni)
#pragma unroll
                        for (int r = 0; r < 4; ++r) {
                            int ml = mi * 16 + h4 * 4 + r;
                            int nl = wc * 64 + ni * 16 + c;
                            Cf[ml * 132 + nl] = acc[mi][ni][r];
                        }
            }
            __syncthreads();
            float bv = bias ? bias[m0 + half * 64 + mr2] : 0.0f;
#pragma unroll
            for (int i = 0; i < 8; ++i) {
                float4 v = *reinterpret_cast<const float4*>(&Cf[mr2 * 132 + seg * 32 + i * 4]);
                v.x += bv; v.y += bv; v.z += bv; v.w += bv;
                *reinterpret_cast<float4*>(&Yb[(size_t)(m0 + half * 64 + mr2) * NN + n0 + seg * 32 + i * 4]) = v;
            }
        }
    }
}

// ---------------------------------------------------------------------------
// Hybrid MFMA flash attention: LDS-staged K/V (shared by all 4 waves, staged
// once per block-tile) + register-only P via sigma-permuted PV (no P LDS
// round-trip), Q frags hoisted from global.  (unchanged from R12 — passing)
// ---------------------------------------------------------------------------
__global__ __launch_bounds__(256, 4) void attn_mfma(const short* __restrict__ qk_t,
                                                    const short* __restrict__ v_cn,
                                                    short* __restrict__ aot_hi,
                                                    short* __restrict__ aot_lo)
{
    const int b  = blockIdx.z;
    const int h  = blockIdx.y;
    const int n0 = blockIdx.x * 128;

    __shared__ __align__(16) short smem[(64 + 48) * 72];
    short* Ks = smem;            // [64][72]
    short* Vs = smem + 64 * 72;  // [48][72] sigma

    const int tid  = threadIdx.x;
    const int lane = tid & 63;
    const int wave = tid >> 6;
    const int c    = lane & 15;
    const int h4   = lane >> 4;
    const int qb   = n0 + wave * 32;

    const short* Qb = qk_t + ((size_t)b * Nn + qb) * 768 + h * HD;
    const short* Kbase = qk_t + (size_t)b * Nn * 768 + 384 + h * HD;
    const short* Vb = v_cn + ((size_t)b * Cc + h * HD) * Nn;

    const bf16x8 z8 = {};

    bf16x8 qf0[2], qf1[2];
#pragma unroll
    for (int s = 0; s < 2; ++s) {
        const short* qrow = Qb + (size_t)(s * 16 + c) * 768;
        qf0[s] = *reinterpret_cast<const bf16x8*>(qrow + 8 * h4);
        qf1[s] = (h4 < 2) ? *reinterpret_cast<const bf16x8*>(qrow + 32 + 8 * h4) : z8;
    }

    f32x4 o[2][3];
#pragma unroll
    for (int s = 0; s < 2; ++s)
#pragma unroll
        for (int jd = 0; jd < 3; ++jd) o[s][jd] = 0.0f;
    float lsum[2] = {0.0f, 0.0f};

    for (int t = 0; t < 16; ++t) {
        const int m0 = t * 64;
        __syncthreads();

#pragma unroll
        for (int l = 0; l < 2; ++l) {
            int u = tid + l * 256;
            int m = u >> 3, ch = u & 7;
            if (ch < 6)
                *reinterpret_cast<bf16x8*>(&Ks[m * 72 + ch * 8]) =
                    *reinterpret_cast<const bf16x8*>(&Kbase[(size_t)(m0 + m) * 768 + ch * 8]);
        }
#pragma unroll
        for (int l = 0; l < 2; ++l) {
            int u = tid + l * 256;
            if (u < 384) {
                int d = u >> 3, uu = u & 7;
                bf16x8 x = *reinterpret_cast<const bf16x8*>(&Vb[(size_t)d * Nn + m0 + uu * 8]);
                int s  = uu >> 2, v = uu & 3;
                int base = 32 * s + 16 * (v & 1);
                int off0 = (v < 2) ? base : base + 4;
                bf16x4 lo = {x[0], x[1], x[2], x[3]};
                bf16x4 hi = {x[4], x[5], x[6], x[7]};
                *reinterpret_cast<bf16x4*>(&Vs[d * 72 + off0])     = lo;
                *reinterpret_cast<bf16x4*>(&Vs[d * 72 + off0 + 8]) = hi;
            }
        }
        __syncthreads();

        f32x4 s4a[4], s4b[4];
#pragma unroll
        for (int j = 0; j < 4; ++j) { s4a[j] = 0.0f; s4b[j] = 0.0f; }
#pragma unroll
        for (int j = 0; j < 4; ++j) {
            bf16x8 kc0 = *reinterpret_cast<const bf16x8*>(&Ks[(16 * j + c) * 72 + h4 * 8]);
            bf16x8 kc1 = (h4 < 2) ? *reinterpret_cast<const bf16x8*>(&Ks[(16 * j + c) * 72 + 32 + h4 * 8]) : z8;
            s4a[j] = __builtin_amdgcn_mfma_f32_16x16x32_bf16(kc0, qf0[0], s4a[j], 0, 0, 0);
            s4a[j] = __builtin_amdgcn_mfma_f32_16x16x32_bf16(kc1, qf1[0], s4a[j], 0, 0, 0);
            s4b[j] = __builtin_amdgcn_mfma_f32_16x16x32_bf16(kc0, qf0[1], s4b[j], 0, 0, 0);
            s4b[j] = __builtin_amdgcn_mfma_f32_16x16x32_bf16(kc1, qf1[1], s4b[j], 0, 0, 0);
        }

        bf16x8 pa[2][2];
        {
            float p[4][4];
#pragma unroll
            for (int j = 0; j < 4; ++j)
#pragma unroll
                for (int r = 0; r < 4; ++r) {
                    p[j][r] = exp2f(s4a[j][r]);
                    lsum[0] += p[j][r];
                }
#pragma unroll
            for (int r = 0; r < 4; ++r) {
                pa[0][0][r]     = f2b(p[0][r]);
                pa[0][0][4 + r] = f2b(p[1][r]);
                pa[0][1][r]     = f2b(p[2][r]);
                pa[0][1][4 + r] = f2b(p[3][r]);
            }
        }
        {
            float p[4][4];
#pragma unroll
            for (int j = 0; j < 4; ++j)
#pragma unroll
                for (int r = 0; r < 4; ++r) {
                    p[j][r] = exp2f(s4b[j][r]);
                    lsum[1] += p[j][r];
                }
#pragma unroll
            for (int r = 0; r < 4; ++r) {
                pa[1][0][r]     = f2b(p[0][r]);
                pa[1][0][4 + r] = f2b(p[1][r]);
                pa[1][1][r]     = f2b(p[2][r]);
                pa[1][1][4 + r] = f2b(p[3][r]);
            }
        }

#pragma unroll
        for (int jd = 0; jd < 3; ++jd) {
            bf16x8 vf0 = *reinterpret_cast<const bf16x8*>(&Vs[(16 * jd + c) * 72 + h4 * 8]);
            bf16x8 vf1 = *reinterpret_cast<const bf16x8*>(&Vs[(16 * jd + c) * 72 + 32 + h4 * 8]);
            o[0][jd] = __builtin_amdgcn_mfma_f32_16x16x32_bf16(vf0, pa[0][0], o[0][jd], 0, 0, 0);
            o[0][jd] = __builtin_amdgcn_mfma_f32_16x16x32_bf16(vf1, pa[0][1], o[0][jd], 0, 0, 0);
            o[1][jd] = __builtin_amdgcn_mfma_f32_16x16x32_bf16(vf0, pa[1][0], o[1][jd], 0, 0, 0);
            o[1][jd] = __builtin_amdgcn_mfma_f32_16x16x32_bf16(vf1, pa[1][1], o[1][jd], 0, 0, 0);
        }
    }

#pragma unroll
    for (int set = 0; set < 2; ++set) {
        lsum[set] += __shfl_xor(lsum[set], 16);
        lsum[set] += __shfl_xor(lsum[set], 32);
        float linv = 1.0f / lsum[set];
        size_t rowoff = ((size_t)b * Nn + qb + set * 16 + c) * Cc + h * HD;
#pragma unroll
        for (int jd = 0; jd < 3; ++jd) {
            bf16x4 hv, lv;
#pragma unroll
            for (int r = 0; r < 4; ++r) {
                float val = o[set][jd][r] * linv;
                short x = f2b(val);
                hv[r] = x;
                lv[r] = f2b(val - b2f(x));
            }
            *reinterpret_cast<bf16x4*>(&aot_hi[rowoff + 16 * jd + 4 * h4]) = hv;
            *reinterpret_cast<bf16x4*>(&aot_lo[rowoff + 16 * jd + 4 * h4]) = lv;
        }
    }
}

// ---------------------------------------------------------------------------
extern "C" void kernel_launch(void* const* d_in, const int* in_sizes, int n_in,
                              void* d_out, int out_size, void* d_ws, size_t ws_size,
                              hipStream_t stream)
{
    const float* x      = (const float*)d_in[0];
    const float* w_qkv  = (const float*)d_in[1];
    const float* w_proj = (const float*)d_in[2];
    const float* b_proj = (const float*)d_in[3];
    float* out = (float*)d_out;

    short* ws = (short*)d_ws;
    const size_t XT = (size_t)Bn * Nn * Cc;            // 6291456
    short* xt_hi  = ws;
    short* xt_lo  = xt_hi + XT;
    short* wq_hi  = xt_lo + XT;
    short* wq_lo  = wq_hi + (size_t)3 * Cc * Cc;
    short* wp_hi  = wq_lo + (size_t)3 * Cc * Cc;
    short* wp_lo  = wp_hi + (size_t)Cc * Cc;
    short* qk_t   = wp_lo + (size_t)Cc * Cc;           // (B, N, 768)
    short* v_cn   = qk_t + (size_t)Bn * Nn * 768;      // (B, 384, N)
    short* aot_hi = v_cn + XT;
    short* aot_lo = aot_hi + XT;

    // 0) weight + x prep
    conv_split<<<(3 * Cc * Cc / 4 + 255) / 256, 256, 0, stream>>>(w_qkv, wq_hi, wq_lo, 3 * Cc * Cc);
    conv_split<<<(Cc * Cc / 4 + 255) / 256, 256, 0, stream>>>(w_proj, wp_hi, wp_lo, Cc * Cc);
    prep_xt<<<dim3(Nn / 64, Cc / 64, Bn), 256, 0, stream>>>(x, xt_hi, xt_lo);

    // 1) QKV GEMM -> qk_t (token-major Q,K; Q pre-scaled) + v_cn (channel-major V)
    gemm_split<0><<<dim3(Nn / 128, (3 * Cc) / 128, Bn), 256, 0, stream>>>(
        wq_hi, wq_lo, xt_hi, xt_lo, qk_t, v_cn, nullptr, nullptr, 3 * Cc, Cc, Nn);

    // 2) Hybrid LDS + sigma-register attention (128q blocks, 1024 blocks)
    attn_mfma<<<dim3(Nn / 128, NHEADS, Bn), 256, 0, stream>>>(qk_t, v_cn, aot_hi, aot_lo);

    // 3) Projection GEMM (fp32 out + bias)
    gemm_split<1><<<dim3(Nn / 128, Cc / 128, Bn), 256, 0, stream>>>(
        wp_hi, wp_lo, aot_hi, aot_lo, nullptr, nullptr, out, b_proj, Cc, Cc, Nn);
}

// Round 14
// 165.395 us; speedup vs baseline: 1.0138x; 1.0138x over previous
//
#include <hip/hip_runtime.h>
#include <hip/hip_bf16.h>
#include <math.h>

// Problem constants
constexpr int Bn     = 16;    // batch
constexpr int Cc     = 384;   // channels
constexpr int Nn     = 1024;  // tokens (32*32)
constexpr int NHEADS = 8;
constexpr int HD     = 48;    // head dim
constexpr float SCALE = 0.14433756729740643f; // 48^-0.5
constexpr float SCL2  = 0.14433756729740643f * 1.4426950408889634f; // SCALE*log2(e)

using bf16x8 = __attribute__((ext_vector_type(8))) short;
using bf16x4 = __attribute__((ext_vector_type(4))) short;
using f32x4  = __attribute__((ext_vector_type(4))) float;

__device__ inline short f2b(float f) {
    __hip_bfloat16 h = __float2bfloat16(f);
    return *reinterpret_cast<short*>(&h);
}
__device__ inline float b2f(short s) {
    __hip_bfloat16 h = *reinterpret_cast<__hip_bfloat16*>(&s);
    return __bfloat162float(h);
}

// async global->LDS, 16B per lane; LDS dest = wave-uniform base + lane*16B
__device__ __forceinline__ void gload16(const short* g, short* l) {
    __builtin_amdgcn_global_load_lds(
        (const __attribute__((address_space(1))) void*)(g),
        (__attribute__((address_space(3))) void*)(l),
        16, 0, 0);
}

// ---------------------------------------------------------------------------
// Elementwise fp32 -> (hi, lo) bf16 split.
// ---------------------------------------------------------------------------
__global__ __launch_bounds__(256) void conv_split(const float* __restrict__ in,
                                                  short* __restrict__ hi,
                                                  short* __restrict__ lo, int n)
{
    int i = (blockIdx.x * 256 + threadIdx.x) * 4;
    if (i >= n) return;
    float4 v = *reinterpret_cast<const float4*>(&in[i]);
    float vs[4] = {v.x, v.y, v.z, v.w};
    bf16x4 h, l;
#pragma unroll
    for (int j = 0; j < 4; ++j) {
        h[j] = f2b(vs[j]);
        l[j] = f2b(vs[j] - b2f(h[j]));
    }
    *reinterpret_cast<bf16x4*>(&hi[i]) = h;
    *reinterpret_cast<bf16x4*>(&lo[i]) = l;
}

// ---------------------------------------------------------------------------
// x (B, C, N) fp32 -> x^T (B, N, C) bf16 hi/lo.  64x64 tile via LDS.
// ---------------------------------------------------------------------------
__global__ __launch_bounds__(256) void prep_xt(const float* __restrict__ x,
                                               short* __restrict__ xt_hi,
                                               short* __restrict__ xt_lo)
{
    const int b  = blockIdx.z;
    const int c0 = blockIdx.y * 64;
    const int n0 = blockIdx.x * 64;
    __shared__ float T[64 * 68];

    const int tid = threadIdx.x;
    const int r   = tid >> 2;
    const int seg = tid & 3;

    const float* xb = x + ((size_t)b * Cc + c0) * Nn;
#pragma unroll
    for (int i = 0; i < 4; ++i) {
        float4 v = *reinterpret_cast<const float4*>(&xb[(size_t)r * Nn + n0 + seg * 16 + i * 4]);
        *reinterpret_cast<float4*>(&T[r * 68 + seg * 16 + i * 4]) = v;
    }
    __syncthreads();

    short* oh = xt_hi + ((size_t)b * Nn + n0 + r) * Cc + c0;
    short* ol = xt_lo + ((size_t)b * Nn + n0 + r) * Cc + c0;
#pragma unroll
    for (int i = 0; i < 4; ++i) {
        bf16x4 hv, lv;
#pragma unroll
        for (int j = 0; j < 4; ++j) {
            float v = T[(seg * 16 + i * 4 + j) * 68 + r];
            hv[j] = f2b(v);
            lv[j] = f2b(v - b2f(hv[j]));
        }
        *reinterpret_cast<bf16x4*>(&oh[seg * 16 + i * 4]) = hv;
        *reinterpret_cast<bf16x4*>(&ol[seg * 16 + i * 4]) = lv;
    }
}

// ---------------------------------------------------------------------------
// Split-bf16 MFMA GEMM (unchanged from R13 — validated).
// Staging via global_load_lds (16B/lane) into linear [128][32]-short tiles.
// MODE 0 (QKV): m<768 -> Yqk token-major (B,N,768) bf16 (Q pre-scaled by SCL2);
//               m>=768 -> Yv (B,384,N) bf16.  MODE 1 (PROJ): fp32 + bias.
// ---------------------------------------------------------------------------
template <int MODE>
__global__ __launch_bounds__(256) void gemm_split(const short* __restrict__ Whi,
                                                  const short* __restrict__ Wlo,
                                                  const short* __restrict__ Xhi,
                                                  const short* __restrict__ Xlo,
                                                  short* __restrict__ Yqk,
                                                  short* __restrict__ Yv,
                                                  float* __restrict__ Yf,
                                                  const float* __restrict__ bias,
                                                  int M, int K, int NN)
{
    const int b  = blockIdx.z;
    const int m0 = blockIdx.y * 128;
    const int n0 = blockIdx.x * 128;
    const short* Xb_hi = Xhi + (size_t)b * NN * K;
    const short* Xb_lo = Xlo + (size_t)b * NN * K;

    __shared__ __align__(16) short smem[17408];   // 34816 B
    short* As_hi = smem;
    short* As_lo = smem + 4096;
    short* Bs_hi = smem + 8192;
    short* Bs_lo = smem + 12288;

    const int tid  = threadIdx.x;
    const int lane = tid & 63;
    const int wave = tid >> 6;
    const int c    = lane & 15;
    const int h4   = lane >> 4;
    const int wr   = wave >> 1;
    const int wc   = wave & 1;

    const int sr = tid >> 2;
    const int sq = ((tid & 3) ^ ((tid >> 3) & 3)) * 8;
    const int lds0 = wave * 512;
    const int lds1 = 2048 + wave * 512;

    const short* gWhi = Whi + (size_t)(m0 + sr) * K + sq;
    const short* gWlo = Wlo + (size_t)(m0 + sr) * K + sq;
    const short* gXhi = Xb_hi + (size_t)(n0 + sr) * K + sq;
    const short* gXlo = Xb_lo + (size_t)(n0 + sr) * K + sq;
    const size_t rowskip = (size_t)64 * K;

    const int sw = (h4 ^ ((c >> 1) & 3)) * 8;

    f32x4 acc[4][4];
#pragma unroll
    for (int mi = 0; mi < 4; ++mi)
#pragma unroll
        for (int ni = 0; ni < 4; ++ni) acc[mi][ni] = 0.0f;

    for (int k0 = 0; k0 < K; k0 += 32) {
        __syncthreads();
        gload16(gWhi + k0,           As_hi + lds0);
        gload16(gWhi + rowskip + k0, As_hi + lds1);
        gload16(gWlo + k0,           As_lo + lds0);
        gload16(gWlo + rowskip + k0, As_lo + lds1);
        gload16(gXhi + k0,           Bs_hi + lds0);
        gload16(gXhi + rowskip + k0, Bs_hi + lds1);
        gload16(gXlo + k0,           Bs_lo + lds0);
        gload16(gXlo + rowskip + k0, Bs_lo + lds1);
        __syncthreads();

        bf16x8 a_hi[4], a_lo[4], b_hi[4], b_lo[4];
#pragma unroll
        for (int mi = 0; mi < 4; ++mi) {
            int row = wr * 64 + mi * 16 + c;
            a_hi[mi] = *reinterpret_cast<const bf16x8*>(&As_hi[row * 32 + sw]);
            a_lo[mi] = *reinterpret_cast<const bf16x8*>(&As_lo[row * 32 + sw]);
        }
#pragma unroll
        for (int ni = 0; ni < 4; ++ni) {
            int row = wc * 64 + ni * 16 + c;
            b_hi[ni] = *reinterpret_cast<const bf16x8*>(&Bs_hi[row * 32 + sw]);
            b_lo[ni] = *reinterpret_cast<const bf16x8*>(&Bs_lo[row * 32 + sw]);
        }
#pragma unroll
        for (int mi = 0; mi < 4; ++mi)
#pragma unroll
            for (int ni = 0; ni < 4; ++ni) {
                acc[mi][ni] = __builtin_amdgcn_mfma_f32_16x16x32_bf16(a_hi[mi], b_hi[ni], acc[mi][ni], 0, 0, 0);
                acc[mi][ni] = __builtin_amdgcn_mfma_f32_16x16x32_bf16(a_hi[mi], b_lo[ni], acc[mi][ni], 0, 0, 0);
                acc[mi][ni] = __builtin_amdgcn_mfma_f32_16x16x32_bf16(a_lo[mi], b_hi[ni], acc[mi][ni], 0, 0, 0);
            }
    }

    if (MODE == 0) {
        if (m0 < 768) {
            const float qscale = (m0 < 384) ? SCL2 : 1.0f;
            __syncthreads();
            short* Cs = smem;  // [128 n][136]
#pragma unroll
            for (int mi = 0; mi < 4; ++mi)
#pragma unroll
                for (int ni = 0; ni < 4; ++ni) {
                    int nl = wc * 64 + ni * 16 + c;
                    int cl = wr * 64 + mi * 16 + 4 * h4;
                    bf16x4 pk;
#pragma unroll
                    for (int r = 0; r < 4; ++r) pk[r] = f2b(acc[mi][ni][r] * qscale);
                    *reinterpret_cast<bf16x4*>(&Cs[nl * 136 + cl]) = pk;
                }
            __syncthreads();
#pragma unroll
            for (int l = 0; l < 8; ++l) {
                int u  = tid + l * 256;
                int nl = u >> 4, ch = u & 15;
                *reinterpret_cast<bf16x8*>(&Yqk[((size_t)b * NN + n0 + nl) * 768 + m0 + ch * 8]) =
                    *reinterpret_cast<const bf16x8*>(&Cs[nl * 136 + ch * 8]);
            }
        } else {
            __syncthreads();
            short* Cs = smem;  // [128 ch][136]
#pragma unroll
            for (int mi = 0; mi < 4; ++mi)
#pragma unroll
                for (int ni = 0; ni < 4; ++ni)
#pragma unroll
                    for (int r = 0; r < 4; ++r) {
                        int ml = wr * 64 + mi * 16 + h4 * 4 + r;
                        int nl = wc * 64 + ni * 16 + c;
                        Cs[ml * 136 + nl] = f2b(acc[mi][ni][r]);
                    }
            __syncthreads();
            short* Yb = Yv + (size_t)b * Cc * NN;
            const int srow2 = tid >> 1;
            const int cseg  = (tid & 1) * 64;
#pragma unroll
            for (int i = 0; i < 8; ++i)
                *reinterpret_cast<bf16x8*>(&Yb[(size_t)(m0 - 768 + srow2) * NN + n0 + cseg + i * 8]) =
                    *reinterpret_cast<const bf16x8*>(&Cs[srow2 * 136 + cseg + i * 8]);
        }
    } else {
        float* Yb = Yf + (size_t)b * M * NN;
        float* Cf = reinterpret_cast<float*>(smem);
        const int mr2 = tid >> 2;
        const int seg = tid & 3;
#pragma unroll
        for (int half = 0; half < 2; ++half) {
            __syncthreads();
            if (wr == half) {
#pragma unroll
                for (int mi = 0; mi < 4; ++mi)
#pragma unroll
                    for (int ni = 0; ni < 4; ++ni)
#pragma unroll
                        for (int r = 0; r < 4; ++r) {
                            int ml = mi * 16 + h4 * 4 + r;
                            int nl = wc * 64 + ni * 16 + c;
                            Cf[ml * 132 + nl] = acc[mi][ni][r];
                        }
            }
            __syncthreads();
            float bv = bias ? bias[m0 + half * 64 + mr2] : 0.0f;
#pragma unroll
            for (int i = 0; i < 8; ++i) {
                float4 v = *reinterpret_cast<const float4*>(&Cf[mr2 * 132 + seg * 32 + i * 4]);
                v.x += bv; v.y += bv; v.z += bv; v.w += bv;
                *reinterpret_cast<float4*>(&Yb[(size_t)(m0 + half * 64 + mr2) * NN + n0 + seg * 32 + i * 4]) = v;
            }
        }
    }
}

// ---------------------------------------------------------------------------
// Hybrid MFMA flash attention, global_load_lds staging.
// Block = (b, head, 128-q tile): 4 waves x 32 q (2 sets of 16). Grid 1024.
// LDS (linear, XOR-8 slot swizzle via per-lane SOURCE address):
//   Ks[64 m][64 d]  rows padded 48->64: slots 6,7 hold adjacent finite data,
//                   neutralized by qf1==0 for h4>=2 (k>=48 contributes 0).
//   Vs[48 d][64 m]  all slots real; sigma fragment = two contiguous b64 reads
//                   per k-half from the LINEAR layout (no repack).
// Store: LDS slot s' of row r holds global chunk s'^(r&7); read chunk g at
// slot g^(r&7), r&7 == c&7 for frag rows -> full-bank conflict-free.
//   QK^T: A=K(LDS), B=Q(regs) -> lane (c,h4): S[q=qb+set*16+c][m=16j+4h4+r]
//   PV  : A=V(LDS,sigma), B=P(regs,sigma) -> O[q=qb+set*16+c][d=16jd+4h4+r]
// ---------------------------------------------------------------------------
__global__ __launch_bounds__(256, 4) void attn_mfma(const short* __restrict__ qk_t,
                                                    const short* __restrict__ v_cn,
                                                    short* __restrict__ aot_hi,
                                                    short* __restrict__ aot_lo)
{
    const int b  = blockIdx.z;
    const int h  = blockIdx.y;
    const int n0 = blockIdx.x * 128;

    __shared__ __align__(16) short smem[4096 + 3072];  // Ks 8KB + Vs 6KB
    short* Ks = smem;
    short* Vs = smem + 4096;

    const int tid  = threadIdx.x;
    const int lane = tid & 63;
    const int wave = tid >> 6;
    const int c    = lane & 15;
    const int h4   = lane >> 4;
    const int qb   = n0 + wave * 32;

    const short* Qb    = qk_t + ((size_t)b * Nn + qb) * 768 + h * HD;
    const short* Kbase = qk_t + (size_t)b * Nn * 768 + 384 + h * HD;
    const short* Vb    = v_cn + ((size_t)b * Cc + h * HD) * Nn;

    const bf16x8 z8 = {};

    // ---- Q fragments (loop-invariant, 2 sets) ----
    bf16x8 qf0[2], qf1[2];
#pragma unroll
    for (int s = 0; s < 2; ++s) {
        const short* qrow = Qb + (size_t)(s * 16 + c) * 768;
        qf0[s] = *reinterpret_cast<const bf16x8*>(qrow + 8 * h4);
        qf1[s] = (h4 < 2) ? *reinterpret_cast<const bf16x8*>(qrow + 32 + 8 * h4) : z8;
    }

    // ---- staging source mapping (tile-invariant) ----
    const int u0 = wave * 64 + lane;           // chunk 0..255
    const int r0 = u0 >> 3;                    // row 0..31
    const int sc0 = ((u0 & 7) ^ (r0 & 7)) * 8; // swizzled source chunk (shorts)
    const int u1 = 256 + u0;                   // chunk 256..511
    const int r1 = u1 >> 3;                    // row 32..63
    const int sc1 = ((u1 & 7) ^ (r1 & 7)) * 8;

    // ---- frag-read slot constants (lane-constant) ----
    const int cs8 = c & 7;
    const int ks0 = (h4 ^ cs8) * 8;            // K k-chunk h4
    const int ks1 = ((4 + h4) ^ cs8) * 8;      // K k-chunk 4+h4
    const int hh  = h4 >> 1;
    const int hb  = (h4 & 1) * 4;
    const int vs00 = ((0 + hh) ^ cs8) * 8 + hb;   // V s0 t0
    const int vs01 = ((2 + hh) ^ cs8) * 8 + hb;   // V s0 t1
    const int vs10 = ((4 + hh) ^ cs8) * 8 + hb;   // V s1 t0
    const int vs11 = ((6 + hh) ^ cs8) * 8 + hb;   // V s1 t1

    f32x4 o[2][3];
#pragma unroll
    for (int s = 0; s < 2; ++s)
#pragma unroll
        for (int jd = 0; jd < 3; ++jd) o[s][jd] = 0.0f;
    float lsum[2] = {0.0f, 0.0f};

    for (int t = 0; t < 16; ++t) {
        const int m0 = t * 64;
        __syncthreads();   // prev iteration's LDS reads done

        // K: 512 chunks (rows padded to 64 shorts; slots 6,7 = harmless data)
        gload16(Kbase + (size_t)(m0 + r0) * 768 + sc0, Ks + wave * 512);
        gload16(Kbase + (size_t)(m0 + r1) * 768 + sc1, Ks + 2048 + wave * 512);
        // V: 384 chunks
        gload16(Vb + (size_t)r0 * Nn + m0 + sc0, Vs + wave * 512);
        if (wave < 2)
            gload16(Vb + (size_t)r1 * Nn + m0 + sc1, Vs + 2048 + wave * 512);
        __syncthreads();   // vmcnt drained by compiler before barrier

        // ---- QK^T: K frags shared by both sets ----
        f32x4 s4a[4], s4b[4];
#pragma unroll
        for (int j = 0; j < 4; ++j) { s4a[j] = 0.0f; s4b[j] = 0.0f; }
#pragma unroll
        for (int j = 0; j < 4; ++j) {
            int kr = (16 * j + c) * 64;
            bf16x8 kc0 = *reinterpret_cast<const bf16x8*>(&Ks[kr + ks0]);
            bf16x8 kc1 = *reinterpret_cast<const bf16x8*>(&Ks[kr + ks1]);
            s4a[j] = __builtin_amdgcn_mfma_f32_16x16x32_bf16(kc0, qf0[0], s4a[j], 0, 0, 0);
            s4a[j] = __builtin_amdgcn_mfma_f32_16x16x32_bf16(kc1, qf1[0], s4a[j], 0, 0, 0);
            s4b[j] = __builtin_amdgcn_mfma_f32_16x16x32_bf16(kc0, qf0[1], s4b[j], 0, 0, 0);
            s4b[j] = __builtin_amdgcn_mfma_f32_16x16x32_bf16(kc1, qf1[1], s4b[j], 0, 0, 0);
        }

        // ---- softmax-lite + pack P (sigma order), both sets ----
        bf16x8 pa[2][2];
        {
            float p[4][4];
#pragma unroll
            for (int j = 0; j < 4; ++j)
#pragma unroll
                for (int r = 0; r < 4; ++r) {
                    p[j][r] = exp2f(s4a[j][r]);
                    lsum[0] += p[j][r];
                }
#pragma unroll
            for (int r = 0; r < 4; ++r) {
                pa[0][0][r]     = f2b(p[0][r]);
                pa[0][0][4 + r] = f2b(p[1][r]);
                pa[0][1][r]     = f2b(p[2][r]);
                pa[0][1][4 + r] = f2b(p[3][r]);
            }
        }
        {
            float p[4][4];
#pragma unroll
            for (int j = 0; j < 4; ++j)
#pragma unroll
                for (int r = 0; r < 4; ++r) {
                    p[j][r] = exp2f(s4b[j][r]);
                    lsum[1] += p[j][r];
                }
#pragma unroll
            for (int r = 0; r < 4; ++r) {
                pa[1][0][r]     = f2b(p[0][r]);
                pa[1][0][4 + r] = f2b(p[1][r]);
                pa[1][1][r]     = f2b(p[2][r]);
                pa[1][1][4 + r] = f2b(p[3][r]);
            }
        }

        // ---- PV: sigma V frags = 4 contiguous b64 reads from linear Vs ----
#pragma unroll
        for (int jd = 0; jd < 3; ++jd) {
            int vr = (16 * jd + c) * 64;
            bf16x4 a0 = *reinterpret_cast<const bf16x4*>(&Vs[vr + vs00]);
            bf16x4 d0 = *reinterpret_cast<const bf16x4*>(&Vs[vr + vs01]);
            bf16x4 a1 = *reinterpret_cast<const bf16x4*>(&Vs[vr + vs10]);
            bf16x4 d1 = *reinterpret_cast<const bf16x4*>(&Vs[vr + vs11]);
            bf16x8 vf0, vf1;
#pragma unroll
            for (int r = 0; r < 4; ++r) {
                vf0[r] = a0[r]; vf0[4 + r] = d0[r];
                vf1[r] = a1[r]; vf1[4 + r] = d1[r];
            }
            o[0][jd] = __builtin_amdgcn_mfma_f32_16x16x32_bf16(vf0, pa[0][0], o[0][jd], 0, 0, 0);
            o[0][jd] = __builtin_amdgcn_mfma_f32_16x16x32_bf16(vf1, pa[0][1], o[0][jd], 0, 0, 0);
            o[1][jd] = __builtin_amdgcn_mfma_f32_16x16x32_bf16(vf0, pa[1][0], o[1][jd], 0, 0, 0);
            o[1][jd] = __builtin_amdgcn_mfma_f32_16x16x32_bf16(vf1, pa[1][1], o[1][jd], 0, 0, 0);
        }
    }

    // ---- epilogue: reduce lsum across h4 slices, normalize, split hi/lo ----
#pragma unroll
    for (int set = 0; set < 2; ++set) {
        lsum[set] += __shfl_xor(lsum[set], 16);
        lsum[set] += __shfl_xor(lsum[set], 32);
        float linv = 1.0f / lsum[set];
        size_t rowoff = ((size_t)b * Nn + qb + set * 16 + c) * Cc + h * HD;
#pragma unroll
        for (int jd = 0; jd < 3; ++jd) {
            bf16x4 hv, lv;
#pragma unroll
            for (int r = 0; r < 4; ++r) {
                float val = o[set][jd][r] * linv;
                short x = f2b(val);
                hv[r] = x;
                lv[r] = f2b(val - b2f(x));
            }
            *reinterpret_cast<bf16x4*>(&aot_hi[rowoff + 16 * jd + 4 * h4]) = hv;
            *reinterpret_cast<bf16x4*>(&aot_lo[rowoff + 16 * jd + 4 * h4]) = lv;
        }
    }
}

// ---------------------------------------------------------------------------
extern "C" void kernel_launch(void* const* d_in, const int* in_sizes, int n_in,
                              void* d_out, int out_size, void* d_ws, size_t ws_size,
                              hipStream_t stream)
{
    const float* x      = (const float*)d_in[0];
    const float* w_qkv  = (const float*)d_in[1];
    const float* w_proj = (const float*)d_in[2];
    const float* b_proj = (const float*)d_in[3];
    float* out = (float*)d_out;

    short* ws = (short*)d_ws;
    const size_t XT = (size_t)Bn * Nn * Cc;            // 6291456
    short* xt_hi  = ws;
    short* xt_lo  = xt_hi + XT;
    short* wq_hi  = xt_lo + XT;
    short* wq_lo  = wq_hi + (size_t)3 * Cc * Cc;
    short* wp_hi  = wq_lo + (size_t)3 * Cc * Cc;
    short* wp_lo  = wp_hi + (size_t)Cc * Cc;
    short* qk_t   = wp_lo + (size_t)Cc * Cc;           // (B, N, 768)
    short* v_cn   = qk_t + (size_t)Bn * Nn * 768;      // (B, 384, N)
    short* aot_hi = v_cn + XT;
    short* aot_lo = aot_hi + XT;

    // 0) weight + x prep
    conv_split<<<(3 * Cc * Cc / 4 + 255) / 256, 256, 0, stream>>>(w_qkv, wq_hi, wq_lo, 3 * Cc * Cc);
    conv_split<<<(Cc * Cc / 4 + 255) / 256, 256, 0, stream>>>(w_proj, wp_hi, wp_lo, Cc * Cc);
    prep_xt<<<dim3(Nn / 64, Cc / 64, Bn), 256, 0, stream>>>(x, xt_hi, xt_lo);

    // 1) QKV GEMM -> qk_t (token-major Q,K; Q pre-scaled) + v_cn (channel-major V)
    gemm_split<0><<<dim3(Nn / 128, (3 * Cc) / 128, Bn), 256, 0, stream>>>(
        wq_hi, wq_lo, xt_hi, xt_lo, qk_t, v_cn, nullptr, nullptr, 3 * Cc, Cc, Nn);

    // 2) Hybrid attention, global_load_lds staging (128q blocks, 1024 blocks)
    attn_mfma<<<dim3(Nn / 128, NHEADS, Bn), 256, 0, stream>>>(qk_t, v_cn, aot_hi, aot_lo);

    // 3) Projection GEMM (fp32 out + bias)
    gemm_split<1><<<dim3(Nn / 128, Cc / 128, Bn), 256, 0, stream>>>(
        wp_hi, wp_lo, aot_hi, aot_lo, nullptr, nullptr, out, b_proj, Cc, Cc, Nn);
}

// Round 15
// 162.439 us; speedup vs baseline: 1.0322x; 1.0182x over previous
//
#include <hip/hip_runtime.h>
#include <hip/hip_bf16.h>
#include <math.h>

// Problem constants
constexpr int Bn     = 16;    // batch
constexpr int Cc     = 384;   // channels
constexpr int Nn     = 1024;  // tokens (32*32)
constexpr int NHEADS = 8;
constexpr int HD     = 48;    // head dim
constexpr float SCALE = 0.14433756729740643f; // 48^-0.5
constexpr float SCL2  = 0.14433756729740643f * 1.4426950408889634f; // SCALE*log2(e)

using bf16x8 = __attribute__((ext_vector_type(8))) short;
using bf16x4 = __attribute__((ext_vector_type(4))) short;
using f32x4  = __attribute__((ext_vector_type(4))) float;

__device__ inline short f2b(float f) {
    __hip_bfloat16 h = __float2bfloat16(f);
    return *reinterpret_cast<short*>(&h);
}
__device__ inline float b2f(short s) {
    __hip_bfloat16 h = *reinterpret_cast<__hip_bfloat16*>(&s);
    return __bfloat162float(h);
}

// async global->LDS, 16B per lane; LDS dest = wave-uniform base + lane*16B
__device__ __forceinline__ void gload16(const short* g, short* l) {
    __builtin_amdgcn_global_load_lds(
        (const __attribute__((address_space(1))) void*)(g),
        (__attribute__((address_space(3))) void*)(l),
        16, 0, 0);
}

// ---------------------------------------------------------------------------
// Elementwise fp32 -> (hi, lo) bf16 split.
// ---------------------------------------------------------------------------
__global__ __launch_bounds__(256) void conv_split(const float* __restrict__ in,
                                                  short* __restrict__ hi,
                                                  short* __restrict__ lo, int n)
{
    int i = (blockIdx.x * 256 + threadIdx.x) * 4;
    if (i >= n) return;
    float4 v = *reinterpret_cast<const float4*>(&in[i]);
    float vs[4] = {v.x, v.y, v.z, v.w};
    bf16x4 h, l;
#pragma unroll
    for (int j = 0; j < 4; ++j) {
        h[j] = f2b(vs[j]);
        l[j] = f2b(vs[j] - b2f(h[j]));
    }
    *reinterpret_cast<bf16x4*>(&hi[i]) = h;
    *reinterpret_cast<bf16x4*>(&lo[i]) = l;
}

// ---------------------------------------------------------------------------
// x (B, C, N) fp32 -> x^T (B, N, C) bf16 hi/lo.  64x64 tile via LDS.
// ---------------------------------------------------------------------------
__global__ __launch_bounds__(256) void prep_xt(const float* __restrict__ x,
                                               short* __restrict__ xt_hi,
                                               short* __restrict__ xt_lo)
{
    const int b  = blockIdx.z;
    const int c0 = blockIdx.y * 64;
    const int n0 = blockIdx.x * 64;
    __shared__ float T[64 * 68];

    const int tid = threadIdx.x;
    const int r   = tid >> 2;
    const int seg = tid & 3;

    const float* xb = x + ((size_t)b * Cc + c0) * Nn;
#pragma unroll
    for (int i = 0; i < 4; ++i) {
        float4 v = *reinterpret_cast<const float4*>(&xb[(size_t)r * Nn + n0 + seg * 16 + i * 4]);
        *reinterpret_cast<float4*>(&T[r * 68 + seg * 16 + i * 4]) = v;
    }
    __syncthreads();

    short* oh = xt_hi + ((size_t)b * Nn + n0 + r) * Cc + c0;
    short* ol = xt_lo + ((size_t)b * Nn + n0 + r) * Cc + c0;
#pragma unroll
    for (int i = 0; i < 4; ++i) {
        bf16x4 hv, lv;
#pragma unroll
        for (int j = 0; j < 4; ++j) {
            float v = T[(seg * 16 + i * 4 + j) * 68 + r];
            hv[j] = f2b(v);
            lv[j] = f2b(v - b2f(hv[j]));
        }
        *reinterpret_cast<bf16x4*>(&oh[seg * 16 + i * 4]) = hv;
        *reinterpret_cast<bf16x4*>(&ol[seg * 16 + i * 4]) = lv;
    }
}

// ---------------------------------------------------------------------------
// Split-bf16 MFMA GEMM, 2-phase LDS double-buffer (T3 minimum recipe):
// stage tile t+1 into buf^1 BEFORE computing tile t; one vmcnt(0)+barrier per
// iteration (via __syncthreads) lands after the MFMA phase -> load latency
// hides under compute.  64 KB LDS (2 x 4 tiles x 8 KB), 2 blocks/CU.
// Staging via global_load_lds (16B/lane), source-side XOR swizzle (R13).
// MODE 0 (QKV): m<768 -> Yqk token-major (B,N,768) bf16 (Q pre-scaled by SCL2);
//               m>=768 -> Yv (B,384,N) bf16.  MODE 1 (PROJ): fp32 + bias.
// ---------------------------------------------------------------------------
template <int MODE>
__global__ __launch_bounds__(256) void gemm_split(const short* __restrict__ Whi,
                                                  const short* __restrict__ Wlo,
                                                  const short* __restrict__ Xhi,
                                                  const short* __restrict__ Xlo,
                                                  short* __restrict__ Yqk,
                                                  short* __restrict__ Yv,
                                                  float* __restrict__ Yf,
                                                  const float* __restrict__ bias,
                                                  int M, int K, int NN)
{
    const int b  = blockIdx.z;
    const int m0 = blockIdx.y * 128;
    const int n0 = blockIdx.x * 128;
    const short* Xb_hi = Xhi + (size_t)b * NN * K;
    const short* Xb_lo = Xlo + (size_t)b * NN * K;

    // 2 buffers x 4 tiles x [128][32] shorts; epilogue overlays buffer 0
    __shared__ __align__(16) short smem[32768];   // 65536 B

    const int tid  = threadIdx.x;
    const int lane = tid & 63;
    const int wave = tid >> 6;
    const int c    = lane & 15;
    const int h4   = lane >> 4;
    const int wr   = wave >> 1;
    const int wc   = wave & 1;

    const int sq   = ((tid & 3) ^ ((tid >> 3) & 3)) * 8;  // swizzled src chunk
    const int lds0 = wave * 512;                          // shorts, per tile
    const int lds1 = 2048 + wave * 512;

    const short* gWhi = Whi + (size_t)(m0 + (tid >> 2)) * K + sq;
    const short* gWlo = Wlo + (size_t)(m0 + (tid >> 2)) * K + sq;
    const short* gXhi = Xb_hi + (size_t)(n0 + (tid >> 2)) * K + sq;
    const short* gXlo = Xb_lo + (size_t)(n0 + (tid >> 2)) * K + sq;
    const size_t rowskip = (size_t)64 * K;

    const int sw = (h4 ^ ((c >> 1) & 3)) * 8;             // frag-read swizzle

    f32x4 acc[4][4];
#pragma unroll
    for (int mi = 0; mi < 4; ++mi)
#pragma unroll
        for (int ni = 0; ni < 4; ++ni) acc[mi][ni] = 0.0f;

    // ---- prologue: stage tile 0 into buffer 0 ----
    gload16(gWhi,           smem + 0     + lds0);
    gload16(gWhi + rowskip, smem + 0     + lds1);
    gload16(gWlo,           smem + 4096  + lds0);
    gload16(gWlo + rowskip, smem + 4096  + lds1);
    gload16(gXhi,           smem + 8192  + lds0);
    gload16(gXhi + rowskip, smem + 8192  + lds1);
    gload16(gXlo,           smem + 12288 + lds0);
    gload16(gXlo + rowskip, smem + 12288 + lds1);
    __syncthreads();

    const int NT = K >> 5;   // 12
    for (int t = 0; t < NT; ++t) {
        short* cbuf = smem + (t & 1) * 16384;

        // issue next-tile loads into the other buffer FIRST (prefetch)
        if (t + 1 < NT) {
            short* nbuf = smem + ((t + 1) & 1) * 16384;
            const int nk = (t + 1) * 32;
            gload16(gWhi + nk,           nbuf + 0     + lds0);
            gload16(gWhi + rowskip + nk, nbuf + 0     + lds1);
            gload16(gWlo + nk,           nbuf + 4096  + lds0);
            gload16(gWlo + rowskip + nk, nbuf + 4096  + lds1);
            gload16(gXhi + nk,           nbuf + 8192  + lds0);
            gload16(gXhi + rowskip + nk, nbuf + 8192  + lds1);
            gload16(gXlo + nk,           nbuf + 12288 + lds0);
            gload16(gXlo + rowskip + nk, nbuf + 12288 + lds1);
        }

        // compute current buffer
        bf16x8 a_hi[4], a_lo[4], b_hi[4], b_lo[4];
#pragma unroll
        for (int mi = 0; mi < 4; ++mi) {
            int row = wr * 64 + mi * 16 + c;
            a_hi[mi] = *reinterpret_cast<const bf16x8*>(&cbuf[row * 32 + sw]);
            a_lo[mi] = *reinterpret_cast<const bf16x8*>(&cbuf[4096 + row * 32 + sw]);
        }
#pragma unroll
        for (int ni = 0; ni < 4; ++ni) {
            int row = wc * 64 + ni * 16 + c;
            b_hi[ni] = *reinterpret_cast<const bf16x8*>(&cbuf[8192 + row * 32 + sw]);
            b_lo[ni] = *reinterpret_cast<const bf16x8*>(&cbuf[12288 + row * 32 + sw]);
        }
#pragma unroll
        for (int mi = 0; mi < 4; ++mi)
#pragma unroll
            for (int ni = 0; ni < 4; ++ni) {
                acc[mi][ni] = __builtin_amdgcn_mfma_f32_16x16x32_bf16(a_hi[mi], b_hi[ni], acc[mi][ni], 0, 0, 0);
                acc[mi][ni] = __builtin_amdgcn_mfma_f32_16x16x32_bf16(a_hi[mi], b_lo[ni], acc[mi][ni], 0, 0, 0);
                acc[mi][ni] = __builtin_amdgcn_mfma_f32_16x16x32_bf16(a_lo[mi], b_hi[ni], acc[mi][ni], 0, 0, 0);
            }

        __syncthreads();   // drains prefetch loads + protects buffer reuse
    }

    if (MODE == 0) {
        if (m0 < 768) {
            const float qscale = (m0 < 384) ? SCL2 : 1.0f;
            short* Cs = smem;  // [128 n][136]
#pragma unroll
            for (int mi = 0; mi < 4; ++mi)
#pragma unroll
                for (int ni = 0; ni < 4; ++ni) {
                    int nl = wc * 64 + ni * 16 + c;
                    int cl = wr * 64 + mi * 16 + 4 * h4;
                    bf16x4 pk;
#pragma unroll
                    for (int r = 0; r < 4; ++r) pk[r] = f2b(acc[mi][ni][r] * qscale);
                    *reinterpret_cast<bf16x4*>(&Cs[nl * 136 + cl]) = pk;
                }
            __syncthreads();
#pragma unroll
            for (int l = 0; l < 8; ++l) {
                int u  = tid + l * 256;
                int nl = u >> 4, ch = u & 15;
                *reinterpret_cast<bf16x8*>(&Yqk[((size_t)b * NN + n0 + nl) * 768 + m0 + ch * 8]) =
                    *reinterpret_cast<const bf16x8*>(&Cs[nl * 136 + ch * 8]);
            }
        } else {
            short* Cs = smem;  // [128 ch][136]
#pragma unroll
            for (int mi = 0; mi < 4; ++mi)
#pragma unroll
                for (int ni = 0; ni < 4; ++ni)
#pragma unroll
                    for (int r = 0; r < 4; ++r) {
                        int ml = wr * 64 + mi * 16 + h4 * 4 + r;
                        int nl = wc * 64 + ni * 16 + c;
                        Cs[ml * 136 + nl] = f2b(acc[mi][ni][r]);
                    }
            __syncthreads();
            short* Yb = Yv + (size_t)b * Cc * NN;
            const int srow2 = tid >> 1;
            const int cseg  = (tid & 1) * 64;
#pragma unroll
            for (int i = 0; i < 8; ++i)
                *reinterpret_cast<bf16x8*>(&Yb[(size_t)(m0 - 768 + srow2) * NN + n0 + cseg + i * 8]) =
                    *reinterpret_cast<const bf16x8*>(&Cs[srow2 * 136 + cseg + i * 8]);
        }
    } else {
        float* Yb = Yf + (size_t)b * M * NN;
        float* Cf = reinterpret_cast<float*>(smem);
        const int mr2 = tid >> 2;
        const int seg = tid & 3;
#pragma unroll
        for (int half = 0; half < 2; ++half) {
            __syncthreads();
            if (wr == half) {
#pragma unroll
                for (int mi = 0; mi < 4; ++mi)
#pragma unroll
                    for (int ni = 0; ni < 4; ++ni)
#pragma unroll
                        for (int r = 0; r < 4; ++r) {
                            int ml = mi * 16 + h4 * 4 + r;
                            int nl = wc * 64 + ni * 16 + c;
                            Cf[ml * 132 + nl] = acc[mi][ni][r];
                        }
            }
            __syncthreads();
            float bv = bias ? bias[m0 + half * 64 + mr2] : 0.0f;
#pragma unroll
            for (int i = 0; i < 8; ++i) {
                float4 v = *reinterpret_cast<const float4*>(&Cf[mr2 * 132 + seg * 32 + i * 4]);
                v.x += bv; v.y += bv; v.z += bv; v.w += bv;
                *reinterpret_cast<float4*>(&Yb[(size_t)(m0 + half * 64 + mr2) * NN + n0 + seg * 32 + i * 4]) = v;
            }
        }
    }
}

// ---------------------------------------------------------------------------
// Hybrid MFMA flash attention, global_load_lds staging (unchanged from R14).
// ---------------------------------------------------------------------------
__global__ __launch_bounds__(256, 4) void attn_mfma(const short* __restrict__ qk_t,
                                                    const short* __restrict__ v_cn,
                                                    short* __restrict__ aot_hi,
                                                    short* __restrict__ aot_lo)
{
    const int b  = blockIdx.z;
    const int h  = blockIdx.y;
    const int n0 = blockIdx.x * 128;

    __shared__ __align__(16) short smem[4096 + 3072];  // Ks 8KB + Vs 6KB
    short* Ks = smem;
    short* Vs = smem + 4096;

    const int tid  = threadIdx.x;
    const int lane = tid & 63;
    const int wave = tid >> 6;
    const int c    = lane & 15;
    const int h4   = lane >> 4;
    const int qb   = n0 + wave * 32;

    const short* Qb    = qk_t + ((size_t)b * Nn + qb) * 768 + h * HD;
    const short* Kbase = qk_t + (size_t)b * Nn * 768 + 384 + h * HD;
    const short* Vb    = v_cn + ((size_t)b * Cc + h * HD) * Nn;

    const bf16x8 z8 = {};

    bf16x8 qf0[2], qf1[2];
#pragma unroll
    for (int s = 0; s < 2; ++s) {
        const short* qrow = Qb + (size_t)(s * 16 + c) * 768;
        qf0[s] = *reinterpret_cast<const bf16x8*>(qrow + 8 * h4);
        qf1[s] = (h4 < 2) ? *reinterpret_cast<const bf16x8*>(qrow + 32 + 8 * h4) : z8;
    }

    const int u0 = wave * 64 + lane;
    const int r0 = u0 >> 3;
    const int sc0 = ((u0 & 7) ^ (r0 & 7)) * 8;
    const int u1 = 256 + u0;
    const int r1 = u1 >> 3;
    const int sc1 = ((u1 & 7) ^ (r1 & 7)) * 8;

    const int cs8 = c & 7;
    const int ks0 = (h4 ^ cs8) * 8;
    const int ks1 = ((4 + h4) ^ cs8) * 8;
    const int hh  = h4 >> 1;
    const int hb  = (h4 & 1) * 4;
    const int vs00 = ((0 + hh) ^ cs8) * 8 + hb;
    const int vs01 = ((2 + hh) ^ cs8) * 8 + hb;
    const int vs10 = ((4 + hh) ^ cs8) * 8 + hb;
    const int vs11 = ((6 + hh) ^ cs8) * 8 + hb;

    f32x4 o[2][3];
#pragma unroll
    for (int s = 0; s < 2; ++s)
#pragma unroll
        for (int jd = 0; jd < 3; ++jd) o[s][jd] = 0.0f;
    float lsum[2] = {0.0f, 0.0f};

    for (int t = 0; t < 16; ++t) {
        const int m0 = t * 64;
        __syncthreads();

        gload16(Kbase + (size_t)(m0 + r0) * 768 + sc0, Ks + wave * 512);
        gload16(Kbase + (size_t)(m0 + r1) * 768 + sc1, Ks + 2048 + wave * 512);
        gload16(Vb + (size_t)r0 * Nn + m0 + sc0, Vs + wave * 512);
        if (wave < 2)
            gload16(Vb + (size_t)r1 * Nn + m0 + sc1, Vs + 2048 + wave * 512);
        __syncthreads();

        f32x4 s4a[4], s4b[4];
#pragma unroll
        for (int j = 0; j < 4; ++j) { s4a[j] = 0.0f; s4b[j] = 0.0f; }
#pragma unroll
        for (int j = 0; j < 4; ++j) {
            int kr = (16 * j + c) * 64;
            bf16x8 kc0 = *reinterpret_cast<const bf16x8*>(&Ks[kr + ks0]);
            bf16x8 kc1 = *reinterpret_cast<const bf16x8*>(&Ks[kr + ks1]);
            s4a[j] = __builtin_amdgcn_mfma_f32_16x16x32_bf16(kc0, qf0[0], s4a[j], 0, 0, 0);
            s4a[j] = __builtin_amdgcn_mfma_f32_16x16x32_bf16(kc1, qf1[0], s4a[j], 0, 0, 0);
            s4b[j] = __builtin_amdgcn_mfma_f32_16x16x32_bf16(kc0, qf0[1], s4b[j], 0, 0, 0);
            s4b[j] = __builtin_amdgcn_mfma_f32_16x16x32_bf16(kc1, qf1[1], s4b[j], 0, 0, 0);
        }

        bf16x8 pa[2][2];
        {
            float p[4][4];
#pragma unroll
            for (int j = 0; j < 4; ++j)
#pragma unroll
                for (int r = 0; r < 4; ++r) {
                    p[j][r] = exp2f(s4a[j][r]);
                    lsum[0] += p[j][r];
                }
#pragma unroll
            for (int r = 0; r < 4; ++r) {
                pa[0][0][r]     = f2b(p[0][r]);
                pa[0][0][4 + r] = f2b(p[1][r]);
                pa[0][1][r]     = f2b(p[2][r]);
                pa[0][1][4 + r] = f2b(p[3][r]);
            }
        }
        {
            float p[4][4];
#pragma unroll
            for (int j = 0; j < 4; ++j)
#pragma unroll
                for (int r = 0; r < 4; ++r) {
                    p[j][r] = exp2f(s4b[j][r]);
                    lsum[1] += p[j][r];
                }
#pragma unroll
            for (int r = 0; r < 4; ++r) {
                pa[1][0][r]     = f2b(p[0][r]);
                pa[1][0][4 + r] = f2b(p[1][r]);
                pa[1][1][r]     = f2b(p[2][r]);
                pa[1][1][4 + r] = f2b(p[3][r]);
            }
        }

#pragma unroll
        for (int jd = 0; jd < 3; ++jd) {
            int vr = (16 * jd + c) * 64;
            bf16x4 a0 = *reinterpret_cast<const bf16x4*>(&Vs[vr + vs00]);
            bf16x4 d0 = *reinterpret_cast<const bf16x4*>(&Vs[vr + vs01]);
            bf16x4 a1 = *reinterpret_cast<const bf16x4*>(&Vs[vr + vs10]);
            bf16x4 d1 = *reinterpret_cast<const bf16x4*>(&Vs[vr + vs11]);
            bf16x8 vf0, vf1;
#pragma unroll
            for (int r = 0; r < 4; ++r) {
                vf0[r] = a0[r]; vf0[4 + r] = d0[r];
                vf1[r] = a1[r]; vf1[4 + r] = d1[r];
            }
            o[0][jd] = __builtin_amdgcn_mfma_f32_16x16x32_bf16(vf0, pa[0][0], o[0][jd], 0, 0, 0);
            o[0][jd] = __builtin_amdgcn_mfma_f32_16x16x32_bf16(vf1, pa[0][1], o[0][jd], 0, 0, 0);
            o[1][jd] = __builtin_amdgcn_mfma_f32_16x16x32_bf16(vf0, pa[1][0], o[1][jd], 0, 0, 0);
            o[1][jd] = __builtin_amdgcn_mfma_f32_16x16x32_bf16(vf1, pa[1][1], o[1][jd], 0, 0, 0);
        }
    }

#pragma unroll
    for (int set = 0; set < 2; ++set) {
        lsum[set] += __shfl_xor(lsum[set], 16);
        lsum[set] += __shfl_xor(lsum[set], 32);
        float linv = 1.0f / lsum[set];
        size_t rowoff = ((size_t)b * Nn + qb + set * 16 + c) * Cc + h * HD;
#pragma unroll
        for (int jd = 0; jd < 3; ++jd) {
            bf16x4 hv, lv;
#pragma unroll
            for (int r = 0; r < 4; ++r) {
                float val = o[set][jd][r] * linv;
                short x = f2b(val);
                hv[r] = x;
                lv[r] = f2b(val - b2f(x));
            }
            *reinterpret_cast<bf16x4*>(&aot_hi[rowoff + 16 * jd + 4 * h4]) = hv;
            *reinterpret_cast<bf16x4*>(&aot_lo[rowoff + 16 * jd + 4 * h4]) = lv;
        }
    }
}

// ---------------------------------------------------------------------------
extern "C" void kernel_launch(void* const* d_in, const int* in_sizes, int n_in,
                              void* d_out, int out_size, void* d_ws, size_t ws_size,
                              hipStream_t stream)
{
    const float* x      = (const float*)d_in[0];
    const float* w_qkv  = (const float*)d_in[1];
    const float* w_proj = (const float*)d_in[2];
    const float* b_proj = (const float*)d_in[3];
    float* out = (float*)d_out;

    short* ws = (short*)d_ws;
    const size_t XT = (size_t)Bn * Nn * Cc;            // 6291456
    short* xt_hi  = ws;
    short* xt_lo  = xt_hi + XT;
    short* wq_hi  = xt_lo + XT;
    short* wq_lo  = wq_hi + (size_t)3 * Cc * Cc;
    short* wp_hi  = wq_lo + (size_t)3 * Cc * Cc;
    short* wp_lo  = wp_hi + (size_t)Cc * Cc;
    short* qk_t   = wp_lo + (size_t)Cc * Cc;           // (B, N, 768)
    short* v_cn   = qk_t + (size_t)Bn * Nn * 768;      // (B, 384, N)
    short* aot_hi = v_cn + XT;
    short* aot_lo = aot_hi + XT;

    // 0) weight + x prep
    conv_split<<<(3 * Cc * Cc / 4 + 255) / 256, 256, 0, stream>>>(w_qkv, wq_hi, wq_lo, 3 * Cc * Cc);
    conv_split<<<(Cc * Cc / 4 + 255) / 256, 256, 0, stream>>>(w_proj, wp_hi, wp_lo, Cc * Cc);
    prep_xt<<<dim3(Nn / 64, Cc / 64, Bn), 256, 0, stream>>>(x, xt_hi, xt_lo);

    // 1) QKV GEMM (2-phase dbuf) -> qk_t + v_cn
    gemm_split<0><<<dim3(Nn / 128, (3 * Cc) / 128, Bn), 256, 0, stream>>>(
        wq_hi, wq_lo, xt_hi, xt_lo, qk_t, v_cn, nullptr, nullptr, 3 * Cc, Cc, Nn);

    // 2) Hybrid attention, global_load_lds staging (128q blocks, 1024 blocks)
    attn_mfma<<<dim3(Nn / 128, NHEADS, Bn), 256, 0, stream>>>(qk_t, v_cn, aot_hi, aot_lo);

    // 3) Projection GEMM (2-phase dbuf, fp32 out + bias)
    gemm_split<1><<<dim3(Nn / 128, Cc / 128, Bn), 256, 0, stream>>>(
        wp_hi, wp_lo, aot_hi, aot_lo, nullptr, nullptr, out, b_proj, Cc, Cc, Nn);
}

// Round 16
// 139.757 us; speedup vs baseline: 1.1998x; 1.1623x over previous
//
#include <hip/hip_runtime.h>
#include <hip/hip_bf16.h>
#include <math.h>

// Problem constants
constexpr int Bn     = 16;    // batch
constexpr int Cc     = 384;   // channels
constexpr int Nn     = 1024;  // tokens (32*32)
constexpr int NHEADS = 8;
constexpr int HD     = 48;    // head dim
constexpr float SCALE = 0.14433756729740643f; // 48^-0.5
constexpr float SCL2  = 0.14433756729740643f * 1.4426950408889634f; // SCALE*log2(e)

using bf16x8 = __attribute__((ext_vector_type(8))) short;
using bf16x4 = __attribute__((ext_vector_type(4))) short;
using f32x4  = __attribute__((ext_vector_type(4))) float;

__device__ inline short f2b(float f) {
    __hip_bfloat16 h = __float2bfloat16(f);
    return *reinterpret_cast<short*>(&h);
}
__device__ inline float b2f(short s) {
    __hip_bfloat16 h = *reinterpret_cast<__hip_bfloat16*>(&s);
    return __bfloat162float(h);
}

// async global->LDS, 16B per lane; LDS dest = wave-uniform base + lane*16B
__device__ __forceinline__ void gload16(const short* g, short* l) {
    __builtin_amdgcn_global_load_lds(
        (const __attribute__((address_space(1))) void*)(g),
        (__attribute__((address_space(3))) void*)(l),
        16, 0, 0);
}

// ---------------------------------------------------------------------------
// Elementwise fp32 -> (hi, lo) bf16 split.
// ---------------------------------------------------------------------------
__global__ __launch_bounds__(256) void conv_split(const float* __restrict__ in,
                                                  short* __restrict__ hi,
                                                  short* __restrict__ lo, int n)
{
    int i = (blockIdx.x * 256 + threadIdx.x) * 4;
    if (i >= n) return;
    float4 v = *reinterpret_cast<const float4*>(&in[i]);
    float vs[4] = {v.x, v.y, v.z, v.w};
    bf16x4 h, l;
#pragma unroll
    for (int j = 0; j < 4; ++j) {
        h[j] = f2b(vs[j]);
        l[j] = f2b(vs[j] - b2f(h[j]));
    }
    *reinterpret_cast<bf16x4*>(&hi[i]) = h;
    *reinterpret_cast<bf16x4*>(&lo[i]) = l;
}

// ---------------------------------------------------------------------------
// x (B, C, N) fp32 -> x^T (B, N, C) bf16 hi/lo.  64x64 tile via LDS.
// ---------------------------------------------------------------------------
__global__ __launch_bounds__(256) void prep_xt(const float* __restrict__ x,
                                               short* __restrict__ xt_hi,
                                               short* __restrict__ xt_lo)
{
    const int b  = blockIdx.z;
    const int c0 = blockIdx.y * 64;
    const int n0 = blockIdx.x * 64;
    __shared__ float T[64 * 68];

    const int tid = threadIdx.x;
    const int r   = tid >> 2;
    const int seg = tid & 3;

    const float* xb = x + ((size_t)b * Cc + c0) * Nn;
#pragma unroll
    for (int i = 0; i < 4; ++i) {
        float4 v = *reinterpret_cast<const float4*>(&xb[(size_t)r * Nn + n0 + seg * 16 + i * 4]);
        *reinterpret_cast<float4*>(&T[r * 68 + seg * 16 + i * 4]) = v;
    }
    __syncthreads();

    short* oh = xt_hi + ((size_t)b * Nn + n0 + r) * Cc + c0;
    short* ol = xt_lo + ((size_t)b * Nn + n0 + r) * Cc + c0;
#pragma unroll
    for (int i = 0; i < 4; ++i) {
        bf16x4 hv, lv;
#pragma unroll
        for (int j = 0; j < 4; ++j) {
            float v = T[(seg * 16 + i * 4 + j) * 68 + r];
            hv[j] = f2b(v);
            lv[j] = f2b(v - b2f(hv[j]));
        }
        *reinterpret_cast<bf16x4*>(&oh[seg * 16 + i * 4]) = hv;
        *reinterpret_cast<bf16x4*>(&ol[seg * 16 + i * 4]) = lv;
    }
}

// ---------------------------------------------------------------------------
// Split-bf16 MFMA GEMM, 2-phase LDS double-buffer, global_load_lds staging.
// MODE 0 (QKV): 2-pass  y = Whi*Xhi + Whi*Xlo  (no Wlo — error ~ output bf16
//               rounding, attenuated through attention). 48 KB LDS -> 3 blk/CU.
//               m<768 -> Yqk token-major (B,N,768) bf16 (Q pre-scaled by SCL2);
//               m>=768 -> Yv (B,384,N) bf16.
// MODE 1 (PROJ): 3-pass (full split precision, error hits output directly);
//               fp32 out + bias.  64 KB LDS.
// ---------------------------------------------------------------------------
template <int MODE>
__global__ __launch_bounds__(256) void gemm_split(const short* __restrict__ Whi,
                                                  const short* __restrict__ Wlo,
                                                  const short* __restrict__ Xhi,
                                                  const short* __restrict__ Xlo,
                                                  short* __restrict__ Yqk,
                                                  short* __restrict__ Yv,
                                                  float* __restrict__ Yf,
                                                  const float* __restrict__ bias,
                                                  int M, int K, int NN)
{
    const int b  = blockIdx.z;
    const int m0 = blockIdx.y * 128;
    const int n0 = blockIdx.x * 128;
    const short* Xb_hi = Xhi + (size_t)b * NN * K;
    const short* Xb_lo = Xlo + (size_t)b * NN * K;

    constexpr int BUFS = (MODE == 0) ? 12288 : 16384;   // shorts per buffer
    constexpr int OAhi = 0;
    constexpr int OAlo = 4096;                          // MODE 1 only
    constexpr int OBhi = (MODE == 0) ? 4096 : 8192;
    constexpr int OBlo = (MODE == 0) ? 8192 : 12288;
    __shared__ __align__(16) short smem[(MODE == 0) ? 24576 : 32768];

    const int tid  = threadIdx.x;
    const int lane = tid & 63;
    const int wave = tid >> 6;
    const int c    = lane & 15;
    const int h4   = lane >> 4;
    const int wr   = wave >> 1;
    const int wc   = wave & 1;

    const int sq   = ((tid & 3) ^ ((tid >> 3) & 3)) * 8;  // swizzled src chunk
    const int lds0 = wave * 512;                          // shorts, per tile
    const int lds1 = 2048 + wave * 512;

    const short* gWhi = Whi + (size_t)(m0 + (tid >> 2)) * K + sq;
    const short* gWlo = Wlo + (size_t)(m0 + (tid >> 2)) * K + sq;
    const short* gXhi = Xb_hi + (size_t)(n0 + (tid >> 2)) * K + sq;
    const short* gXlo = Xb_lo + (size_t)(n0 + (tid >> 2)) * K + sq;
    const size_t rowskip = (size_t)64 * K;

    const int sw = (h4 ^ ((c >> 1) & 3)) * 8;             // frag-read swizzle

    f32x4 acc[4][4];
#pragma unroll
    for (int mi = 0; mi < 4; ++mi)
#pragma unroll
        for (int ni = 0; ni < 4; ++ni) acc[mi][ni] = 0.0f;

    // ---- prologue: stage tile 0 into buffer 0 ----
    {
        short* buf = smem;
        gload16(gWhi,           buf + OAhi + lds0);
        gload16(gWhi + rowskip, buf + OAhi + lds1);
        if constexpr (MODE == 1) {
            gload16(gWlo,           buf + OAlo + lds0);
            gload16(gWlo + rowskip, buf + OAlo + lds1);
        }
        gload16(gXhi,           buf + OBhi + lds0);
        gload16(gXhi + rowskip, buf + OBhi + lds1);
        gload16(gXlo,           buf + OBlo + lds0);
        gload16(gXlo + rowskip, buf + OBlo + lds1);
    }
    __syncthreads();

    const int NT = K >> 5;   // 12
    for (int t = 0; t < NT; ++t) {
        short* cbuf = smem + (t & 1) * BUFS;

        // prefetch next tile into the other buffer FIRST
        if (t + 1 < NT) {
            short* nbuf = smem + ((t + 1) & 1) * BUFS;
            const int nk = (t + 1) * 32;
            gload16(gWhi + nk,           nbuf + OAhi + lds0);
            gload16(gWhi + rowskip + nk, nbuf + OAhi + lds1);
            if constexpr (MODE == 1) {
                gload16(gWlo + nk,           nbuf + OAlo + lds0);
                gload16(gWlo + rowskip + nk, nbuf + OAlo + lds1);
            }
            gload16(gXhi + nk,           nbuf + OBhi + lds0);
            gload16(gXhi + rowskip + nk, nbuf + OBhi + lds1);
            gload16(gXlo + nk,           nbuf + OBlo + lds0);
            gload16(gXlo + rowskip + nk, nbuf + OBlo + lds1);
        }

        bf16x8 a_hi[4], a_lo[4], b_hi[4], b_lo[4];
#pragma unroll
        for (int mi = 0; mi < 4; ++mi) {
            int row = wr * 64 + mi * 16 + c;
            a_hi[mi] = *reinterpret_cast<const bf16x8*>(&cbuf[OAhi + row * 32 + sw]);
            if constexpr (MODE == 1)
                a_lo[mi] = *reinterpret_cast<const bf16x8*>(&cbuf[OAlo + row * 32 + sw]);
        }
#pragma unroll
        for (int ni = 0; ni < 4; ++ni) {
            int row = wc * 64 + ni * 16 + c;
            b_hi[ni] = *reinterpret_cast<const bf16x8*>(&cbuf[OBhi + row * 32 + sw]);
            b_lo[ni] = *reinterpret_cast<const bf16x8*>(&cbuf[OBlo + row * 32 + sw]);
        }
#pragma unroll
        for (int mi = 0; mi < 4; ++mi)
#pragma unroll
            for (int ni = 0; ni < 4; ++ni) {
                acc[mi][ni] = __builtin_amdgcn_mfma_f32_16x16x32_bf16(a_hi[mi], b_hi[ni], acc[mi][ni], 0, 0, 0);
                acc[mi][ni] = __builtin_amdgcn_mfma_f32_16x16x32_bf16(a_hi[mi], b_lo[ni], acc[mi][ni], 0, 0, 0);
                if constexpr (MODE == 1)
                    acc[mi][ni] = __builtin_amdgcn_mfma_f32_16x16x32_bf16(a_lo[mi], b_hi[ni], acc[mi][ni], 0, 0, 0);
            }

        __syncthreads();   // drains prefetch loads + protects buffer reuse
    }

    if (MODE == 0) {
        if (m0 < 768) {
            const float qscale = (m0 < 384) ? SCL2 : 1.0f;
            short* Cs = smem;  // [128 n][136]
#pragma unroll
            for (int mi = 0; mi < 4; ++mi)
#pragma unroll
                for (int ni = 0; ni < 4; ++ni) {
                    int nl = wc * 64 + ni * 16 + c;
                    int cl = wr * 64 + mi * 16 + 4 * h4;
                    bf16x4 pk;
#pragma unroll
                    for (int r = 0; r < 4; ++r) pk[r] = f2b(acc[mi][ni][r] * qscale);
                    *reinterpret_cast<bf16x4*>(&Cs[nl * 136 + cl]) = pk;
                }
            __syncthreads();
#pragma unroll
            for (int l = 0; l < 8; ++l) {
                int u  = tid + l * 256;
                int nl = u >> 4, ch = u & 15;
                *reinterpret_cast<bf16x8*>(&Yqk[((size_t)b * NN + n0 + nl) * 768 + m0 + ch * 8]) =
                    *reinterpret_cast<const bf16x8*>(&Cs[nl * 136 + ch * 8]);
            }
        } else {
            short* Cs = smem;  // [128 ch][136]
#pragma unroll
            for (int mi = 0; mi < 4; ++mi)
#pragma unroll
                for (int ni = 0; ni < 4; ++ni)
#pragma unroll
                    for (int r = 0; r < 4; ++r) {
                        int ml = wr * 64 + mi * 16 + h4 * 4 + r;
                        int nl = wc * 64 + ni * 16 + c;
                        Cs[ml * 136 + nl] = f2b(acc[mi][ni][r]);
                    }
            __syncthreads();
            short* Yb = Yv + (size_t)b * Cc * NN;
            const int srow2 = tid >> 1;
            const int cseg  = (tid & 1) * 64;
#pragma unroll
            for (int i = 0; i < 8; ++i)
                *reinterpret_cast<bf16x8*>(&Yb[(size_t)(m0 - 768 + srow2) * NN + n0 + cseg + i * 8]) =
                    *reinterpret_cast<const bf16x8*>(&Cs[srow2 * 136 + cseg + i * 8]);
        }
    } else {
        float* Yb = Yf + (size_t)b * M * NN;
        float* Cf = reinterpret_cast<float*>(smem);
        const int mr2 = tid >> 2;
        const int seg = tid & 3;
#pragma unroll
        for (int half = 0; half < 2; ++half) {
            __syncthreads();
            if (wr == half) {
#pragma unroll
                for (int mi = 0; mi < 4; ++mi)
#pragma unroll
                    for (int ni = 0; ni < 4; ++ni)
#pragma unroll
                        for (int r = 0; r < 4; ++r) {
                            int ml = mi * 16 + h4 * 4 + r;
                            int nl = wc * 64 + ni * 16 + c;
                            Cf[ml * 132 + nl] = acc[mi][ni][r];
                        }
            }
            __syncthreads();
            float bv = bias ? bias[m0 + half * 64 + mr2] : 0.0f;
#pragma unroll
            for (int i = 0; i < 8; ++i) {
                float4 v = *reinterpret_cast<const float4*>(&Cf[mr2 * 132 + seg * 32 + i * 4]);
                v.x += bv; v.y += bv; v.z += bv; v.w += bv;
                *reinterpret_cast<float4*>(&Yb[(size_t)(m0 + half * 64 + mr2) * NN + n0 + seg * 32 + i * 4]) = v;
            }
        }
    }
}

// ---------------------------------------------------------------------------
// Hybrid MFMA flash attention, global_load_lds staging.
// New: lsum computed on the MATRIX pipe via a ones-row V block (Vs rows 48..63:
// row 48 = 1.0, rows 49..63 = 0, initialized once — V staging only writes rows
// 0..47).  jd=3 PV MFMA accumulates Sigma_m P[q][m] into o3[set][0] (lanes
// h4==0, col=q); epilogue broadcasts via one __shfl.  Replaces 32 VALU adds
// per tile + the end xor-reduce.
// ---------------------------------------------------------------------------
__global__ __launch_bounds__(256, 4) void attn_mfma(const short* __restrict__ qk_t,
                                                    const short* __restrict__ v_cn,
                                                    short* __restrict__ aot_hi,
                                                    short* __restrict__ aot_lo)
{
    const int b  = blockIdx.z;
    const int h  = blockIdx.y;
    const int n0 = blockIdx.x * 128;

    __shared__ __align__(16) short smem[4096 + 4096];  // Ks 8KB + Vs[64][64] 8KB
    short* Ks = smem;
    short* Vs = smem + 4096;

    const int tid  = threadIdx.x;
    const int lane = tid & 63;
    const int wave = tid >> 6;
    const int c    = lane & 15;
    const int h4   = lane >> 4;
    const int qb   = n0 + wave * 32;

    const short* Qb    = qk_t + ((size_t)b * Nn + qb) * 768 + h * HD;
    const short* Kbase = qk_t + (size_t)b * Nn * 768 + 384 + h * HD;
    const short* Vb    = v_cn + ((size_t)b * Cc + h * HD) * Nn;

    const bf16x8 z8 = {};

    // init Vs rows 48..63: row 48 = bf16 1.0, rows 49..63 = 0 (once)
    {
        int i0 = tid * 4;                       // 0..1023
        short v = (i0 < 64) ? (short)0x3F80 : (short)0;
        bf16x4 iv = {v, v, v, v};
        *reinterpret_cast<bf16x4*>(&Vs[3072 + i0]) = iv;
    }

    // ---- Q fragments (loop-invariant, 2 sets) ----
    bf16x8 qf0[2], qf1[2];
#pragma unroll
    for (int s = 0; s < 2; ++s) {
        const short* qrow = Qb + (size_t)(s * 16 + c) * 768;
        qf0[s] = *reinterpret_cast<const bf16x8*>(qrow + 8 * h4);
        qf1[s] = (h4 < 2) ? *reinterpret_cast<const bf16x8*>(qrow + 32 + 8 * h4) : z8;
    }

    const int u0 = wave * 64 + lane;
    const int r0 = u0 >> 3;
    const int sc0 = ((u0 & 7) ^ (r0 & 7)) * 8;
    const int u1 = 256 + u0;
    const int r1 = u1 >> 3;
    const int sc1 = ((u1 & 7) ^ (r1 & 7)) * 8;

    const int cs8 = c & 7;
    const int ks0 = (h4 ^ cs8) * 8;
    const int ks1 = ((4 + h4) ^ cs8) * 8;
    const int hh  = h4 >> 1;
    const int hb  = (h4 & 1) * 4;
    const int vs00 = ((0 + hh) ^ cs8) * 8 + hb;
    const int vs01 = ((2 + hh) ^ cs8) * 8 + hb;
    const int vs10 = ((4 + hh) ^ cs8) * 8 + hb;
    const int vs11 = ((6 + hh) ^ cs8) * 8 + hb;

    f32x4 o[2][3];
#pragma unroll
    for (int s = 0; s < 2; ++s)
#pragma unroll
        for (int jd = 0; jd < 3; ++jd) o[s][jd] = 0.0f;
    f32x4 o3[2];
    o3[0] = 0.0f; o3[1] = 0.0f;

    for (int t = 0; t < 16; ++t) {
        const int m0 = t * 64;
        __syncthreads();

        gload16(Kbase + (size_t)(m0 + r0) * 768 + sc0, Ks + wave * 512);
        gload16(Kbase + (size_t)(m0 + r1) * 768 + sc1, Ks + 2048 + wave * 512);
        gload16(Vb + (size_t)r0 * Nn + m0 + sc0, Vs + wave * 512);
        if (wave < 2)
            gload16(Vb + (size_t)r1 * Nn + m0 + sc1, Vs + 2048 + wave * 512);
        __syncthreads();

        f32x4 s4a[4], s4b[4];
#pragma unroll
        for (int j = 0; j < 4; ++j) { s4a[j] = 0.0f; s4b[j] = 0.0f; }
#pragma unroll
        for (int j = 0; j < 4; ++j) {
            int kr = (16 * j + c) * 64;
            bf16x8 kc0 = *reinterpret_cast<const bf16x8*>(&Ks[kr + ks0]);
            bf16x8 kc1 = *reinterpret_cast<const bf16x8*>(&Ks[kr + ks1]);
            s4a[j] = __builtin_amdgcn_mfma_f32_16x16x32_bf16(kc0, qf0[0], s4a[j], 0, 0, 0);
            s4a[j] = __builtin_amdgcn_mfma_f32_16x16x32_bf16(kc1, qf1[0], s4a[j], 0, 0, 0);
            s4b[j] = __builtin_amdgcn_mfma_f32_16x16x32_bf16(kc0, qf0[1], s4b[j], 0, 0, 0);
            s4b[j] = __builtin_amdgcn_mfma_f32_16x16x32_bf16(kc1, qf1[1], s4b[j], 0, 0, 0);
        }

        bf16x8 pa[2][2];
        {
            float p[4][4];
#pragma unroll
            for (int j = 0; j < 4; ++j)
#pragma unroll
                for (int r = 0; r < 4; ++r)
                    p[j][r] = exp2f(s4a[j][r]);
#pragma unroll
            for (int r = 0; r < 4; ++r) {
                pa[0][0][r]     = f2b(p[0][r]);
                pa[0][0][4 + r] = f2b(p[1][r]);
                pa[0][1][r]     = f2b(p[2][r]);
                pa[0][1][4 + r] = f2b(p[3][r]);
            }
        }
        {
            float p[4][4];
#pragma unroll
            for (int j = 0; j < 4; ++j)
#pragma unroll
                for (int r = 0; r < 4; ++r)
                    p[j][r] = exp2f(s4b[j][r]);
#pragma unroll
            for (int r = 0; r < 4; ++r) {
                pa[1][0][r]     = f2b(p[0][r]);
                pa[1][0][4 + r] = f2b(p[1][r]);
                pa[1][1][r]     = f2b(p[2][r]);
                pa[1][1][4 + r] = f2b(p[3][r]);
            }
        }

        // ---- PV (jd 0..2) + ones-row lsum (jd 3) ----
#pragma unroll
        for (int jd = 0; jd < 4; ++jd) {
            int vr = (16 * jd + c) * 64;
            bf16x4 a0 = *reinterpret_cast<const bf16x4*>(&Vs[vr + vs00]);
            bf16x4 d0 = *reinterpret_cast<const bf16x4*>(&Vs[vr + vs01]);
            bf16x4 a1 = *reinterpret_cast<const bf16x4*>(&Vs[vr + vs10]);
            bf16x4 d1 = *reinterpret_cast<const bf16x4*>(&Vs[vr + vs11]);
            bf16x8 vf0, vf1;
#pragma unroll
            for (int r = 0; r < 4; ++r) {
                vf0[r] = a0[r]; vf0[4 + r] = d0[r];
                vf1[r] = a1[r]; vf1[4 + r] = d1[r];
            }
            if (jd < 3) {
                o[0][jd] = __builtin_amdgcn_mfma_f32_16x16x32_bf16(vf0, pa[0][0], o[0][jd], 0, 0, 0);
                o[0][jd] = __builtin_amdgcn_mfma_f32_16x16x32_bf16(vf1, pa[0][1], o[0][jd], 0, 0, 0);
                o[1][jd] = __builtin_amdgcn_mfma_f32_16x16x32_bf16(vf0, pa[1][0], o[1][jd], 0, 0, 0);
                o[1][jd] = __builtin_amdgcn_mfma_f32_16x16x32_bf16(vf1, pa[1][1], o[1][jd], 0, 0, 0);
            } else {
                o3[0] = __builtin_amdgcn_mfma_f32_16x16x32_bf16(vf0, pa[0][0], o3[0], 0, 0, 0);
                o3[0] = __builtin_amdgcn_mfma_f32_16x16x32_bf16(vf1, pa[0][1], o3[0], 0, 0, 0);
                o3[1] = __builtin_amdgcn_mfma_f32_16x16x32_bf16(vf0, pa[1][0], o3[1], 0, 0, 0);
                o3[1] = __builtin_amdgcn_mfma_f32_16x16x32_bf16(vf1, pa[1][1], o3[1], 0, 0, 0);
            }
        }
    }

    // ---- epilogue: lsum broadcast from h4==0 lanes, normalize, split hi/lo ----
#pragma unroll
    for (int set = 0; set < 2; ++set) {
        float ls = __shfl(o3[set][0], c);    // lane (c, h4=0) holds Sigma P for q=c
        float linv = 1.0f / ls;
        size_t rowoff = ((size_t)b * Nn + qb + set * 16 + c) * Cc + h * HD;
#pragma unroll
        for (int jd = 0; jd < 3; ++jd) {
            bf16x4 hv, lv;
#pragma unroll
            for (int r = 0; r < 4; ++r) {
                float val = o[set][jd][r] * linv;
                short x = f2b(val);
                hv[r] = x;
                lv[r] = f2b(val - b2f(x));
            }
            *reinterpret_cast<bf16x4*>(&aot_hi[rowoff + 16 * jd + 4 * h4]) = hv;
            *reinterpret_cast<bf16x4*>(&aot_lo[rowoff + 16 * jd + 4 * h4]) = lv;
        }
    }
}

// ---------------------------------------------------------------------------
extern "C" void kernel_launch(void* const* d_in, const int* in_sizes, int n_in,
                              void* d_out, int out_size, void* d_ws, size_t ws_size,
                              hipStream_t stream)
{
    const float* x      = (const float*)d_in[0];
    const float* w_qkv  = (const float*)d_in[1];
    const float* w_proj = (const float*)d_in[2];
    const float* b_proj = (const float*)d_in[3];
    float* out = (float*)d_out;

    short* ws = (short*)d_ws;
    const size_t XT = (size_t)Bn * Nn * Cc;            // 6291456
    short* xt_hi  = ws;
    short* xt_lo  = xt_hi + XT;
    short* wq_hi  = xt_lo + XT;
    short* wq_lo  = wq_hi + (size_t)3 * Cc * Cc;
    short* wp_hi  = wq_lo + (size_t)3 * Cc * Cc;
    short* wp_lo  = wp_hi + (size_t)Cc * Cc;
    short* qk_t   = wp_lo + (size_t)Cc * Cc;           // (B, N, 768)
    short* v_cn   = qk_t + (size_t)Bn * Nn * 768;      // (B, 384, N)
    short* aot_hi = v_cn + XT;
    short* aot_lo = aot_hi + XT;

    // 0) weight + x prep
    conv_split<<<(3 * Cc * Cc / 4 + 255) / 256, 256, 0, stream>>>(w_qkv, wq_hi, wq_lo, 3 * Cc * Cc);
    conv_split<<<(Cc * Cc / 4 + 255) / 256, 256, 0, stream>>>(w_proj, wp_hi, wp_lo, Cc * Cc);
    prep_xt<<<dim3(Nn / 64, Cc / 64, Bn), 256, 0, stream>>>(x, xt_hi, xt_lo);

    // 1) QKV GEMM (2-pass, 2-phase dbuf) -> qk_t + v_cn
    gemm_split<0><<<dim3(Nn / 128, (3 * Cc) / 128, Bn), 256, 0, stream>>>(
        wq_hi, wq_lo, xt_hi, xt_lo, qk_t, v_cn, nullptr, nullptr, 3 * Cc, Cc, Nn);

    // 2) Hybrid attention (ones-row lsum, 1024 blocks)
    attn_mfma<<<dim3(Nn / 128, NHEADS, Bn), 256, 0, stream>>>(qk_t, v_cn, aot_hi, aot_lo);

    // 3) Projection GEMM (3-pass, 2-phase dbuf, fp32 out + bias)
    gemm_split<1><<<dim3(Nn / 128, Cc / 128, Bn), 256, 0, stream>>>(
        wp_hi, wp_lo, aot_hi, aot_lo, nullptr, nullptr, out, b_proj, Cc, Cc, Nn);
}

// Round 17
// 137.256 us; speedup vs baseline: 1.2216x; 1.0182x over previous
//
#include <hip/hip_runtime.h>
#include <hip/hip_bf16.h>
#include <math.h>

// Problem constants
constexpr int Bn     = 16;    // batch
constexpr int Cc     = 384;   // channels
constexpr int Nn     = 1024;  // tokens (32*32)
constexpr int NHEADS = 8;
constexpr int HD     = 48;    // head dim
constexpr float SCALE = 0.14433756729740643f; // 48^-0.5
constexpr float SCL2  = 0.14433756729740643f * 1.4426950408889634f; // SCALE*log2(e)

using bf16x8 = __attribute__((ext_vector_type(8))) short;
using bf16x4 = __attribute__((ext_vector_type(4))) short;
using f32x4  = __attribute__((ext_vector_type(4))) float;

__device__ inline short f2b(float f) {
    __hip_bfloat16 h = __float2bfloat16(f);
    return *reinterpret_cast<short*>(&h);
}
__device__ inline float b2f(short s) {
    __hip_bfloat16 h = *reinterpret_cast<__hip_bfloat16*>(&s);
    return __bfloat162float(h);
}

// async global->LDS, 16B per lane; LDS dest = wave-uniform base + lane*16B
__device__ __forceinline__ void gload16(const short* g, short* l) {
    __builtin_amdgcn_global_load_lds(
        (const __attribute__((address_space(1))) void*)(g),
        (__attribute__((address_space(3))) void*)(l),
        16, 0, 0);
}

// ---------------------------------------------------------------------------
// Elementwise fp32 -> (hi, lo) bf16 split.
// ---------------------------------------------------------------------------
__global__ __launch_bounds__(256) void conv_split(const float* __restrict__ in,
                                                  short* __restrict__ hi,
                                                  short* __restrict__ lo, int n)
{
    int i = (blockIdx.x * 256 + threadIdx.x) * 4;
    if (i >= n) return;
    float4 v = *reinterpret_cast<const float4*>(&in[i]);
    float vs[4] = {v.x, v.y, v.z, v.w};
    bf16x4 h, l;
#pragma unroll
    for (int j = 0; j < 4; ++j) {
        h[j] = f2b(vs[j]);
        l[j] = f2b(vs[j] - b2f(h[j]));
    }
    *reinterpret_cast<bf16x4*>(&hi[i]) = h;
    *reinterpret_cast<bf16x4*>(&lo[i]) = l;
}

// ---------------------------------------------------------------------------
// x (B, C, N) fp32 -> x^T (B, N, C) bf16 hi/lo.  64x64 tile via LDS.
// ---------------------------------------------------------------------------
__global__ __launch_bounds__(256) void prep_xt(const float* __restrict__ x,
                                               short* __restrict__ xt_hi,
                                               short* __restrict__ xt_lo)
{
    const int b  = blockIdx.z;
    const int c0 = blockIdx.y * 64;
    const int n0 = blockIdx.x * 64;
    __shared__ float T[64 * 68];

    const int tid = threadIdx.x;
    const int r   = tid >> 2;
    const int seg = tid & 3;

    const float* xb = x + ((size_t)b * Cc + c0) * Nn;
#pragma unroll
    for (int i = 0; i < 4; ++i) {
        float4 v = *reinterpret_cast<const float4*>(&xb[(size_t)r * Nn + n0 + seg * 16 + i * 4]);
        *reinterpret_cast<float4*>(&T[r * 68 + seg * 16 + i * 4]) = v;
    }
    __syncthreads();

    short* oh = xt_hi + ((size_t)b * Nn + n0 + r) * Cc + c0;
    short* ol = xt_lo + ((size_t)b * Nn + n0 + r) * Cc + c0;
#pragma unroll
    for (int i = 0; i < 4; ++i) {
        bf16x4 hv, lv;
#pragma unroll
        for (int j = 0; j < 4; ++j) {
            float v = T[(seg * 16 + i * 4 + j) * 68 + r];
            hv[j] = f2b(v);
            lv[j] = f2b(v - b2f(hv[j]));
        }
        *reinterpret_cast<bf16x4*>(&oh[seg * 16 + i * 4]) = hv;
        *reinterpret_cast<bf16x4*>(&ol[seg * 16 + i * 4]) = lv;
    }
}

// ---------------------------------------------------------------------------
// Split-bf16 MFMA GEMM, 2-phase LDS double-buffer, global_load_lds staging.
// MODE 0 (QKV): 2-pass  y = Whi*Xhi + Whi*Xlo.  48 KB LDS.
// MODE 1 (PROJ): 3-pass; fp32 out + bias.  64 KB LDS.   (unchanged from R16)
// ---------------------------------------------------------------------------
template <int MODE>
__global__ __launch_bounds__(256) void gemm_split(const short* __restrict__ Whi,
                                                  const short* __restrict__ Wlo,
                                                  const short* __restrict__ Xhi,
                                                  const short* __restrict__ Xlo,
                                                  short* __restrict__ Yqk,
                                                  short* __restrict__ Yv,
                                                  float* __restrict__ Yf,
                                                  const float* __restrict__ bias,
                                                  int M, int K, int NN)
{
    const int b  = blockIdx.z;
    const int m0 = blockIdx.y * 128;
    const int n0 = blockIdx.x * 128;
    const short* Xb_hi = Xhi + (size_t)b * NN * K;
    const short* Xb_lo = Xlo + (size_t)b * NN * K;

    constexpr int BUFS = (MODE == 0) ? 12288 : 16384;   // shorts per buffer
    constexpr int OAhi = 0;
    constexpr int OAlo = 4096;                          // MODE 1 only
    constexpr int OBhi = (MODE == 0) ? 4096 : 8192;
    constexpr int OBlo = (MODE == 0) ? 8192 : 12288;
    __shared__ __align__(16) short smem[(MODE == 0) ? 24576 : 32768];

    const int tid  = threadIdx.x;
    const int lane = tid & 63;
    const int wave = tid >> 6;
    const int c    = lane & 15;
    const int h4   = lane >> 4;
    const int wr   = wave >> 1;
    const int wc   = wave & 1;

    const int sq   = ((tid & 3) ^ ((tid >> 3) & 3)) * 8;  // swizzled src chunk
    const int lds0 = wave * 512;                          // shorts, per tile
    const int lds1 = 2048 + wave * 512;

    const short* gWhi = Whi + (size_t)(m0 + (tid >> 2)) * K + sq;
    const short* gWlo = Wlo + (size_t)(m0 + (tid >> 2)) * K + sq;
    const short* gXhi = Xb_hi + (size_t)(n0 + (tid >> 2)) * K + sq;
    const short* gXlo = Xb_lo + (size_t)(n0 + (tid >> 2)) * K + sq;
    const size_t rowskip = (size_t)64 * K;

    const int sw = (h4 ^ ((c >> 1) & 3)) * 8;             // frag-read swizzle

    f32x4 acc[4][4];
#pragma unroll
    for (int mi = 0; mi < 4; ++mi)
#pragma unroll
        for (int ni = 0; ni < 4; ++ni) acc[mi][ni] = 0.0f;

    // ---- prologue: stage tile 0 into buffer 0 ----
    {
        short* buf = smem;
        gload16(gWhi,           buf + OAhi + lds0);
        gload16(gWhi + rowskip, buf + OAhi + lds1);
        if constexpr (MODE == 1) {
            gload16(gWlo,           buf + OAlo + lds0);
            gload16(gWlo + rowskip, buf + OAlo + lds1);
        }
        gload16(gXhi,           buf + OBhi + lds0);
        gload16(gXhi + rowskip, buf + OBhi + lds1);
        gload16(gXlo,           buf + OBlo + lds0);
        gload16(gXlo + rowskip, buf + OBlo + lds1);
    }
    __syncthreads();

    const int NT = K >> 5;   // 12
    for (int t = 0; t < NT; ++t) {
        short* cbuf = smem + (t & 1) * BUFS;

        // prefetch next tile into the other buffer FIRST
        if (t + 1 < NT) {
            short* nbuf = smem + ((t + 1) & 1) * BUFS;
            const int nk = (t + 1) * 32;
            gload16(gWhi + nk,           nbuf + OAhi + lds0);
            gload16(gWhi + rowskip + nk, nbuf + OAhi + lds1);
            if constexpr (MODE == 1) {
                gload16(gWlo + nk,           nbuf + OAlo + lds0);
                gload16(gWlo + rowskip + nk, nbuf + OAlo + lds1);
            }
            gload16(gXhi + nk,           nbuf + OBhi + lds0);
            gload16(gXhi + rowskip + nk, nbuf + OBhi + lds1);
            gload16(gXlo + nk,           nbuf + OBlo + lds0);
            gload16(gXlo + rowskip + nk, nbuf + OBlo + lds1);
        }

        bf16x8 a_hi[4], a_lo[4], b_hi[4], b_lo[4];
#pragma unroll
        for (int mi = 0; mi < 4; ++mi) {
            int row = wr * 64 + mi * 16 + c;
            a_hi[mi] = *reinterpret_cast<const bf16x8*>(&cbuf[OAhi + row * 32 + sw]);
            if constexpr (MODE == 1)
                a_lo[mi] = *reinterpret_cast<const bf16x8*>(&cbuf[OAlo + row * 32 + sw]);
        }
#pragma unroll
        for (int ni = 0; ni < 4; ++ni) {
            int row = wc * 64 + ni * 16 + c;
            b_hi[ni] = *reinterpret_cast<const bf16x8*>(&cbuf[OBhi + row * 32 + sw]);
            b_lo[ni] = *reinterpret_cast<const bf16x8*>(&cbuf[OBlo + row * 32 + sw]);
        }
#pragma unroll
        for (int mi = 0; mi < 4; ++mi)
#pragma unroll
            for (int ni = 0; ni < 4; ++ni) {
                acc[mi][ni] = __builtin_amdgcn_mfma_f32_16x16x32_bf16(a_hi[mi], b_hi[ni], acc[mi][ni], 0, 0, 0);
                acc[mi][ni] = __builtin_amdgcn_mfma_f32_16x16x32_bf16(a_hi[mi], b_lo[ni], acc[mi][ni], 0, 0, 0);
                if constexpr (MODE == 1)
                    acc[mi][ni] = __builtin_amdgcn_mfma_f32_16x16x32_bf16(a_lo[mi], b_hi[ni], acc[mi][ni], 0, 0, 0);
            }

        __syncthreads();   // drains prefetch loads + protects buffer reuse
    }

    if (MODE == 0) {
        if (m0 < 768) {
            const float qscale = (m0 < 384) ? SCL2 : 1.0f;
            short* Cs = smem;  // [128 n][136]
#pragma unroll
            for (int mi = 0; mi < 4; ++mi)
#pragma unroll
                for (int ni = 0; ni < 4; ++ni) {
                    int nl = wc * 64 + ni * 16 + c;
                    int cl = wr * 64 + mi * 16 + 4 * h4;
                    bf16x4 pk;
#pragma unroll
                    for (int r = 0; r < 4; ++r) pk[r] = f2b(acc[mi][ni][r] * qscale);
                    *reinterpret_cast<bf16x4*>(&Cs[nl * 136 + cl]) = pk;
                }
            __syncthreads();
#pragma unroll
            for (int l = 0; l < 8; ++l) {
                int u  = tid + l * 256;
                int nl = u >> 4, ch = u & 15;
                *reinterpret_cast<bf16x8*>(&Yqk[((size_t)b * NN + n0 + nl) * 768 + m0 + ch * 8]) =
                    *reinterpret_cast<const bf16x8*>(&Cs[nl * 136 + ch * 8]);
            }
        } else {
            short* Cs = smem;  // [128 ch][136]
#pragma unroll
            for (int mi = 0; mi < 4; ++mi)
#pragma unroll
                for (int ni = 0; ni < 4; ++ni)
#pragma unroll
                    for (int r = 0; r < 4; ++r) {
                        int ml = wr * 64 + mi * 16 + h4 * 4 + r;
                        int nl = wc * 64 + ni * 16 + c;
                        Cs[ml * 136 + nl] = f2b(acc[mi][ni][r]);
                    }
            __syncthreads();
            short* Yb = Yv + (size_t)b * Cc * NN;
            const int srow2 = tid >> 1;
            const int cseg  = (tid & 1) * 64;
#pragma unroll
            for (int i = 0; i < 8; ++i)
                *reinterpret_cast<bf16x8*>(&Yb[(size_t)(m0 - 768 + srow2) * NN + n0 + cseg + i * 8]) =
                    *reinterpret_cast<const bf16x8*>(&Cs[srow2 * 136 + cseg + i * 8]);
        }
    } else {
        float* Yb = Yf + (size_t)b * M * NN;
        float* Cf = reinterpret_cast<float*>(smem);
        const int mr2 = tid >> 2;
        const int seg = tid & 3;
#pragma unroll
        for (int half = 0; half < 2; ++half) {
            __syncthreads();
            if (wr == half) {
#pragma unroll
                for (int mi = 0; mi < 4; ++mi)
#pragma unroll
                    for (int ni = 0; ni < 4; ++ni)
#pragma unroll
                        for (int r = 0; r < 4; ++r) {
                            int ml = mi * 16 + h4 * 4 + r;
                            int nl = wc * 64 + ni * 16 + c;
                            Cf[ml * 132 + nl] = acc[mi][ni][r];
                        }
            }
            __syncthreads();
            float bv = bias ? bias[m0 + half * 64 + mr2] : 0.0f;
#pragma unroll
            for (int i = 0; i < 8; ++i) {
                float4 v = *reinterpret_cast<const float4*>(&Cf[mr2 * 132 + seg * 32 + i * 4]);
                v.x += bv; v.y += bv; v.z += bv; v.w += bv;
                *reinterpret_cast<float4*>(&Yb[(size_t)(m0 + half * 64 + mr2) * NN + n0 + seg * 32 + i * 4]) = v;
            }
        }
    }
}

// ---------------------------------------------------------------------------
// Hybrid MFMA flash attention, global_load_lds staging, 2-PHASE K/V DOUBLE
// BUFFER: stage tile t+1 into buf^1 before computing tile t; the single
// __syncthreads per iteration drains the prefetch under the compute phase.
// Buf b: Ks at smem + b*8192, Vs at smem + b*8192 + 4096 (shorts). 32 KB LDS.
// Ones-row lsum (Vs rows 48..63) initialized in BOTH buffers once; V staging
// only writes rows 0..47.
// ---------------------------------------------------------------------------
__global__ __launch_bounds__(256, 4) void attn_mfma(const short* __restrict__ qk_t,
                                                    const short* __restrict__ v_cn,
                                                    short* __restrict__ aot_hi,
                                                    short* __restrict__ aot_lo)
{
    const int b  = blockIdx.z;
    const int h  = blockIdx.y;
    const int n0 = blockIdx.x * 128;

    __shared__ __align__(16) short smem[16384];  // 2 x (Ks 4096 + Vs 4096)

    const int tid  = threadIdx.x;
    const int lane = tid & 63;
    const int wave = tid >> 6;
    const int c    = lane & 15;
    const int h4   = lane >> 4;
    const int qb   = n0 + wave * 32;

    const short* Qb    = qk_t + ((size_t)b * Nn + qb) * 768 + h * HD;
    const short* Kbase = qk_t + (size_t)b * Nn * 768 + 384 + h * HD;
    const short* Vb    = v_cn + ((size_t)b * Cc + h * HD) * Nn;

    const bf16x8 z8 = {};

    // init Vs rows 48..63 in BOTH buffers: row 48 = 1.0, rows 49..63 = 0
    {
        int i0 = tid * 4;                       // 0..1023
        short v = (i0 < 64) ? (short)0x3F80 : (short)0;
        bf16x4 iv = {v, v, v, v};
        *reinterpret_cast<bf16x4*>(&smem[4096 + 3072 + i0]) = iv;
        *reinterpret_cast<bf16x4*>(&smem[12288 + 3072 + i0]) = iv;
    }

    // ---- Q fragments (loop-invariant, 2 sets) ----
    bf16x8 qf0[2], qf1[2];
#pragma unroll
    for (int s = 0; s < 2; ++s) {
        const short* qrow = Qb + (size_t)(s * 16 + c) * 768;
        qf0[s] = *reinterpret_cast<const bf16x8*>(qrow + 8 * h4);
        qf1[s] = (h4 < 2) ? *reinterpret_cast<const bf16x8*>(qrow + 32 + 8 * h4) : z8;
    }

    const int u0 = wave * 64 + lane;
    const int r0 = u0 >> 3;
    const int sc0 = ((u0 & 7) ^ (r0 & 7)) * 8;
    const int u1 = 256 + u0;
    const int r1 = u1 >> 3;
    const int sc1 = ((u1 & 7) ^ (r1 & 7)) * 8;

    const int cs8 = c & 7;
    const int ks0 = (h4 ^ cs8) * 8;
    const int ks1 = ((4 + h4) ^ cs8) * 8;
    const int hh  = h4 >> 1;
    const int hb  = (h4 & 1) * 4;
    const int vs00 = ((0 + hh) ^ cs8) * 8 + hb;
    const int vs01 = ((2 + hh) ^ cs8) * 8 + hb;
    const int vs10 = ((4 + hh) ^ cs8) * 8 + hb;
    const int vs11 = ((6 + hh) ^ cs8) * 8 + hb;

    f32x4 o[2][3];
#pragma unroll
    for (int s = 0; s < 2; ++s)
#pragma unroll
        for (int jd = 0; jd < 3; ++jd) o[s][jd] = 0.0f;
    f32x4 o3[2];
    o3[0] = 0.0f; o3[1] = 0.0f;

    // ---- prologue: stage tile 0 into buffer 0 ----
    {
        short* Ksb = smem;
        short* Vsb = smem + 4096;
        gload16(Kbase + (size_t)r0 * 768 + sc0, Ksb + wave * 512);
        gload16(Kbase + (size_t)r1 * 768 + sc1, Ksb + 2048 + wave * 512);
        gload16(Vb + (size_t)r0 * Nn + sc0, Vsb + wave * 512);
        if (wave < 2)
            gload16(Vb + (size_t)r1 * Nn + sc1, Vsb + 2048 + wave * 512);
    }
    __syncthreads();

    for (int t = 0; t < 16; ++t) {
        const short* Ks = smem + (t & 1) * 8192;
        const short* Vs = Ks + 4096;

        // prefetch next tile into the other buffer FIRST
        if (t + 1 < 16) {
            short* Ksn = smem + ((t + 1) & 1) * 8192;
            short* Vsn = Ksn + 4096;
            const int mn = (t + 1) * 64;
            gload16(Kbase + (size_t)(mn + r0) * 768 + sc0, Ksn + wave * 512);
            gload16(Kbase + (size_t)(mn + r1) * 768 + sc1, Ksn + 2048 + wave * 512);
            gload16(Vb + (size_t)r0 * Nn + mn + sc0, Vsn + wave * 512);
            if (wave < 2)
                gload16(Vb + (size_t)r1 * Nn + mn + sc1, Vsn + 2048 + wave * 512);
        }

        // ---- QK^T (K frags shared by both sets) ----
        f32x4 s4a[4], s4b[4];
#pragma unroll
        for (int j = 0; j < 4; ++j) { s4a[j] = 0.0f; s4b[j] = 0.0f; }
#pragma unroll
        for (int j = 0; j < 4; ++j) {
            int kr = (16 * j + c) * 64;
            bf16x8 kc0 = *reinterpret_cast<const bf16x8*>(&Ks[kr + ks0]);
            bf16x8 kc1 = *reinterpret_cast<const bf16x8*>(&Ks[kr + ks1]);
            s4a[j] = __builtin_amdgcn_mfma_f32_16x16x32_bf16(kc0, qf0[0], s4a[j], 0, 0, 0);
            s4a[j] = __builtin_amdgcn_mfma_f32_16x16x32_bf16(kc1, qf1[0], s4a[j], 0, 0, 0);
            s4b[j] = __builtin_amdgcn_mfma_f32_16x16x32_bf16(kc0, qf0[1], s4b[j], 0, 0, 0);
            s4b[j] = __builtin_amdgcn_mfma_f32_16x16x32_bf16(kc1, qf1[1], s4b[j], 0, 0, 0);
        }

        // ---- softmax-lite + pack P (sigma order), both sets ----
        bf16x8 pa[2][2];
        {
            float p[4][4];
#pragma unroll
            for (int j = 0; j < 4; ++j)
#pragma unroll
                for (int r = 0; r < 4; ++r)
                    p[j][r] = exp2f(s4a[j][r]);
#pragma unroll
            for (int r = 0; r < 4; ++r) {
                pa[0][0][r]     = f2b(p[0][r]);
                pa[0][0][4 + r] = f2b(p[1][r]);
                pa[0][1][r]     = f2b(p[2][r]);
                pa[0][1][4 + r] = f2b(p[3][r]);
            }
        }
        {
            float p[4][4];
#pragma unroll
            for (int j = 0; j < 4; ++j)
#pragma unroll
                for (int r = 0; r < 4; ++r)
                    p[j][r] = exp2f(s4b[j][r]);
#pragma unroll
            for (int r = 0; r < 4; ++r) {
                pa[1][0][r]     = f2b(p[0][r]);
                pa[1][0][4 + r] = f2b(p[1][r]);
                pa[1][1][r]     = f2b(p[2][r]);
                pa[1][1][4 + r] = f2b(p[3][r]);
            }
        }

        // ---- PV (jd 0..2) + ones-row lsum (jd 3) ----
#pragma unroll
        for (int jd = 0; jd < 4; ++jd) {
            int vr = (16 * jd + c) * 64;
            bf16x4 a0 = *reinterpret_cast<const bf16x4*>(&Vs[vr + vs00]);
            bf16x4 d0 = *reinterpret_cast<const bf16x4*>(&Vs[vr + vs01]);
            bf16x4 a1 = *reinterpret_cast<const bf16x4*>(&Vs[vr + vs10]);
            bf16x4 d1 = *reinterpret_cast<const bf16x4*>(&Vs[vr + vs11]);
            bf16x8 vf0, vf1;
#pragma unroll
            for (int r = 0; r < 4; ++r) {
                vf0[r] = a0[r]; vf0[4 + r] = d0[r];
                vf1[r] = a1[r]; vf1[4 + r] = d1[r];
            }
            if (jd < 3) {
                o[0][jd] = __builtin_amdgcn_mfma_f32_16x16x32_bf16(vf0, pa[0][0], o[0][jd], 0, 0, 0);
                o[0][jd] = __builtin_amdgcn_mfma_f32_16x16x32_bf16(vf1, pa[0][1], o[0][jd], 0, 0, 0);
                o[1][jd] = __builtin_amdgcn_mfma_f32_16x16x32_bf16(vf0, pa[1][0], o[1][jd], 0, 0, 0);
                o[1][jd] = __builtin_amdgcn_mfma_f32_16x16x32_bf16(vf1, pa[1][1], o[1][jd], 0, 0, 0);
            } else {
                o3[0] = __builtin_amdgcn_mfma_f32_16x16x32_bf16(vf0, pa[0][0], o3[0], 0, 0, 0);
                o3[0] = __builtin_amdgcn_mfma_f32_16x16x32_bf16(vf1, pa[0][1], o3[0], 0, 0, 0);
                o3[1] = __builtin_amdgcn_mfma_f32_16x16x32_bf16(vf0, pa[1][0], o3[1], 0, 0, 0);
                o3[1] = __builtin_amdgcn_mfma_f32_16x16x32_bf16(vf1, pa[1][1], o3[1], 0, 0, 0);
            }
        }

        __syncthreads();   // drains prefetch + protects buffer reuse
    }

    // ---- epilogue: lsum broadcast from h4==0 lanes, normalize, split hi/lo ----
#pragma unroll
    for (int set = 0; set < 2; ++set) {
        float ls = __shfl(o3[set][0], c);    // lane (c, h4=0) holds Sigma P for q=c
        float linv = 1.0f / ls;
        size_t rowoff = ((size_t)b * Nn + qb + set * 16 + c) * Cc + h * HD;
#pragma unroll
        for (int jd = 0; jd < 3; ++jd) {
            bf16x4 hv, lv;
#pragma unroll
            for (int r = 0; r < 4; ++r) {
                float val = o[set][jd][r] * linv;
                short x = f2b(val);
                hv[r] = x;
                lv[r] = f2b(val - b2f(x));
            }
            *reinterpret_cast<bf16x4*>(&aot_hi[rowoff + 16 * jd + 4 * h4]) = hv;
            *reinterpret_cast<bf16x4*>(&aot_lo[rowoff + 16 * jd + 4 * h4]) = lv;
        }
    }
}

// ---------------------------------------------------------------------------
extern "C" void kernel_launch(void* const* d_in, const int* in_sizes, int n_in,
                              void* d_out, int out_size, void* d_ws, size_t ws_size,
                              hipStream_t stream)
{
    const float* x      = (const float*)d_in[0];
    const float* w_qkv  = (const float*)d_in[1];
    const float* w_proj = (const float*)d_in[2];
    const float* b_proj = (const float*)d_in[3];
    float* out = (float*)d_out;

    short* ws = (short*)d_ws;
    const size_t XT = (size_t)Bn * Nn * Cc;            // 6291456
    short* xt_hi  = ws;
    short* xt_lo  = xt_hi + XT;
    short* wq_hi  = xt_lo + XT;
    short* wq_lo  = wq_hi + (size_t)3 * Cc * Cc;
    short* wp_hi  = wq_lo + (size_t)3 * Cc * Cc;
    short* wp_lo  = wp_hi + (size_t)Cc * Cc;
    short* qk_t   = wp_lo + (size_t)Cc * Cc;           // (B, N, 768)
    short* v_cn   = qk_t + (size_t)Bn * Nn * 768;      // (B, 384, N)
    short* aot_hi = v_cn + XT;
    short* aot_lo = aot_hi + XT;

    // 0) weight + x prep
    conv_split<<<(3 * Cc * Cc / 4 + 255) / 256, 256, 0, stream>>>(w_qkv, wq_hi, wq_lo, 3 * Cc * Cc);
    conv_split<<<(Cc * Cc / 4 + 255) / 256, 256, 0, stream>>>(w_proj, wp_hi, wp_lo, Cc * Cc);
    prep_xt<<<dim3(Nn / 64, Cc / 64, Bn), 256, 0, stream>>>(x, xt_hi, xt_lo);

    // 1) QKV GEMM (2-pass, 2-phase dbuf) -> qk_t + v_cn
    gemm_split<0><<<dim3(Nn / 128, (3 * Cc) / 128, Bn), 256, 0, stream>>>(
        wq_hi, wq_lo, xt_hi, xt_lo, qk_t, v_cn, nullptr, nullptr, 3 * Cc, Cc, Nn);

    // 2) Hybrid attention (2-phase K/V dbuf, ones-row lsum, 1024 blocks)
    attn_mfma<<<dim3(Nn / 128, NHEADS, Bn), 256, 0, stream>>>(qk_t, v_cn, aot_hi, aot_lo);

    // 3) Projection GEMM (3-pass, 2-phase dbuf, fp32 out + bias)
    gemm_split<1><<<dim3(Nn / 128, Cc / 128, Bn), 256, 0, stream>>>(
        wp_hi, wp_lo, aot_hi, aot_lo, nullptr, nullptr, out, b_proj, Cc, Cc, Nn);
}

// Round 18
// 136.073 us; speedup vs baseline: 1.2323x; 1.0087x over previous
//
#include <hip/hip_runtime.h>
#include <hip/hip_bf16.h>
#include <math.h>

// Problem constants
constexpr int Bn     = 16;    // batch
constexpr int Cc     = 384;   // channels
constexpr int Nn     = 1024;  // tokens (32*32)
constexpr int NHEADS = 8;
constexpr int HD     = 48;    // head dim
constexpr float SCALE = 0.14433756729740643f; // 48^-0.5
constexpr float SCL2  = 0.14433756729740643f * 1.4426950408889634f; // SCALE*log2(e)

using bf16x8 = __attribute__((ext_vector_type(8))) short;
using bf16x4 = __attribute__((ext_vector_type(4))) short;
using f32x4  = __attribute__((ext_vector_type(4))) float;

__device__ inline short f2b(float f) {
    __hip_bfloat16 h = __float2bfloat16(f);
    return *reinterpret_cast<short*>(&h);
}
__device__ inline float b2f(short s) {
    __hip_bfloat16 h = *reinterpret_cast<__hip_bfloat16*>(&s);
    return __bfloat162float(h);
}

// async global->LDS, 16B per lane; LDS dest = wave-uniform base + lane*16B
__device__ __forceinline__ void gload16(const short* g, short* l) {
    __builtin_amdgcn_global_load_lds(
        (const __attribute__((address_space(1))) void*)(g),
        (__attribute__((address_space(3))) void*)(l),
        16, 0, 0);
}

// ---------------------------------------------------------------------------
// Elementwise fp32 -> (hi, lo) bf16 split.
// ---------------------------------------------------------------------------
__global__ __launch_bounds__(256) void conv_split(const float* __restrict__ in,
                                                  short* __restrict__ hi,
                                                  short* __restrict__ lo, int n)
{
    int i = (blockIdx.x * 256 + threadIdx.x) * 4;
    if (i >= n) return;
    float4 v = *reinterpret_cast<const float4*>(&in[i]);
    float vs[4] = {v.x, v.y, v.z, v.w};
    bf16x4 h, l;
#pragma unroll
    for (int j = 0; j < 4; ++j) {
        h[j] = f2b(vs[j]);
        l[j] = f2b(vs[j] - b2f(h[j]));
    }
    *reinterpret_cast<bf16x4*>(&hi[i]) = h;
    *reinterpret_cast<bf16x4*>(&lo[i]) = l;
}

// ---------------------------------------------------------------------------
// x (B, C, N) fp32 -> x^T (B, N, C) bf16 hi/lo.  64x64 tile via LDS.
// ---------------------------------------------------------------------------
__global__ __launch_bounds__(256) void prep_xt(const float* __restrict__ x,
                                               short* __restrict__ xt_hi,
                                               short* __restrict__ xt_lo)
{
    const int b  = blockIdx.z;
    const int c0 = blockIdx.y * 64;
    const int n0 = blockIdx.x * 64;
    __shared__ float T[64 * 68];

    const int tid = threadIdx.x;
    const int r   = tid >> 2;
    const int seg = tid & 3;

    const float* xb = x + ((size_t)b * Cc + c0) * Nn;
#pragma unroll
    for (int i = 0; i < 4; ++i) {
        float4 v = *reinterpret_cast<const float4*>(&xb[(size_t)r * Nn + n0 + seg * 16 + i * 4]);
        *reinterpret_cast<float4*>(&T[r * 68 + seg * 16 + i * 4]) = v;
    }
    __syncthreads();

    short* oh = xt_hi + ((size_t)b * Nn + n0 + r) * Cc + c0;
    short* ol = xt_lo + ((size_t)b * Nn + n0 + r) * Cc + c0;
#pragma unroll
    for (int i = 0; i < 4; ++i) {
        bf16x4 hv, lv;
#pragma unroll
        for (int j = 0; j < 4; ++j) {
            float v = T[(seg * 16 + i * 4 + j) * 68 + r];
            hv[j] = f2b(v);
            lv[j] = f2b(v - b2f(hv[j]));
        }
        *reinterpret_cast<bf16x4*>(&oh[seg * 16 + i * 4]) = hv;
        *reinterpret_cast<bf16x4*>(&ol[seg * 16 + i * 4]) = lv;
    }
}

// ---------------------------------------------------------------------------
// Split-bf16 MFMA GEMM, 2-phase LDS double-buffer, global_load_lds staging.
// MODE 0 (QKV): 2-pass  y = Whi*Xhi + Whi*Xlo.  48 KB LDS.
// MODE 1 (PROJ): 3-pass; fp32 out + bias.  64 KB LDS.   (unchanged)
// ---------------------------------------------------------------------------
template <int MODE>
__global__ __launch_bounds__(256) void gemm_split(const short* __restrict__ Whi,
                                                  const short* __restrict__ Wlo,
                                                  const short* __restrict__ Xhi,
                                                  const short* __restrict__ Xlo,
                                                  short* __restrict__ Yqk,
                                                  short* __restrict__ Yv,
                                                  float* __restrict__ Yf,
                                                  const float* __restrict__ bias,
                                                  int M, int K, int NN)
{
    const int b  = blockIdx.z;
    const int m0 = blockIdx.y * 128;
    const int n0 = blockIdx.x * 128;
    const short* Xb_hi = Xhi + (size_t)b * NN * K;
    const short* Xb_lo = Xlo + (size_t)b * NN * K;

    constexpr int BUFS = (MODE == 0) ? 12288 : 16384;   // shorts per buffer
    constexpr int OAhi = 0;
    constexpr int OAlo = 4096;                          // MODE 1 only
    constexpr int OBhi = (MODE == 0) ? 4096 : 8192;
    constexpr int OBlo = (MODE == 0) ? 8192 : 12288;
    __shared__ __align__(16) short smem[(MODE == 0) ? 24576 : 32768];

    const int tid  = threadIdx.x;
    const int lane = tid & 63;
    const int wave = tid >> 6;
    const int c    = lane & 15;
    const int h4   = lane >> 4;
    const int wr   = wave >> 1;
    const int wc   = wave & 1;

    const int sq   = ((tid & 3) ^ ((tid >> 3) & 3)) * 8;  // swizzled src chunk
    const int lds0 = wave * 512;                          // shorts, per tile
    const int lds1 = 2048 + wave * 512;

    const short* gWhi = Whi + (size_t)(m0 + (tid >> 2)) * K + sq;
    const short* gWlo = Wlo + (size_t)(m0 + (tid >> 2)) * K + sq;
    const short* gXhi = Xb_hi + (size_t)(n0 + (tid >> 2)) * K + sq;
    const short* gXlo = Xb_lo + (size_t)(n0 + (tid >> 2)) * K + sq;
    const size_t rowskip = (size_t)64 * K;

    const int sw = (h4 ^ ((c >> 1) & 3)) * 8;             // frag-read swizzle

    f32x4 acc[4][4];
#pragma unroll
    for (int mi = 0; mi < 4; ++mi)
#pragma unroll
        for (int ni = 0; ni < 4; ++ni) acc[mi][ni] = 0.0f;

    // ---- prologue: stage tile 0 into buffer 0 ----
    {
        short* buf = smem;
        gload16(gWhi,           buf + OAhi + lds0);
        gload16(gWhi + rowskip, buf + OAhi + lds1);
        if constexpr (MODE == 1) {
            gload16(gWlo,           buf + OAlo + lds0);
            gload16(gWlo + rowskip, buf + OAlo + lds1);
        }
        gload16(gXhi,           buf + OBhi + lds0);
        gload16(gXhi + rowskip, buf + OBhi + lds1);
        gload16(gXlo,           buf + OBlo + lds0);
        gload16(gXlo + rowskip, buf + OBlo + lds1);
    }
    __syncthreads();

    const int NT = K >> 5;   // 12
    for (int t = 0; t < NT; ++t) {
        short* cbuf = smem + (t & 1) * BUFS;

        // prefetch next tile into the other buffer FIRST
        if (t + 1 < NT) {
            short* nbuf = smem + ((t + 1) & 1) * BUFS;
            const int nk = (t + 1) * 32;
            gload16(gWhi + nk,           nbuf + OAhi + lds0);
            gload16(gWhi + rowskip + nk, nbuf + OAhi + lds1);
            if constexpr (MODE == 1) {
                gload16(gWlo + nk,           nbuf + OAlo + lds0);
                gload16(gWlo + rowskip + nk, nbuf + OAlo + lds1);
            }
            gload16(gXhi + nk,           nbuf + OBhi + lds0);
            gload16(gXhi + rowskip + nk, nbuf + OBhi + lds1);
            gload16(gXlo + nk,           nbuf + OBlo + lds0);
            gload16(gXlo + rowskip + nk, nbuf + OBlo + lds1);
        }

        bf16x8 a_hi[4], a_lo[4], b_hi[4], b_lo[4];
#pragma unroll
        for (int mi = 0; mi < 4; ++mi) {
            int row = wr * 64 + mi * 16 + c;
            a_hi[mi] = *reinterpret_cast<const bf16x8*>(&cbuf[OAhi + row * 32 + sw]);
            if constexpr (MODE == 1)
                a_lo[mi] = *reinterpret_cast<const bf16x8*>(&cbuf[OAlo + row * 32 + sw]);
        }
#pragma unroll
        for (int ni = 0; ni < 4; ++ni) {
            int row = wc * 64 + ni * 16 + c;
            b_hi[ni] = *reinterpret_cast<const bf16x8*>(&cbuf[OBhi + row * 32 + sw]);
            b_lo[ni] = *reinterpret_cast<const bf16x8*>(&cbuf[OBlo + row * 32 + sw]);
        }
#pragma unroll
        for (int mi = 0; mi < 4; ++mi)
#pragma unroll
            for (int ni = 0; ni < 4; ++ni) {
                acc[mi][ni] = __builtin_amdgcn_mfma_f32_16x16x32_bf16(a_hi[mi], b_hi[ni], acc[mi][ni], 0, 0, 0);
                acc[mi][ni] = __builtin_amdgcn_mfma_f32_16x16x32_bf16(a_hi[mi], b_lo[ni], acc[mi][ni], 0, 0, 0);
                if constexpr (MODE == 1)
                    acc[mi][ni] = __builtin_amdgcn_mfma_f32_16x16x32_bf16(a_lo[mi], b_hi[ni], acc[mi][ni], 0, 0, 0);
            }

        __syncthreads();   // drains prefetch loads + protects buffer reuse
    }

    if (MODE == 0) {
        if (m0 < 768) {
            const float qscale = (m0 < 384) ? SCL2 : 1.0f;
            short* Cs = smem;  // [128 n][136]
#pragma unroll
            for (int mi = 0; mi < 4; ++mi)
#pragma unroll
                for (int ni = 0; ni < 4; ++ni) {
                    int nl = wc * 64 + ni * 16 + c;
                    int cl = wr * 64 + mi * 16 + 4 * h4;
                    bf16x4 pk;
#pragma unroll
                    for (int r = 0; r < 4; ++r) pk[r] = f2b(acc[mi][ni][r] * qscale);
                    *reinterpret_cast<bf16x4*>(&Cs[nl * 136 + cl]) = pk;
                }
            __syncthreads();
#pragma unroll
            for (int l = 0; l < 8; ++l) {
                int u  = tid + l * 256;
                int nl = u >> 4, ch = u & 15;
                *reinterpret_cast<bf16x8*>(&Yqk[((size_t)b * NN + n0 + nl) * 768 + m0 + ch * 8]) =
                    *reinterpret_cast<const bf16x8*>(&Cs[nl * 136 + ch * 8]);
            }
        } else {
            short* Cs = smem;  // [128 ch][136]
#pragma unroll
            for (int mi = 0; mi < 4; ++mi)
#pragma unroll
                for (int ni = 0; ni < 4; ++ni)
#pragma unroll
                    for (int r = 0; r < 4; ++r) {
                        int ml = wr * 64 + mi * 16 + h4 * 4 + r;
                        int nl = wc * 64 + ni * 16 + c;
                        Cs[ml * 136 + nl] = f2b(acc[mi][ni][r]);
                    }
            __syncthreads();
            short* Yb = Yv + (size_t)b * Cc * NN;
            const int srow2 = tid >> 1;
            const int cseg  = (tid & 1) * 64;
#pragma unroll
            for (int i = 0; i < 8; ++i)
                *reinterpret_cast<bf16x8*>(&Yb[(size_t)(m0 - 768 + srow2) * NN + n0 + cseg + i * 8]) =
                    *reinterpret_cast<const bf16x8*>(&Cs[srow2 * 136 + cseg + i * 8]);
        }
    } else {
        float* Yb = Yf + (size_t)b * M * NN;
        float* Cf = reinterpret_cast<float*>(smem);
        const int mr2 = tid >> 2;
        const int seg = tid & 3;
#pragma unroll
        for (int half = 0; half < 2; ++half) {
            __syncthreads();
            if (wr == half) {
#pragma unroll
                for (int mi = 0; mi < 4; ++mi)
#pragma unroll
                    for (int ni = 0; ni < 4; ++ni)
#pragma unroll
                        for (int r = 0; r < 4; ++r) {
                            int ml = mi * 16 + h4 * 4 + r;
                            int nl = wc * 64 + ni * 16 + c;
                            Cf[ml * 132 + nl] = acc[mi][ni][r];
                        }
            }
            __syncthreads();
            float bv = bias ? bias[m0 + half * 64 + mr2] : 0.0f;
#pragma unroll
            for (int i = 0; i < 8; ++i) {
                float4 v = *reinterpret_cast<const float4*>(&Cf[mr2 * 132 + seg * 32 + i * 4]);
                v.x += bv; v.y += bv; v.z += bv; v.w += bv;
                *reinterpret_cast<float4*>(&Yb[(size_t)(m0 + half * 64 + mr2) * NN + n0 + seg * 32 + i * 4]) = v;
            }
        }
    }
}

// ---------------------------------------------------------------------------
// Hybrid MFMA flash attention, global_load_lds staging, 2-phase K/V dbuf,
// ones-row lsum.  NEW: XCD-aware 1D block remap — all 8 q-tile blocks of a
// given (b,h) land on the same XCD (round-robin id%8), so that (b,h)'s K/V
// (192 KB) is fetched from HBM once per XCD and then L2-resident (16 bh x
// 192 KB = 3 MB < 4 MB per-XCD L2).  Bijective remap -> correctness-neutral.
// ---------------------------------------------------------------------------
__global__ __launch_bounds__(256, 4) void attn_mfma(const short* __restrict__ qk_t,
                                                    const short* __restrict__ v_cn,
                                                    short* __restrict__ aot_hi,
                                                    short* __restrict__ aot_lo)
{
    // XCD-aware decode: id%8 selects XCD under round-robin dispatch.
    const int id = blockIdx.x;           // 0..1023
    const int rx = id & 7;
    const int kk = id >> 3;              // 0..127
    const int bh = rx * 16 + (kk & 15);  // 0..127, constant per XCD group
    const int qt = kk >> 4;              // 0..7
    const int b  = bh >> 3;
    const int h  = bh & 7;
    const int n0 = qt * 128;

    __shared__ __align__(16) short smem[16384];  // 2 x (Ks 4096 + Vs 4096)

    const int tid  = threadIdx.x;
    const int lane = tid & 63;
    const int wave = tid >> 6;
    const int c    = lane & 15;
    const int h4   = lane >> 4;
    const int qb   = n0 + wave * 32;

    const short* Qb    = qk_t + ((size_t)b * Nn + qb) * 768 + h * HD;
    const short* Kbase = qk_t + (size_t)b * Nn * 768 + 384 + h * HD;
    const short* Vb    = v_cn + ((size_t)b * Cc + h * HD) * Nn;

    const bf16x8 z8 = {};

    // init Vs rows 48..63 in BOTH buffers: row 48 = 1.0, rows 49..63 = 0
    {
        int i0 = tid * 4;                       // 0..1023
        short v = (i0 < 64) ? (short)0x3F80 : (short)0;
        bf16x4 iv = {v, v, v, v};
        *reinterpret_cast<bf16x4*>(&smem[4096 + 3072 + i0]) = iv;
        *reinterpret_cast<bf16x4*>(&smem[12288 + 3072 + i0]) = iv;
    }

    // ---- Q fragments (loop-invariant, 2 sets) ----
    bf16x8 qf0[2], qf1[2];
#pragma unroll
    for (int s = 0; s < 2; ++s) {
        const short* qrow = Qb + (size_t)(s * 16 + c) * 768;
        qf0[s] = *reinterpret_cast<const bf16x8*>(qrow + 8 * h4);
        qf1[s] = (h4 < 2) ? *reinterpret_cast<const bf16x8*>(qrow + 32 + 8 * h4) : z8;
    }

    const int u0 = wave * 64 + lane;
    const int r0 = u0 >> 3;
    const int sc0 = ((u0 & 7) ^ (r0 & 7)) * 8;
    const int u1 = 256 + u0;
    const int r1 = u1 >> 3;
    const int sc1 = ((u1 & 7) ^ (r1 & 7)) * 8;

    const int cs8 = c & 7;
    const int ks0 = (h4 ^ cs8) * 8;
    const int ks1 = ((4 + h4) ^ cs8) * 8;
    const int hh  = h4 >> 1;
    const int hb  = (h4 & 1) * 4;
    const int vs00 = ((0 + hh) ^ cs8) * 8 + hb;
    const int vs01 = ((2 + hh) ^ cs8) * 8 + hb;
    const int vs10 = ((4 + hh) ^ cs8) * 8 + hb;
    const int vs11 = ((6 + hh) ^ cs8) * 8 + hb;

    f32x4 o[2][3];
#pragma unroll
    for (int s = 0; s < 2; ++s)
#pragma unroll
        for (int jd = 0; jd < 3; ++jd) o[s][jd] = 0.0f;
    f32x4 o3[2];
    o3[0] = 0.0f; o3[1] = 0.0f;

    // ---- prologue: stage tile 0 into buffer 0 ----
    {
        short* Ksb = smem;
        short* Vsb = smem + 4096;
        gload16(Kbase + (size_t)r0 * 768 + sc0, Ksb + wave * 512);
        gload16(Kbase + (size_t)r1 * 768 + sc1, Ksb + 2048 + wave * 512);
        gload16(Vb + (size_t)r0 * Nn + sc0, Vsb + wave * 512);
        if (wave < 2)
            gload16(Vb + (size_t)r1 * Nn + sc1, Vsb + 2048 + wave * 512);
    }
    __syncthreads();

    for (int t = 0; t < 16; ++t) {
        const short* Ks = smem + (t & 1) * 8192;
        const short* Vs = Ks + 4096;

        // prefetch next tile into the other buffer FIRST
        if (t + 1 < 16) {
            short* Ksn = smem + ((t + 1) & 1) * 8192;
            short* Vsn = Ksn + 4096;
            const int mn = (t + 1) * 64;
            gload16(Kbase + (size_t)(mn + r0) * 768 + sc0, Ksn + wave * 512);
            gload16(Kbase + (size_t)(mn + r1) * 768 + sc1, Ksn + 2048 + wave * 512);
            gload16(Vb + (size_t)r0 * Nn + mn + sc0, Vsn + wave * 512);
            if (wave < 2)
                gload16(Vb + (size_t)r1 * Nn + mn + sc1, Vsn + 2048 + wave * 512);
        }

        // ---- QK^T (K frags shared by both sets) ----
        f32x4 s4a[4], s4b[4];
#pragma unroll
        for (int j = 0; j < 4; ++j) { s4a[j] = 0.0f; s4b[j] = 0.0f; }
#pragma unroll
        for (int j = 0; j < 4; ++j) {
            int kr = (16 * j + c) * 64;
            bf16x8 kc0 = *reinterpret_cast<const bf16x8*>(&Ks[kr + ks0]);
            bf16x8 kc1 = *reinterpret_cast<const bf16x8*>(&Ks[kr + ks1]);
            s4a[j] = __builtin_amdgcn_mfma_f32_16x16x32_bf16(kc0, qf0[0], s4a[j], 0, 0, 0);
            s4a[j] = __builtin_amdgcn_mfma_f32_16x16x32_bf16(kc1, qf1[0], s4a[j], 0, 0, 0);
            s4b[j] = __builtin_amdgcn_mfma_f32_16x16x32_bf16(kc0, qf0[1], s4b[j], 0, 0, 0);
            s4b[j] = __builtin_amdgcn_mfma_f32_16x16x32_bf16(kc1, qf1[1], s4b[j], 0, 0, 0);
        }

        // ---- softmax-lite + pack P (sigma order), both sets ----
        bf16x8 pa[2][2];
        {
            float p[4][4];
#pragma unroll
            for (int j = 0; j < 4; ++j)
#pragma unroll
                for (int r = 0; r < 4; ++r)
                    p[j][r] = exp2f(s4a[j][r]);
#pragma unroll
            for (int r = 0; r < 4; ++r) {
                pa[0][0][r]     = f2b(p[0][r]);
                pa[0][0][4 + r] = f2b(p[1][r]);
                pa[0][1][r]     = f2b(p[2][r]);
                pa[0][1][4 + r] = f2b(p[3][r]);
            }
        }
        {
            float p[4][4];
#pragma unroll
            for (int j = 0; j < 4; ++j)
#pragma unroll
                for (int r = 0; r < 4; ++r)
                    p[j][r] = exp2f(s4b[j][r]);
#pragma unroll
            for (int r = 0; r < 4; ++r) {
                pa[1][0][r]     = f2b(p[0][r]);
                pa[1][0][4 + r] = f2b(p[1][r]);
                pa[1][1][r]     = f2b(p[2][r]);
                pa[1][1][4 + r] = f2b(p[3][r]);
            }
        }

        // ---- PV (jd 0..2) + ones-row lsum (jd 3) ----
#pragma unroll
        for (int jd = 0; jd < 4; ++jd) {
            int vr = (16 * jd + c) * 64;
            bf16x4 a0 = *reinterpret_cast<const bf16x4*>(&Vs[vr + vs00]);
            bf16x4 d0 = *reinterpret_cast<const bf16x4*>(&Vs[vr + vs01]);
            bf16x4 a1 = *reinterpret_cast<const bf16x4*>(&Vs[vr + vs10]);
            bf16x4 d1 = *reinterpret_cast<const bf16x4*>(&Vs[vr + vs11]);
            bf16x8 vf0, vf1;
#pragma unroll
            for (int r = 0; r < 4; ++r) {
                vf0[r] = a0[r]; vf0[4 + r] = d0[r];
                vf1[r] = a1[r]; vf1[4 + r] = d1[r];
            }
            if (jd < 3) {
                o[0][jd] = __builtin_amdgcn_mfma_f32_16x16x32_bf16(vf0, pa[0][0], o[0][jd], 0, 0, 0);
                o[0][jd] = __builtin_amdgcn_mfma_f32_16x16x32_bf16(vf1, pa[0][1], o[0][jd], 0, 0, 0);
                o[1][jd] = __builtin_amdgcn_mfma_f32_16x16x32_bf16(vf0, pa[1][0], o[1][jd], 0, 0, 0);
                o[1][jd] = __builtin_amdgcn_mfma_f32_16x16x32_bf16(vf1, pa[1][1], o[1][jd], 0, 0, 0);
            } else {
                o3[0] = __builtin_amdgcn_mfma_f32_16x16x32_bf16(vf0, pa[0][0], o3[0], 0, 0, 0);
                o3[0] = __builtin_amdgcn_mfma_f32_16x16x32_bf16(vf1, pa[0][1], o3[0], 0, 0, 0);
                o3[1] = __builtin_amdgcn_mfma_f32_16x16x32_bf16(vf0, pa[1][0], o3[1], 0, 0, 0);
                o3[1] = __builtin_amdgcn_mfma_f32_16x16x32_bf16(vf1, pa[1][1], o3[1], 0, 0, 0);
            }
        }

        __syncthreads();   // drains prefetch + protects buffer reuse
    }

    // ---- epilogue: lsum broadcast from h4==0 lanes, normalize, split hi/lo ----
#pragma unroll
    for (int set = 0; set < 2; ++set) {
        float ls = __shfl(o3[set][0], c);    // lane (c, h4=0) holds Sigma P for q=c
        float linv = 1.0f / ls;
        size_t rowoff = ((size_t)b * Nn + qb + set * 16 + c) * Cc + h * HD;
#pragma unroll
        for (int jd = 0; jd < 3; ++jd) {
            bf16x4 hv, lv;
#pragma unroll
            for (int r = 0; r < 4; ++r) {
                float val = o[set][jd][r] * linv;
                short x = f2b(val);
                hv[r] = x;
                lv[r] = f2b(val - b2f(x));
            }
            *reinterpret_cast<bf16x4*>(&aot_hi[rowoff + 16 * jd + 4 * h4]) = hv;
            *reinterpret_cast<bf16x4*>(&aot_lo[rowoff + 16 * jd + 4 * h4]) = lv;
        }
    }
}

// ---------------------------------------------------------------------------
extern "C" void kernel_launch(void* const* d_in, const int* in_sizes, int n_in,
                              void* d_out, int out_size, void* d_ws, size_t ws_size,
                              hipStream_t stream)
{
    const float* x      = (const float*)d_in[0];
    const float* w_qkv  = (const float*)d_in[1];
    const float* w_proj = (const float*)d_in[2];
    const float* b_proj = (const float*)d_in[3];
    float* out = (float*)d_out;

    short* ws = (short*)d_ws;
    const size_t XT = (size_t)Bn * Nn * Cc;            // 6291456
    short* xt_hi  = ws;
    short* xt_lo  = xt_hi + XT;
    short* wq_hi  = xt_lo + XT;
    short* wq_lo  = wq_hi + (size_t)3 * Cc * Cc;
    short* wp_hi  = wq_lo + (size_t)3 * Cc * Cc;
    short* wp_lo  = wp_hi + (size_t)Cc * Cc;
    short* qk_t   = wp_lo + (size_t)Cc * Cc;           // (B, N, 768)
    short* v_cn   = qk_t + (size_t)Bn * Nn * 768;      // (B, 384, N)
    short* aot_hi = v_cn + XT;
    short* aot_lo = aot_hi + XT;

    // 0) weight + x prep
    conv_split<<<(3 * Cc * Cc / 4 + 255) / 256, 256, 0, stream>>>(w_qkv, wq_hi, wq_lo, 3 * Cc * Cc);
    conv_split<<<(Cc * Cc / 4 + 255) / 256, 256, 0, stream>>>(w_proj, wp_hi, wp_lo, Cc * Cc);
    prep_xt<<<dim3(Nn / 64, Cc / 64, Bn), 256, 0, stream>>>(x, xt_hi, xt_lo);

    // 1) QKV GEMM (2-pass, 2-phase dbuf) -> qk_t + v_cn
    gemm_split<0><<<dim3(Nn / 128, (3 * Cc) / 128, Bn), 256, 0, stream>>>(
        wq_hi, wq_lo, xt_hi, xt_lo, qk_t, v_cn, nullptr, nullptr, 3 * Cc, Cc, Nn);

    // 2) Hybrid attention (XCD-aware 1D remap, 2-phase K/V dbuf, ones-row lsum)
    attn_mfma<<<1024, 256, 0, stream>>>(qk_t, v_cn, aot_hi, aot_lo);

    // 3) Projection GEMM (3-pass, 2-phase dbuf, fp32 out + bias)
    gemm_split<1><<<dim3(Nn / 128, Cc / 128, Bn), 256, 0, stream>>>(
        wp_hi, wp_lo, aot_hi, aot_lo, nullptr, nullptr, out, b_proj, Cc, Cc, Nn);
}

// Round 19
// 133.379 us; speedup vs baseline: 1.2571x; 1.0202x over previous
//
#include <hip/hip_runtime.h>
#include <hip/hip_bf16.h>
#include <math.h>

// Problem constants
constexpr int Bn     = 16;    // batch
constexpr int Cc     = 384;   // channels
constexpr int Nn     = 1024;  // tokens (32*32)
constexpr int NHEADS = 8;
constexpr int HD     = 48;    // head dim
constexpr float SCALE = 0.14433756729740643f; // 48^-0.5
constexpr float SCL2  = 0.14433756729740643f * 1.4426950408889634f; // SCALE*log2(e)

using bf16x8 = __attribute__((ext_vector_type(8))) short;
using bf16x4 = __attribute__((ext_vector_type(4))) short;
using f32x4  = __attribute__((ext_vector_type(4))) float;

__device__ inline short f2b(float f) {
    __hip_bfloat16 h = __float2bfloat16(f);
    return *reinterpret_cast<short*>(&h);
}
__device__ inline float b2f(short s) {
    __hip_bfloat16 h = *reinterpret_cast<__hip_bfloat16*>(&s);
    return __bfloat162float(h);
}

// async global->LDS, 16B per lane; LDS dest = wave-uniform base + lane*16B
__device__ __forceinline__ void gload16(const short* g, short* l) {
    __builtin_amdgcn_global_load_lds(
        (const __attribute__((address_space(1))) void*)(g),
        (__attribute__((address_space(3))) void*)(l),
        16, 0, 0);
}

// ---------------------------------------------------------------------------
// Elementwise fp32 -> (hi, lo) bf16 split.
// ---------------------------------------------------------------------------
__global__ __launch_bounds__(256) void conv_split(const float* __restrict__ in,
                                                  short* __restrict__ hi,
                                                  short* __restrict__ lo, int n)
{
    int i = (blockIdx.x * 256 + threadIdx.x) * 4;
    if (i >= n) return;
    float4 v = *reinterpret_cast<const float4*>(&in[i]);
    float vs[4] = {v.x, v.y, v.z, v.w};
    bf16x4 h, l;
#pragma unroll
    for (int j = 0; j < 4; ++j) {
        h[j] = f2b(vs[j]);
        l[j] = f2b(vs[j] - b2f(h[j]));
    }
    *reinterpret_cast<bf16x4*>(&hi[i]) = h;
    *reinterpret_cast<bf16x4*>(&lo[i]) = l;
}

// ---------------------------------------------------------------------------
// x (B, C, N) fp32 -> x^T (B, N, C) bf16 hi/lo.  64x64 tile via LDS.
// ---------------------------------------------------------------------------
__global__ __launch_bounds__(256) void prep_xt(const float* __restrict__ x,
                                               short* __restrict__ xt_hi,
                                               short* __restrict__ xt_lo)
{
    const int b  = blockIdx.z;
    const int c0 = blockIdx.y * 64;
    const int n0 = blockIdx.x * 64;
    __shared__ float T[64 * 68];

    const int tid = threadIdx.x;
    const int r   = tid >> 2;
    const int seg = tid & 3;

    const float* xb = x + ((size_t)b * Cc + c0) * Nn;
#pragma unroll
    for (int i = 0; i < 4; ++i) {
        float4 v = *reinterpret_cast<const float4*>(&xb[(size_t)r * Nn + n0 + seg * 16 + i * 4]);
        *reinterpret_cast<float4*>(&T[r * 68 + seg * 16 + i * 4]) = v;
    }
    __syncthreads();

    short* oh = xt_hi + ((size_t)b * Nn + n0 + r) * Cc + c0;
    short* ol = xt_lo + ((size_t)b * Nn + n0 + r) * Cc + c0;
#pragma unroll
    for (int i = 0; i < 4; ++i) {
        bf16x4 hv, lv;
#pragma unroll
        for (int j = 0; j < 4; ++j) {
            float v = T[(seg * 16 + i * 4 + j) * 68 + r];
            hv[j] = f2b(v);
            lv[j] = f2b(v - b2f(hv[j]));
        }
        *reinterpret_cast<bf16x4*>(&oh[seg * 16 + i * 4]) = hv;
        *reinterpret_cast<bf16x4*>(&ol[seg * 16 + i * 4]) = lv;
    }
}

// ---------------------------------------------------------------------------
// Split-bf16 MFMA GEMM, 2-phase LDS double-buffer, global_load_lds staging.
// MODE 0 (QKV): 2-pass  y = Whi*Xhi + Whi*Xlo.  48 KB LDS.
//   m<768 -> Yqk token-major (B,N,768) bf16 (Q pre-scaled by SCL2);
//   m>=768 -> Yv (B,384,N) bf16 with columns SIGMA-PERMUTED within each
//   64-n group (np = 32(ni>>1)+8(c>>2)+4(ni&1)+(c&3)) so attention's PV
//   A-fragment is a single conflict-free b128 LDS read.
// MODE 1 (PROJ): 3-pass; fp32 out + bias.  64 KB LDS.
// ---------------------------------------------------------------------------
template <int MODE>
__global__ __launch_bounds__(256) void gemm_split(const short* __restrict__ Whi,
                                                  const short* __restrict__ Wlo,
                                                  const short* __restrict__ Xhi,
                                                  const short* __restrict__ Xlo,
                                                  short* __restrict__ Yqk,
                                                  short* __restrict__ Yv,
                                                  float* __restrict__ Yf,
                                                  const float* __restrict__ bias,
                                                  int M, int K, int NN)
{
    const int b  = blockIdx.z;
    const int m0 = blockIdx.y * 128;
    const int n0 = blockIdx.x * 128;
    const short* Xb_hi = Xhi + (size_t)b * NN * K;
    const short* Xb_lo = Xlo + (size_t)b * NN * K;

    constexpr int BUFS = (MODE == 0) ? 12288 : 16384;   // shorts per buffer
    constexpr int OAhi = 0;
    constexpr int OAlo = 4096;                          // MODE 1 only
    constexpr int OBhi = (MODE == 0) ? 4096 : 8192;
    constexpr int OBlo = (MODE == 0) ? 8192 : 12288;
    __shared__ __align__(16) short smem[(MODE == 0) ? 24576 : 32768];

    const int tid  = threadIdx.x;
    const int lane = tid & 63;
    const int wave = tid >> 6;
    const int c    = lane & 15;
    const int h4   = lane >> 4;
    const int wr   = wave >> 1;
    const int wc   = wave & 1;

    const int sq   = ((tid & 3) ^ ((tid >> 3) & 3)) * 8;  // swizzled src chunk
    const int lds0 = wave * 512;                          // shorts, per tile
    const int lds1 = 2048 + wave * 512;

    const short* gWhi = Whi + (size_t)(m0 + (tid >> 2)) * K + sq;
    const short* gWlo = Wlo + (size_t)(m0 + (tid >> 2)) * K + sq;
    const short* gXhi = Xb_hi + (size_t)(n0 + (tid >> 2)) * K + sq;
    const short* gXlo = Xb_lo + (size_t)(n0 + (tid >> 2)) * K + sq;
    const size_t rowskip = (size_t)64 * K;

    const int sw = (h4 ^ ((c >> 1) & 3)) * 8;             // frag-read swizzle

    f32x4 acc[4][4];
#pragma unroll
    for (int mi = 0; mi < 4; ++mi)
#pragma unroll
        for (int ni = 0; ni < 4; ++ni) acc[mi][ni] = 0.0f;

    // ---- prologue: stage tile 0 into buffer 0 ----
    {
        short* buf = smem;
        gload16(gWhi,           buf + OAhi + lds0);
        gload16(gWhi + rowskip, buf + OAhi + lds1);
        if constexpr (MODE == 1) {
            gload16(gWlo,           buf + OAlo + lds0);
            gload16(gWlo + rowskip, buf + OAlo + lds1);
        }
        gload16(gXhi,           buf + OBhi + lds0);
        gload16(gXhi + rowskip, buf + OBhi + lds1);
        gload16(gXlo,           buf + OBlo + lds0);
        gload16(gXlo + rowskip, buf + OBlo + lds1);
    }
    __syncthreads();

    const int NT = K >> 5;   // 12
    for (int t = 0; t < NT; ++t) {
        short* cbuf = smem + (t & 1) * BUFS;

        // prefetch next tile into the other buffer FIRST
        if (t + 1 < NT) {
            short* nbuf = smem + ((t + 1) & 1) * BUFS;
            const int nk = (t + 1) * 32;
            gload16(gWhi + nk,           nbuf + OAhi + lds0);
            gload16(gWhi + rowskip + nk, nbuf + OAhi + lds1);
            if constexpr (MODE == 1) {
                gload16(gWlo + nk,           nbuf + OAlo + lds0);
                gload16(gWlo + rowskip + nk, nbuf + OAlo + lds1);
            }
            gload16(gXhi + nk,           nbuf + OBhi + lds0);
            gload16(gXhi + rowskip + nk, nbuf + OBhi + lds1);
            gload16(gXlo + nk,           nbuf + OBlo + lds0);
            gload16(gXlo + rowskip + nk, nbuf + OBlo + lds1);
        }

        bf16x8 a_hi[4], a_lo[4], b_hi[4], b_lo[4];
#pragma unroll
        for (int mi = 0; mi < 4; ++mi) {
            int row = wr * 64 + mi * 16 + c;
            a_hi[mi] = *reinterpret_cast<const bf16x8*>(&cbuf[OAhi + row * 32 + sw]);
            if constexpr (MODE == 1)
                a_lo[mi] = *reinterpret_cast<const bf16x8*>(&cbuf[OAlo + row * 32 + sw]);
        }
#pragma unroll
        for (int ni = 0; ni < 4; ++ni) {
            int row = wc * 64 + ni * 16 + c;
            b_hi[ni] = *reinterpret_cast<const bf16x8*>(&cbuf[OBhi + row * 32 + sw]);
            b_lo[ni] = *reinterpret_cast<const bf16x8*>(&cbuf[OBlo + row * 32 + sw]);
        }
#pragma unroll
        for (int mi = 0; mi < 4; ++mi)
#pragma unroll
            for (int ni = 0; ni < 4; ++ni) {
                acc[mi][ni] = __builtin_amdgcn_mfma_f32_16x16x32_bf16(a_hi[mi], b_hi[ni], acc[mi][ni], 0, 0, 0);
                acc[mi][ni] = __builtin_amdgcn_mfma_f32_16x16x32_bf16(a_hi[mi], b_lo[ni], acc[mi][ni], 0, 0, 0);
                if constexpr (MODE == 1)
                    acc[mi][ni] = __builtin_amdgcn_mfma_f32_16x16x32_bf16(a_lo[mi], b_hi[ni], acc[mi][ni], 0, 0, 0);
            }

        __syncthreads();   // drains prefetch loads + protects buffer reuse
    }

    if (MODE == 0) {
        if (m0 < 768) {
            const float qscale = (m0 < 384) ? SCL2 : 1.0f;
            short* Cs = smem;  // [128 n][136]
#pragma unroll
            for (int mi = 0; mi < 4; ++mi)
#pragma unroll
                for (int ni = 0; ni < 4; ++ni) {
                    int nl = wc * 64 + ni * 16 + c;
                    int cl = wr * 64 + mi * 16 + 4 * h4;
                    bf16x4 pk;
#pragma unroll
                    for (int r = 0; r < 4; ++r) pk[r] = f2b(acc[mi][ni][r] * qscale);
                    *reinterpret_cast<bf16x4*>(&Cs[nl * 136 + cl]) = pk;
                }
            __syncthreads();
#pragma unroll
            for (int l = 0; l < 8; ++l) {
                int u  = tid + l * 256;
                int nl = u >> 4, ch = u & 15;
                *reinterpret_cast<bf16x8*>(&Yqk[((size_t)b * NN + n0 + nl) * 768 + m0 + ch * 8]) =
                    *reinterpret_cast<const bf16x8*>(&Cs[nl * 136 + ch * 8]);
            }
        } else {
            // V: channel-major bf16 out (d, n), columns sigma-permuted per
            // 64-n group so PV A-frag = single b128 LDS read in attention.
            short* Cs = smem;  // [128 ch][136]
#pragma unroll
            for (int mi = 0; mi < 4; ++mi)
#pragma unroll
                for (int ni = 0; ni < 4; ++ni) {
                    int npb = wc * 64 + 32 * (ni >> 1) + 8 * (c >> 2) + 4 * (ni & 1) + (c & 3);
#pragma unroll
                    for (int r = 0; r < 4; ++r) {
                        int ml = wr * 64 + mi * 16 + h4 * 4 + r;
                        Cs[ml * 136 + npb] = f2b(acc[mi][ni][r]);
                    }
                }
            __syncthreads();
            short* Yb = Yv + (size_t)b * Cc * NN;
            const int srow2 = tid >> 1;
            const int cseg  = (tid & 1) * 64;
#pragma unroll
            for (int i = 0; i < 8; ++i)
                *reinterpret_cast<bf16x8*>(&Yb[(size_t)(m0 - 768 + srow2) * NN + n0 + cseg + i * 8]) =
                    *reinterpret_cast<const bf16x8*>(&Cs[srow2 * 136 + cseg + i * 8]);
        }
    } else {
        float* Yb = Yf + (size_t)b * M * NN;
        float* Cf = reinterpret_cast<float*>(smem);
        const int mr2 = tid >> 2;
        const int seg = tid & 3;
#pragma unroll
        for (int half = 0; half < 2; ++half) {
            __syncthreads();
            if (wr == half) {
#pragma unroll
                for (int mi = 0; mi < 4; ++mi)
#pragma unroll
                    for (int ni = 0; ni < 4; ++ni)
#pragma unroll
                        for (int r = 0; r < 4; ++r) {
                            int ml = mi * 16 + h4 * 4 + r;
                            int nl = wc * 64 + ni * 16 + c;
                            Cf[ml * 132 + nl] = acc[mi][ni][r];
                        }
            }
            __syncthreads();
            float bv = bias ? bias[m0 + half * 64 + mr2] : 0.0f;
#pragma unroll
            for (int i = 0; i < 8; ++i) {
                float4 v = *reinterpret_cast<const float4*>(&Cf[mr2 * 132 + seg * 32 + i * 4]);
                v.x += bv; v.y += bv; v.z += bv; v.w += bv;
                *reinterpret_cast<float4*>(&Yb[(size_t)(m0 + half * 64 + mr2) * NN + n0 + seg * 32 + i * 4]) = v;
            }
        }
    }
}

// ---------------------------------------------------------------------------
// Hybrid MFMA flash attention: global_load_lds staging, 2-phase K/V dbuf,
// ones-row lsum, XCD-aware 1D remap.  V is sigma-pre-permuted in global so
// the PV A-fragment is a single b128 read at the SAME conflict-free slot
// pattern as K (2 lanes/bank = free).
// ---------------------------------------------------------------------------
__global__ __launch_bounds__(256, 4) void attn_mfma(const short* __restrict__ qk_t,
                                                    const short* __restrict__ v_cn,
                                                    short* __restrict__ aot_hi,
                                                    short* __restrict__ aot_lo)
{
    // XCD-aware decode: id%8 selects XCD under round-robin dispatch.
    const int id = blockIdx.x;           // 0..1023
    const int rx = id & 7;
    const int kk = id >> 3;              // 0..127
    const int bh = rx * 16 + (kk & 15);  // 0..127, constant per XCD group
    const int qt = kk >> 4;              // 0..7
    const int b  = bh >> 3;
    const int h  = bh & 7;
    const int n0 = qt * 128;

    __shared__ __align__(16) short smem[16384];  // 2 x (Ks 4096 + Vs 4096)

    const int tid  = threadIdx.x;
    const int lane = tid & 63;
    const int wave = tid >> 6;
    const int c    = lane & 15;
    const int h4   = lane >> 4;
    const int qb   = n0 + wave * 32;

    const short* Qb    = qk_t + ((size_t)b * Nn + qb) * 768 + h * HD;
    const short* Kbase = qk_t + (size_t)b * Nn * 768 + 384 + h * HD;
    const short* Vb    = v_cn + ((size_t)b * Cc + h * HD) * Nn;

    const bf16x8 z8 = {};

    // init Vs rows 48..63 in BOTH buffers: row 48 = 1.0, rows 49..63 = 0
    // (permutation-invariant contents)
    {
        int i0 = tid * 4;                       // 0..1023
        short v = (i0 < 64) ? (short)0x3F80 : (short)0;
        bf16x4 iv = {v, v, v, v};
        *reinterpret_cast<bf16x4*>(&smem[4096 + 3072 + i0]) = iv;
        *reinterpret_cast<bf16x4*>(&smem[12288 + 3072 + i0]) = iv;
    }

    // ---- Q fragments (loop-invariant, 2 sets) ----
    bf16x8 qf0[2], qf1[2];
#pragma unroll
    for (int s = 0; s < 2; ++s) {
        const short* qrow = Qb + (size_t)(s * 16 + c) * 768;
        qf0[s] = *reinterpret_cast<const bf16x8*>(qrow + 8 * h4);
        qf1[s] = (h4 < 2) ? *reinterpret_cast<const bf16x8*>(qrow + 32 + 8 * h4) : z8;
    }

    const int u0 = wave * 64 + lane;
    const int r0 = u0 >> 3;
    const int sc0 = ((u0 & 7) ^ (r0 & 7)) * 8;
    const int u1 = 256 + u0;
    const int r1 = u1 >> 3;
    const int sc1 = ((u1 & 7) ^ (r1 & 7)) * 8;

    const int cs8 = c & 7;
    const int ks0 = (h4 ^ cs8) * 8;            // K/V k-chunk h4
    const int ks1 = ((4 + h4) ^ cs8) * 8;      // K/V k-chunk 4+h4

    f32x4 o[2][3];
#pragma unroll
    for (int s = 0; s < 2; ++s)
#pragma unroll
        for (int jd = 0; jd < 3; ++jd) o[s][jd] = 0.0f;
    f32x4 o3[2];
    o3[0] = 0.0f; o3[1] = 0.0f;

    // ---- prologue: stage tile 0 into buffer 0 ----
    {
        short* Ksb = smem;
        short* Vsb = smem + 4096;
        gload16(Kbase + (size_t)r0 * 768 + sc0, Ksb + wave * 512);
        gload16(Kbase + (size_t)r1 * 768 + sc1, Ksb + 2048 + wave * 512);
        gload16(Vb + (size_t)r0 * Nn + sc0, Vsb + wave * 512);
        if (wave < 2)
            gload16(Vb + (size_t)r1 * Nn + sc1, Vsb + 2048 + wave * 512);
    }
    __syncthreads();

    for (int t = 0; t < 16; ++t) {
        const short* Ks = smem + (t & 1) * 8192;
        const short* Vs = Ks + 4096;

        // prefetch next tile into the other buffer FIRST
        if (t + 1 < 16) {
            short* Ksn = smem + ((t + 1) & 1) * 8192;
            short* Vsn = Ksn + 4096;
            const int mn = (t + 1) * 64;
            gload16(Kbase + (size_t)(mn + r0) * 768 + sc0, Ksn + wave * 512);
            gload16(Kbase + (size_t)(mn + r1) * 768 + sc1, Ksn + 2048 + wave * 512);
            gload16(Vb + (size_t)r0 * Nn + mn + sc0, Vsn + wave * 512);
            if (wave < 2)
                gload16(Vb + (size_t)r1 * Nn + mn + sc1, Vsn + 2048 + wave * 512);
        }

        // ---- QK^T (K frags shared by both sets) ----
        f32x4 s4a[4], s4b[4];
#pragma unroll
        for (int j = 0; j < 4; ++j) { s4a[j] = 0.0f; s4b[j] = 0.0f; }
#pragma unroll
        for (int j = 0; j < 4; ++j) {
            int kr = (16 * j + c) * 64;
            bf16x8 kc0 = *reinterpret_cast<const bf16x8*>(&Ks[kr + ks0]);
            bf16x8 kc1 = *reinterpret_cast<const bf16x8*>(&Ks[kr + ks1]);
            s4a[j] = __builtin_amdgcn_mfma_f32_16x16x32_bf16(kc0, qf0[0], s4a[j], 0, 0, 0);
            s4a[j] = __builtin_amdgcn_mfma_f32_16x16x32_bf16(kc1, qf1[0], s4a[j], 0, 0, 0);
            s4b[j] = __builtin_amdgcn_mfma_f32_16x16x32_bf16(kc0, qf0[1], s4b[j], 0, 0, 0);
            s4b[j] = __builtin_amdgcn_mfma_f32_16x16x32_bf16(kc1, qf1[1], s4b[j], 0, 0, 0);
        }

        // ---- softmax-lite + pack P (sigma order), both sets ----
        bf16x8 pa[2][2];
        {
            float p[4][4];
#pragma unroll
            for (int j = 0; j < 4; ++j)
#pragma unroll
                for (int r = 0; r < 4; ++r)
                    p[j][r] = exp2f(s4a[j][r]);
#pragma unroll
            for (int r = 0; r < 4; ++r) {
                pa[0][0][r]     = f2b(p[0][r]);
                pa[0][0][4 + r] = f2b(p[1][r]);
                pa[0][1][r]     = f2b(p[2][r]);
                pa[0][1][4 + r] = f2b(p[3][r]);
            }
        }
        {
            float p[4][4];
#pragma unroll
            for (int j = 0; j < 4; ++j)
#pragma unroll
                for (int r = 0; r < 4; ++r)
                    p[j][r] = exp2f(s4b[j][r]);
#pragma unroll
            for (int r = 0; r < 4; ++r) {
                pa[1][0][r]     = f2b(p[0][r]);
                pa[1][0][4 + r] = f2b(p[1][r]);
                pa[1][1][r]     = f2b(p[2][r]);
                pa[1][1][4 + r] = f2b(p[3][r]);
            }
        }

        // ---- PV (jd 0..2) + ones-row lsum (jd 3): single b128 V frags ----
#pragma unroll
        for (int jd = 0; jd < 4; ++jd) {
            int vr = (16 * jd + c) * 64;
            bf16x8 vf0 = *reinterpret_cast<const bf16x8*>(&Vs[vr + ks0]);
            bf16x8 vf1 = *reinterpret_cast<const bf16x8*>(&Vs[vr + ks1]);
            if (jd < 3) {
                o[0][jd] = __builtin_amdgcn_mfma_f32_16x16x32_bf16(vf0, pa[0][0], o[0][jd], 0, 0, 0);
                o[0][jd] = __builtin_amdgcn_mfma_f32_16x16x32_bf16(vf1, pa[0][1], o[0][jd], 0, 0, 0);
                o[1][jd] = __builtin_amdgcn_mfma_f32_16x16x32_bf16(vf0, pa[1][0], o[1][jd], 0, 0, 0);
                o[1][jd] = __builtin_amdgcn_mfma_f32_16x16x32_bf16(vf1, pa[1][1], o[1][jd], 0, 0, 0);
            } else {
                o3[0] = __builtin_amdgcn_mfma_f32_16x16x32_bf16(vf0, pa[0][0], o3[0], 0, 0, 0);
                o3[0] = __builtin_amdgcn_mfma_f32_16x16x32_bf16(vf1, pa[0][1], o3[0], 0, 0, 0);
                o3[1] = __builtin_amdgcn_mfma_f32_16x16x32_bf16(vf0, pa[1][0], o3[1], 0, 0, 0);
                o3[1] = __builtin_amdgcn_mfma_f32_16x16x32_bf16(vf1, pa[1][1], o3[1], 0, 0, 0);
            }
        }

        __syncthreads();   // drains prefetch + protects buffer reuse
    }

    // ---- epilogue: lsum broadcast from h4==0 lanes, normalize, split hi/lo ----
#pragma unroll
    for (int set = 0; set < 2; ++set) {
        float ls = __shfl(o3[set][0], c);    // lane (c, h4=0) holds Sigma P for q=c
        float linv = 1.0f / ls;
        size_t rowoff = ((size_t)b * Nn + qb + set * 16 + c) * Cc + h * HD;
#pragma unroll
        for (int jd = 0; jd < 3; ++jd) {
            bf16x4 hv, lv;
#pragma unroll
            for (int r = 0; r < 4; ++r) {
                float val = o[set][jd][r] * linv;
                short x = f2b(val);
                hv[r] = x;
                lv[r] = f2b(val - b2f(x));
            }
            *reinterpret_cast<bf16x4*>(&aot_hi[rowoff + 16 * jd + 4 * h4]) = hv;
            *reinterpret_cast<bf16x4*>(&aot_lo[rowoff + 16 * jd + 4 * h4]) = lv;
        }
    }
}

// ---------------------------------------------------------------------------
extern "C" void kernel_launch(void* const* d_in, const int* in_sizes, int n_in,
                              void* d_out, int out_size, void* d_ws, size_t ws_size,
                              hipStream_t stream)
{
    const float* x      = (const float*)d_in[0];
    const float* w_qkv  = (const float*)d_in[1];
    const float* w_proj = (const float*)d_in[2];
    const float* b_proj = (const float*)d_in[3];
    float* out = (float*)d_out;

    short* ws = (short*)d_ws;
    const size_t XT = (size_t)Bn * Nn * Cc;            // 6291456
    short* xt_hi  = ws;
    short* xt_lo  = xt_hi + XT;
    short* wq_hi  = xt_lo + XT;
    short* wq_lo  = wq_hi + (size_t)3 * Cc * Cc;
    short* wp_hi  = wq_lo + (size_t)3 * Cc * Cc;
    short* wp_lo  = wp_hi + (size_t)Cc * Cc;
    short* qk_t   = wp_lo + (size_t)Cc * Cc;           // (B, N, 768)
    short* v_cn   = qk_t + (size_t)Bn * Nn * 768;      // (B, 384, N) sigma-perm
    short* aot_hi = v_cn + XT;
    short* aot_lo = aot_hi + XT;

    // 0) weight + x prep
    conv_split<<<(3 * Cc * Cc / 4 + 255) / 256, 256, 0, stream>>>(w_qkv, wq_hi, wq_lo, 3 * Cc * Cc);
    conv_split<<<(Cc * Cc / 4 + 255) / 256, 256, 0, stream>>>(w_proj, wp_hi, wp_lo, Cc * Cc);
    prep_xt<<<dim3(Nn / 64, Cc / 64, Bn), 256, 0, stream>>>(x, xt_hi, xt_lo);

    // 1) QKV GEMM (2-pass, 2-phase dbuf) -> qk_t + sigma-permuted v_cn
    gemm_split<0><<<dim3(Nn / 128, (3 * Cc) / 128, Bn), 256, 0, stream>>>(
        wq_hi, wq_lo, xt_hi, xt_lo, qk_t, v_cn, nullptr, nullptr, 3 * Cc, Cc, Nn);

    // 2) Hybrid attention (XCD remap, 2-phase dbuf, ones-row lsum, b128 V frags)
    attn_mfma<<<1024, 256, 0, stream>>>(qk_t, v_cn, aot_hi, aot_lo);

    // 3) Projection GEMM (3-pass, 2-phase dbuf, fp32 out + bias)
    gemm_split<1><<<dim3(Nn / 128, Cc / 128, Bn), 256, 0, stream>>>(
        wp_hi, wp_lo, aot_hi, aot_lo, nullptr, nullptr, out, b_proj, Cc, Cc, Nn);
}

// Round 20
// 128.373 us; speedup vs baseline: 1.3062x; 1.0390x over previous
//
#include <hip/hip_runtime.h>
#include <hip/hip_bf16.h>
#include <math.h>

// Problem constants
constexpr int Bn     = 16;    // batch
constexpr int Cc     = 384;   // channels
constexpr int Nn     = 1024;  // tokens (32*32)
constexpr int NHEADS = 8;
constexpr int HD     = 48;    // head dim
constexpr float SCALE = 0.14433756729740643f; // 48^-0.5
constexpr float SCL2  = 0.14433756729740643f * 1.4426950408889634f; // SCALE*log2(e)

using bf16x8 = __attribute__((ext_vector_type(8))) short;
using bf16x4 = __attribute__((ext_vector_type(4))) short;
using f32x4  = __attribute__((ext_vector_type(4))) float;

__device__ inline short f2b(float f) {
    __hip_bfloat16 h = __float2bfloat16(f);
    return *reinterpret_cast<short*>(&h);
}
__device__ inline float b2f(short s) {
    __hip_bfloat16 h = *reinterpret_cast<__hip_bfloat16*>(&s);
    return __bfloat162float(h);
}

// async global->LDS, 16B per lane; LDS dest = wave-uniform base + lane*16B
__device__ __forceinline__ void gload16(const short* g, short* l) {
    __builtin_amdgcn_global_load_lds(
        (const __attribute__((address_space(1))) void*)(g),
        (__attribute__((address_space(3))) void*)(l),
        16, 0, 0);
}

// ---------------------------------------------------------------------------
// Fused elementwise fp32 -> (hi, lo) bf16 split for BOTH weight tensors.
// ---------------------------------------------------------------------------
__global__ __launch_bounds__(256) void conv_split2(const float* __restrict__ in1,
                                                   short* __restrict__ hi1,
                                                   short* __restrict__ lo1, int n1,
                                                   const float* __restrict__ in2,
                                                   short* __restrict__ hi2,
                                                   short* __restrict__ lo2, int n2)
{
    int u = blockIdx.x * 256 + threadIdx.x;
    const float* in; short* hi; short* lo; int i;
    if (u * 4 < n1) { in = in1; hi = hi1; lo = lo1; i = u * 4; }
    else {
        i = u * 4 - n1;
        if (i >= n2) return;
        in = in2; hi = hi2; lo = lo2;
    }
    float4 v = *reinterpret_cast<const float4*>(&in[i]);
    float vs[4] = {v.x, v.y, v.z, v.w};
    bf16x4 h, l;
#pragma unroll
    for (int j = 0; j < 4; ++j) {
        h[j] = f2b(vs[j]);
        l[j] = f2b(vs[j] - b2f(h[j]));
    }
    *reinterpret_cast<bf16x4*>(&hi[i]) = h;
    *reinterpret_cast<bf16x4*>(&lo[i]) = l;
}

// ---------------------------------------------------------------------------
// x (B, C, N) fp32 -> x^T (B, N, C) bf16 hi/lo.  64x64 tile via LDS.
// ---------------------------------------------------------------------------
__global__ __launch_bounds__(256) void prep_xt(const float* __restrict__ x,
                                               short* __restrict__ xt_hi,
                                               short* __restrict__ xt_lo)
{
    const int b  = blockIdx.z;
    const int c0 = blockIdx.y * 64;
    const int n0 = blockIdx.x * 64;
    __shared__ float T[64 * 68];

    const int tid = threadIdx.x;
    const int r   = tid >> 2;
    const int seg = tid & 3;

    const float* xb = x + ((size_t)b * Cc + c0) * Nn;
#pragma unroll
    for (int i = 0; i < 4; ++i) {
        float4 v = *reinterpret_cast<const float4*>(&xb[(size_t)r * Nn + n0 + seg * 16 + i * 4]);
        *reinterpret_cast<float4*>(&T[r * 68 + seg * 16 + i * 4]) = v;
    }
    __syncthreads();

    short* oh = xt_hi + ((size_t)b * Nn + n0 + r) * Cc + c0;
    short* ol = xt_lo + ((size_t)b * Nn + n0 + r) * Cc + c0;
#pragma unroll
    for (int i = 0; i < 4; ++i) {
        bf16x4 hv, lv;
#pragma unroll
        for (int j = 0; j < 4; ++j) {
            float v = T[(seg * 16 + i * 4 + j) * 68 + r];
            hv[j] = f2b(v);
            lv[j] = f2b(v - b2f(hv[j]));
        }
        *reinterpret_cast<bf16x4*>(&oh[seg * 16 + i * 4]) = hv;
        *reinterpret_cast<bf16x4*>(&ol[seg * 16 + i * 4]) = lv;
    }
}

// ---------------------------------------------------------------------------
// Split-bf16 MFMA GEMM, 2-phase LDS double-buffer, global_load_lds staging.
// BOTH modes: 2-pass  y = Whi*Xhi + Whi*Xlo  (Wlo dropped — error below the
// bf16 output-rounding / threshold floor; R16 empirically confirmed for QKV).
// 48 KB LDS -> 3 blocks/CU.
// MODE 0 (QKV): m<768 -> Yqk token-major (B,N,768) bf16 (Q pre-scaled by SCL2);
//   m>=768 -> Yv (B,384,N) bf16, columns sigma-permuted per 64-n group.
// MODE 1 (PROJ): fp32 out + bias.
// ---------------------------------------------------------------------------
template <int MODE>
__global__ __launch_bounds__(256) void gemm_split(const short* __restrict__ Whi,
                                                  const short* __restrict__ Xhi,
                                                  const short* __restrict__ Xlo,
                                                  short* __restrict__ Yqk,
                                                  short* __restrict__ Yv,
                                                  float* __restrict__ Yf,
                                                  const float* __restrict__ bias,
                                                  int M, int K, int NN)
{
    const int b  = blockIdx.z;
    const int m0 = blockIdx.y * 128;
    const int n0 = blockIdx.x * 128;
    const short* Xb_hi = Xhi + (size_t)b * NN * K;
    const short* Xb_lo = Xlo + (size_t)b * NN * K;

    constexpr int BUFS = 12288;   // shorts per buffer
    constexpr int OAhi = 0;
    constexpr int OBhi = 4096;
    constexpr int OBlo = 8192;
    __shared__ __align__(16) short smem[24576];

    const int tid  = threadIdx.x;
    const int lane = tid & 63;
    const int wave = tid >> 6;
    const int c    = lane & 15;
    const int h4   = lane >> 4;
    const int wr   = wave >> 1;
    const int wc   = wave & 1;

    const int sq   = ((tid & 3) ^ ((tid >> 3) & 3)) * 8;  // swizzled src chunk
    const int lds0 = wave * 512;                          // shorts, per tile
    const int lds1 = 2048 + wave * 512;

    const short* gWhi = Whi + (size_t)(m0 + (tid >> 2)) * K + sq;
    const short* gXhi = Xb_hi + (size_t)(n0 + (tid >> 2)) * K + sq;
    const short* gXlo = Xb_lo + (size_t)(n0 + (tid >> 2)) * K + sq;
    const size_t rowskip = (size_t)64 * K;

    const int sw = (h4 ^ ((c >> 1) & 3)) * 8;             // frag-read swizzle

    f32x4 acc[4][4];
#pragma unroll
    for (int mi = 0; mi < 4; ++mi)
#pragma unroll
        for (int ni = 0; ni < 4; ++ni) acc[mi][ni] = 0.0f;

    // ---- prologue: stage tile 0 into buffer 0 ----
    {
        short* buf = smem;
        gload16(gWhi,           buf + OAhi + lds0);
        gload16(gWhi + rowskip, buf + OAhi + lds1);
        gload16(gXhi,           buf + OBhi + lds0);
        gload16(gXhi + rowskip, buf + OBhi + lds1);
        gload16(gXlo,           buf + OBlo + lds0);
        gload16(gXlo + rowskip, buf + OBlo + lds1);
    }
    __syncthreads();

    const int NT = K >> 5;   // 12
    for (int t = 0; t < NT; ++t) {
        short* cbuf = smem + (t & 1) * BUFS;

        // prefetch next tile into the other buffer FIRST
        if (t + 1 < NT) {
            short* nbuf = smem + ((t + 1) & 1) * BUFS;
            const int nk = (t + 1) * 32;
            gload16(gWhi + nk,           nbuf + OAhi + lds0);
            gload16(gWhi + rowskip + nk, nbuf + OAhi + lds1);
            gload16(gXhi + nk,           nbuf + OBhi + lds0);
            gload16(gXhi + rowskip + nk, nbuf + OBhi + lds1);
            gload16(gXlo + nk,           nbuf + OBlo + lds0);
            gload16(gXlo + rowskip + nk, nbuf + OBlo + lds1);
        }

        bf16x8 a_hi[4], b_hi[4], b_lo[4];
#pragma unroll
        for (int mi = 0; mi < 4; ++mi) {
            int row = wr * 64 + mi * 16 + c;
            a_hi[mi] = *reinterpret_cast<const bf16x8*>(&cbuf[OAhi + row * 32 + sw]);
        }
#pragma unroll
        for (int ni = 0; ni < 4; ++ni) {
            int row = wc * 64 + ni * 16 + c;
            b_hi[ni] = *reinterpret_cast<const bf16x8*>(&cbuf[OBhi + row * 32 + sw]);
            b_lo[ni] = *reinterpret_cast<const bf16x8*>(&cbuf[OBlo + row * 32 + sw]);
        }
        __builtin_amdgcn_s_setprio(1);
#pragma unroll
        for (int mi = 0; mi < 4; ++mi)
#pragma unroll
            for (int ni = 0; ni < 4; ++ni) {
                acc[mi][ni] = __builtin_amdgcn_mfma_f32_16x16x32_bf16(a_hi[mi], b_hi[ni], acc[mi][ni], 0, 0, 0);
                acc[mi][ni] = __builtin_amdgcn_mfma_f32_16x16x32_bf16(a_hi[mi], b_lo[ni], acc[mi][ni], 0, 0, 0);
            }
        __builtin_amdgcn_s_setprio(0);

        __syncthreads();   // drains prefetch loads + protects buffer reuse
    }

    if (MODE == 0) {
        if (m0 < 768) {
            const float qscale = (m0 < 384) ? SCL2 : 1.0f;
            short* Cs = smem;  // [128 n][136]
#pragma unroll
            for (int mi = 0; mi < 4; ++mi)
#pragma unroll
                for (int ni = 0; ni < 4; ++ni) {
                    int nl = wc * 64 + ni * 16 + c;
                    int cl = wr * 64 + mi * 16 + 4 * h4;
                    bf16x4 pk;
#pragma unroll
                    for (int r = 0; r < 4; ++r) pk[r] = f2b(acc[mi][ni][r] * qscale);
                    *reinterpret_cast<bf16x4*>(&Cs[nl * 136 + cl]) = pk;
                }
            __syncthreads();
#pragma unroll
            for (int l = 0; l < 8; ++l) {
                int u  = tid + l * 256;
                int nl = u >> 4, ch = u & 15;
                *reinterpret_cast<bf16x8*>(&Yqk[((size_t)b * NN + n0 + nl) * 768 + m0 + ch * 8]) =
                    *reinterpret_cast<const bf16x8*>(&Cs[nl * 136 + ch * 8]);
            }
        } else {
            // V: channel-major bf16 out (d, n), columns sigma-permuted per
            // 64-n group so PV A-frag = single b128 LDS read in attention.
            short* Cs = smem;  // [128 ch][136]
#pragma unroll
            for (int mi = 0; mi < 4; ++mi)
#pragma unroll
                for (int ni = 0; ni < 4; ++ni) {
                    int npb = wc * 64 + 32 * (ni >> 1) + 8 * (c >> 2) + 4 * (ni & 1) + (c & 3);
#pragma unroll
                    for (int r = 0; r < 4; ++r) {
                        int ml = wr * 64 + mi * 16 + h4 * 4 + r;
                        Cs[ml * 136 + npb] = f2b(acc[mi][ni][r]);
                    }
                }
            __syncthreads();
            short* Yb = Yv + (size_t)b * Cc * NN;
            const int srow2 = tid >> 1;
            const int cseg  = (tid & 1) * 64;
#pragma unroll
            for (int i = 0; i < 8; ++i)
                *reinterpret_cast<bf16x8*>(&Yb[(size_t)(m0 - 768 + srow2) * NN + n0 + cseg + i * 8]) =
                    *reinterpret_cast<const bf16x8*>(&Cs[srow2 * 136 + cseg + i * 8]);
        }
    } else {
        float* Yb = Yf + (size_t)b * M * NN;
        float* Cf = reinterpret_cast<float*>(smem);
        const int mr2 = tid >> 2;
        const int seg = tid & 3;
#pragma unroll
        for (int half = 0; half < 2; ++half) {
            __syncthreads();
            if (wr == half) {
#pragma unroll
                for (int mi = 0; mi < 4; ++mi)
#pragma unroll
                    for (int ni = 0; ni < 4; ++ni)
#pragma unroll
                        for (int r = 0; r < 4; ++r) {
                            int ml = mi * 16 + h4 * 4 + r;
                            int nl = wc * 64 + ni * 16 + c;
                            Cf[ml * 132 + nl] = acc[mi][ni][r];
                        }
            }
            __syncthreads();
            float bv = bias ? bias[m0 + half * 64 + mr2] : 0.0f;
#pragma unroll
            for (int i = 0; i < 8; ++i) {
                float4 v = *reinterpret_cast<const float4*>(&Cf[mr2 * 132 + seg * 32 + i * 4]);
                v.x += bv; v.y += bv; v.z += bv; v.w += bv;
                *reinterpret_cast<float4*>(&Yb[(size_t)(m0 + half * 64 + mr2) * NN + n0 + seg * 32 + i * 4]) = v;
            }
        }
    }
}

// ---------------------------------------------------------------------------
// Hybrid MFMA flash attention: global_load_lds staging, 2-phase K/V dbuf,
// ones-row lsum, XCD-aware 1D remap, sigma-pre-permuted V (single b128 frags),
// s_setprio around MFMA clusters.
// ---------------------------------------------------------------------------
__global__ __launch_bounds__(256, 4) void attn_mfma(const short* __restrict__ qk_t,
                                                    const short* __restrict__ v_cn,
                                                    short* __restrict__ aot_hi,
                                                    short* __restrict__ aot_lo)
{
    // XCD-aware decode: id%8 selects XCD under round-robin dispatch.
    const int id = blockIdx.x;           // 0..1023
    const int rx = id & 7;
    const int kk = id >> 3;              // 0..127
    const int bh = rx * 16 + (kk & 15);  // 0..127, constant per XCD group
    const int qt = kk >> 4;              // 0..7
    const int b  = bh >> 3;
    const int h  = bh & 7;
    const int n0 = qt * 128;

    __shared__ __align__(16) short smem[16384];  // 2 x (Ks 4096 + Vs 4096)

    const int tid  = threadIdx.x;
    const int lane = tid & 63;
    const int wave = tid >> 6;
    const int c    = lane & 15;
    const int h4   = lane >> 4;
    const int qb   = n0 + wave * 32;

    const short* Qb    = qk_t + ((size_t)b * Nn + qb) * 768 + h * HD;
    const short* Kbase = qk_t + (size_t)b * Nn * 768 + 384 + h * HD;
    const short* Vb    = v_cn + ((size_t)b * Cc + h * HD) * Nn;

    const bf16x8 z8 = {};

    // init Vs rows 48..63 in BOTH buffers: row 48 = 1.0, rows 49..63 = 0
    {
        int i0 = tid * 4;                       // 0..1023
        short v = (i0 < 64) ? (short)0x3F80 : (short)0;
        bf16x4 iv = {v, v, v, v};
        *reinterpret_cast<bf16x4*>(&smem[4096 + 3072 + i0]) = iv;
        *reinterpret_cast<bf16x4*>(&smem[12288 + 3072 + i0]) = iv;
    }

    // ---- Q fragments (loop-invariant, 2 sets) ----
    bf16x8 qf0[2], qf1[2];
#pragma unroll
    for (int s = 0; s < 2; ++s) {
        const short* qrow = Qb + (size_t)(s * 16 + c) * 768;
        qf0[s] = *reinterpret_cast<const bf16x8*>(qrow + 8 * h4);
        qf1[s] = (h4 < 2) ? *reinterpret_cast<const bf16x8*>(qrow + 32 + 8 * h4) : z8;
    }

    const int u0 = wave * 64 + lane;
    const int r0 = u0 >> 3;
    const int sc0 = ((u0 & 7) ^ (r0 & 7)) * 8;
    const int u1 = 256 + u0;
    const int r1 = u1 >> 3;
    const int sc1 = ((u1 & 7) ^ (r1 & 7)) * 8;

    const int cs8 = c & 7;
    const int ks0 = (h4 ^ cs8) * 8;            // K/V k-chunk h4
    const int ks1 = ((4 + h4) ^ cs8) * 8;      // K/V k-chunk 4+h4

    f32x4 o[2][3];
#pragma unroll
    for (int s = 0; s < 2; ++s)
#pragma unroll
        for (int jd = 0; jd < 3; ++jd) o[s][jd] = 0.0f;
    f32x4 o3[2];
    o3[0] = 0.0f; o3[1] = 0.0f;

    // ---- prologue: stage tile 0 into buffer 0 ----
    {
        short* Ksb = smem;
        short* Vsb = smem + 4096;
        gload16(Kbase + (size_t)r0 * 768 + sc0, Ksb + wave * 512);
        gload16(Kbase + (size_t)r1 * 768 + sc1, Ksb + 2048 + wave * 512);
        gload16(Vb + (size_t)r0 * Nn + sc0, Vsb + wave * 512);
        if (wave < 2)
            gload16(Vb + (size_t)r1 * Nn + sc1, Vsb + 2048 + wave * 512);
    }
    __syncthreads();

    for (int t = 0; t < 16; ++t) {
        const short* Ks = smem + (t & 1) * 8192;
        const short* Vs = Ks + 4096;

        // prefetch next tile into the other buffer FIRST
        if (t + 1 < 16) {
            short* Ksn = smem + ((t + 1) & 1) * 8192;
            short* Vsn = Ksn + 4096;
            const int mn = (t + 1) * 64;
            gload16(Kbase + (size_t)(mn + r0) * 768 + sc0, Ksn + wave * 512);
            gload16(Kbase + (size_t)(mn + r1) * 768 + sc1, Ksn + 2048 + wave * 512);
            gload16(Vb + (size_t)r0 * Nn + mn + sc0, Vsn + wave * 512);
            if (wave < 2)
                gload16(Vb + (size_t)r1 * Nn + mn + sc1, Vsn + 2048 + wave * 512);
        }

        // ---- QK^T (K frags shared by both sets) ----
        f32x4 s4a[4], s4b[4];
#pragma unroll
        for (int j = 0; j < 4; ++j) { s4a[j] = 0.0f; s4b[j] = 0.0f; }
        __builtin_amdgcn_s_setprio(1);
#pragma unroll
        for (int j = 0; j < 4; ++j) {
            int kr = (16 * j + c) * 64;
            bf16x8 kc0 = *reinterpret_cast<const bf16x8*>(&Ks[kr + ks0]);
            bf16x8 kc1 = *reinterpret_cast<const bf16x8*>(&Ks[kr + ks1]);
            s4a[j] = __builtin_amdgcn_mfma_f32_16x16x32_bf16(kc0, qf0[0], s4a[j], 0, 0, 0);
            s4a[j] = __builtin_amdgcn_mfma_f32_16x16x32_bf16(kc1, qf1[0], s4a[j], 0, 0, 0);
            s4b[j] = __builtin_amdgcn_mfma_f32_16x16x32_bf16(kc0, qf0[1], s4b[j], 0, 0, 0);
            s4b[j] = __builtin_amdgcn_mfma_f32_16x16x32_bf16(kc1, qf1[1], s4b[j], 0, 0, 0);
        }
        __builtin_amdgcn_s_setprio(0);

        // ---- softmax-lite + pack P (sigma order), both sets ----
        bf16x8 pa[2][2];
        {
            float p[4][4];
#pragma unroll
            for (int j = 0; j < 4; ++j)
#pragma unroll
                for (int r = 0; r < 4; ++r)
                    p[j][r] = exp2f(s4a[j][r]);
#pragma unroll
            for (int r = 0; r < 4; ++r) {
                pa[0][0][r]     = f2b(p[0][r]);
                pa[0][0][4 + r] = f2b(p[1][r]);
                pa[0][1][r]     = f2b(p[2][r]);
                pa[0][1][4 + r] = f2b(p[3][r]);
            }
        }
        {
            float p[4][4];
#pragma unroll
            for (int j = 0; j < 4; ++j)
#pragma unroll
                for (int r = 0; r < 4; ++r)
                    p[j][r] = exp2f(s4b[j][r]);
#pragma unroll
            for (int r = 0; r < 4; ++r) {
                pa[1][0][r]     = f2b(p[0][r]);
                pa[1][0][4 + r] = f2b(p[1][r]);
                pa[1][1][r]     = f2b(p[2][r]);
                pa[1][1][4 + r] = f2b(p[3][r]);
            }
        }

        // ---- PV (jd 0..2) + ones-row lsum (jd 3): single b128 V frags ----
        __builtin_amdgcn_s_setprio(1);
#pragma unroll
        for (int jd = 0; jd < 4; ++jd) {
            int vr = (16 * jd + c) * 64;
            bf16x8 vf0 = *reinterpret_cast<const bf16x8*>(&Vs[vr + ks0]);
            bf16x8 vf1 = *reinterpret_cast<const bf16x8*>(&Vs[vr + ks1]);
            if (jd < 3) {
                o[0][jd] = __builtin_amdgcn_mfma_f32_16x16x32_bf16(vf0, pa[0][0], o[0][jd], 0, 0, 0);
                o[0][jd] = __builtin_amdgcn_mfma_f32_16x16x32_bf16(vf1, pa[0][1], o[0][jd], 0, 0, 0);
                o[1][jd] = __builtin_amdgcn_mfma_f32_16x16x32_bf16(vf0, pa[1][0], o[1][jd], 0, 0, 0);
                o[1][jd] = __builtin_amdgcn_mfma_f32_16x16x32_bf16(vf1, pa[1][1], o[1][jd], 0, 0, 0);
            } else {
                o3[0] = __builtin_amdgcn_mfma_f32_16x16x32_bf16(vf0, pa[0][0], o3[0], 0, 0, 0);
                o3[0] = __builtin_amdgcn_mfma_f32_16x16x32_bf16(vf1, pa[0][1], o3[0], 0, 0, 0);
                o3[1] = __builtin_amdgcn_mfma_f32_16x16x32_bf16(vf0, pa[1][0], o3[1], 0, 0, 0);
                o3[1] = __builtin_amdgcn_mfma_f32_16x16x32_bf16(vf1, pa[1][1], o3[1], 0, 0, 0);
            }
        }
        __builtin_amdgcn_s_setprio(0);

        __syncthreads();   // drains prefetch + protects buffer reuse
    }

    // ---- epilogue: lsum broadcast from h4==0 lanes, normalize, split hi/lo ----
#pragma unroll
    for (int set = 0; set < 2; ++set) {
        float ls = __shfl(o3[set][0], c);    // lane (c, h4=0) holds Sigma P for q=c
        float linv = 1.0f / ls;
        size_t rowoff = ((size_t)b * Nn + qb + set * 16 + c) * Cc + h * HD;
#pragma unroll
        for (int jd = 0; jd < 3; ++jd) {
            bf16x4 hv, lv;
#pragma unroll
            for (int r = 0; r < 4; ++r) {
                float val = o[set][jd][r] * linv;
                short x = f2b(val);
                hv[r] = x;
                lv[r] = f2b(val - b2f(x));
            }
            *reinterpret_cast<bf16x4*>(&aot_hi[rowoff + 16 * jd + 4 * h4]) = hv;
            *reinterpret_cast<bf16x4*>(&aot_lo[rowoff + 16 * jd + 4 * h4]) = lv;
        }
    }
}

// ---------------------------------------------------------------------------
extern "C" void kernel_launch(void* const* d_in, const int* in_sizes, int n_in,
                              void* d_out, int out_size, void* d_ws, size_t ws_size,
                              hipStream_t stream)
{
    const float* x      = (const float*)d_in[0];
    const float* w_qkv  = (const float*)d_in[1];
    const float* w_proj = (const float*)d_in[2];
    const float* b_proj = (const float*)d_in[3];
    float* out = (float*)d_out;

    short* ws = (short*)d_ws;
    const size_t XT = (size_t)Bn * Nn * Cc;            // 6291456
    short* xt_hi  = ws;
    short* xt_lo  = xt_hi + XT;
    short* wq_hi  = xt_lo + XT;
    short* wq_lo  = wq_hi + (size_t)3 * Cc * Cc;
    short* wp_hi  = wq_lo + (size_t)3 * Cc * Cc;
    short* wp_lo  = wp_hi + (size_t)Cc * Cc;
    short* qk_t   = wp_lo + (size_t)Cc * Cc;           // (B, N, 768)
    short* v_cn   = qk_t + (size_t)Bn * Nn * 768;      // (B, 384, N) sigma-perm
    short* aot_hi = v_cn + XT;
    short* aot_lo = aot_hi + XT;

    // 0) weight prep (fused) + x prep
    {
        int n1 = 3 * Cc * Cc, n2 = Cc * Cc;
        int units = (n1 + n2) / 4;
        conv_split2<<<(units + 255) / 256, 256, 0, stream>>>(
            w_qkv, wq_hi, wq_lo, n1, w_proj, wp_hi, wp_lo, n2);
    }
    prep_xt<<<dim3(Nn / 64, Cc / 64, Bn), 256, 0, stream>>>(x, xt_hi, xt_lo);

    // 1) QKV GEMM (2-pass, 2-phase dbuf) -> qk_t + sigma-permuted v_cn
    gemm_split<0><<<dim3(Nn / 128, (3 * Cc) / 128, Bn), 256, 0, stream>>>(
        wq_hi, xt_hi, xt_lo, qk_t, v_cn, nullptr, nullptr, 3 * Cc, Cc, Nn);

    // 2) Hybrid attention (XCD remap, dbuf, ones-row lsum, b128 V frags, setprio)
    attn_mfma<<<1024, 256, 0, stream>>>(qk_t, v_cn, aot_hi, aot_lo);

    // 3) Projection GEMM (2-pass, 2-phase dbuf, fp32 out + bias)
    gemm_split<1><<<dim3(Nn / 128, Cc / 128, Bn), 256, 0, stream>>>(
        wp_hi, aot_hi, aot_lo, nullptr, nullptr, out, b_proj, Cc, Cc, Nn);
}

// Round 21
// 112.831 us; speedup vs baseline: 1.4861x; 1.1378x over previous
//
#include <hip/hip_runtime.h>
#include <hip/hip_bf16.h>
#include <math.h>

// Problem constants
constexpr int Bn     = 16;    // batch
constexpr int Cc     = 384;   // channels
constexpr int Nn     = 1024;  // tokens (32*32)
constexpr int NHEADS = 8;
constexpr int HD     = 48;    // head dim
constexpr float SCALE = 0.14433756729740643f; // 48^-0.5
constexpr float SCL2  = 0.14433756729740643f * 1.4426950408889634f; // SCALE*log2(e)

using bf16x8 = __attribute__((ext_vector_type(8))) short;
using bf16x4 = __attribute__((ext_vector_type(4))) short;
using f32x4  = __attribute__((ext_vector_type(4))) float;

__device__ inline short f2b(float f) {
    __hip_bfloat16 h = __float2bfloat16(f);
    return *reinterpret_cast<short*>(&h);
}

// async global->LDS, 16B per lane; LDS dest = wave-uniform base + lane*16B
__device__ __forceinline__ void gload16(const short* g, short* l) {
    __builtin_amdgcn_global_load_lds(
        (const __attribute__((address_space(1))) void*)(g),
        (__attribute__((address_space(3))) void*)(l),
        16, 0, 0);
}

// ---------------------------------------------------------------------------
// Fused fp32 -> bf16 cast for BOTH weight tensors (no lo split).
// ---------------------------------------------------------------------------
__global__ __launch_bounds__(256) void conv_cast2(const float* __restrict__ in1,
                                                  short* __restrict__ hi1, int n1,
                                                  const float* __restrict__ in2,
                                                  short* __restrict__ hi2, int n2)
{
    int u = blockIdx.x * 256 + threadIdx.x;
    const float* in; short* hi; int i;
    if (u * 4 < n1) { in = in1; hi = hi1; i = u * 4; }
    else {
        i = u * 4 - n1;
        if (i >= n2) return;
        in = in2; hi = hi2;
    }
    float4 v = *reinterpret_cast<const float4*>(&in[i]);
    bf16x4 h = { f2b(v.x), f2b(v.y), f2b(v.z), f2b(v.w) };
    *reinterpret_cast<bf16x4*>(&hi[i]) = h;
}

// ---------------------------------------------------------------------------
// x (B, C, N) fp32 -> x^T (B, N, C) bf16.  64x64 tile via LDS.
// ---------------------------------------------------------------------------
__global__ __launch_bounds__(256) void prep_xt(const float* __restrict__ x,
                                               short* __restrict__ xt)
{
    const int b  = blockIdx.z;
    const int c0 = blockIdx.y * 64;
    const int n0 = blockIdx.x * 64;
    __shared__ float T[64 * 68];

    const int tid = threadIdx.x;
    const int r   = tid >> 2;
    const int seg = tid & 3;

    const float* xb = x + ((size_t)b * Cc + c0) * Nn;
#pragma unroll
    for (int i = 0; i < 4; ++i) {
        float4 v = *reinterpret_cast<const float4*>(&xb[(size_t)r * Nn + n0 + seg * 16 + i * 4]);
        *reinterpret_cast<float4*>(&T[r * 68 + seg * 16 + i * 4]) = v;
    }
    __syncthreads();

    short* oh = xt + ((size_t)b * Nn + n0 + r) * Cc + c0;
#pragma unroll
    for (int i = 0; i < 4; ++i) {
        bf16x4 hv;
#pragma unroll
        for (int j = 0; j < 4; ++j)
            hv[j] = f2b(T[(seg * 16 + i * 4 + j) * 68 + r]);
        *reinterpret_cast<bf16x4*>(&oh[seg * 16 + i * 4]) = hv;
    }
}

// ---------------------------------------------------------------------------
// Single-pass bf16 MFMA GEMM: Y = Whi * Xhi (lo terms dropped — below the
// attention-path bf16 error floor; R16 confirmed empirically).
// 2-phase LDS double-buffer, global_load_lds staging, 34.8 KB LDS.
// MODE 0 (QKV): m<768 -> Yqk token-major (B,N,768) bf16 (Q pre-scaled SCL2);
//   m>=768 -> Yv (B,384,N) bf16, columns sigma-permuted per 64-n group.
// MODE 1 (PROJ): fp32 out + bias.
// ---------------------------------------------------------------------------
template <int MODE>
__global__ __launch_bounds__(256) void gemm_bf16(const short* __restrict__ Whi,
                                                 const short* __restrict__ Xh,
                                                 short* __restrict__ Yqk,
                                                 short* __restrict__ Yv,
                                                 float* __restrict__ Yf,
                                                 const float* __restrict__ bias,
                                                 int M, int K, int NN)
{
    const int b  = blockIdx.z;
    const int m0 = blockIdx.y * 128;
    const int n0 = blockIdx.x * 128;
    const short* Xb = Xh + (size_t)b * NN * K;

    constexpr int BUFS = 8192;    // shorts per buffer (2 tiles)
    constexpr int OA = 0;
    constexpr int OB = 4096;
    __shared__ __align__(16) short smem[17408];   // epilogue overlay needs 17408

    const int tid  = threadIdx.x;
    const int lane = tid & 63;
    const int wave = tid >> 6;
    const int c    = lane & 15;
    const int h4   = lane >> 4;
    const int wr   = wave >> 1;
    const int wc   = wave & 1;

    const int sq   = ((tid & 3) ^ ((tid >> 3) & 3)) * 8;  // swizzled src chunk
    const int lds0 = wave * 512;                          // shorts, per tile
    const int lds1 = 2048 + wave * 512;

    const short* gW = Whi + (size_t)(m0 + (tid >> 2)) * K + sq;
    const short* gX = Xb + (size_t)(n0 + (tid >> 2)) * K + sq;
    const size_t rowskip = (size_t)64 * K;

    const int sw = (h4 ^ ((c >> 1) & 3)) * 8;             // frag-read swizzle

    f32x4 acc[4][4];
#pragma unroll
    for (int mi = 0; mi < 4; ++mi)
#pragma unroll
        for (int ni = 0; ni < 4; ++ni) acc[mi][ni] = 0.0f;

    // ---- prologue: stage tile 0 into buffer 0 ----
    gload16(gW,           smem + OA + lds0);
    gload16(gW + rowskip, smem + OA + lds1);
    gload16(gX,           smem + OB + lds0);
    gload16(gX + rowskip, smem + OB + lds1);
    __syncthreads();

    const int NT = K >> 5;   // 12
    for (int t = 0; t < NT; ++t) {
        short* cbuf = smem + (t & 1) * BUFS;

        // prefetch next tile into the other buffer FIRST
        if (t + 1 < NT) {
            short* nbuf = smem + ((t + 1) & 1) * BUFS;
            const int nk = (t + 1) * 32;
            gload16(gW + nk,           nbuf + OA + lds0);
            gload16(gW + rowskip + nk, nbuf + OA + lds1);
            gload16(gX + nk,           nbuf + OB + lds0);
            gload16(gX + rowskip + nk, nbuf + OB + lds1);
        }

        bf16x8 a[4], bb[4];
#pragma unroll
        for (int mi = 0; mi < 4; ++mi) {
            int row = wr * 64 + mi * 16 + c;
            a[mi] = *reinterpret_cast<const bf16x8*>(&cbuf[OA + row * 32 + sw]);
        }
#pragma unroll
        for (int ni = 0; ni < 4; ++ni) {
            int row = wc * 64 + ni * 16 + c;
            bb[ni] = *reinterpret_cast<const bf16x8*>(&cbuf[OB + row * 32 + sw]);
        }
        __builtin_amdgcn_s_setprio(1);
#pragma unroll
        for (int mi = 0; mi < 4; ++mi)
#pragma unroll
            for (int ni = 0; ni < 4; ++ni)
                acc[mi][ni] = __builtin_amdgcn_mfma_f32_16x16x32_bf16(a[mi], bb[ni], acc[mi][ni], 0, 0, 0);
        __builtin_amdgcn_s_setprio(0);

        __syncthreads();   // drains prefetch loads + protects buffer reuse
    }

    if (MODE == 0) {
        if (m0 < 768) {
            const float qscale = (m0 < 384) ? SCL2 : 1.0f;
            short* Cs = smem;  // [128 n][136]
#pragma unroll
            for (int mi = 0; mi < 4; ++mi)
#pragma unroll
                for (int ni = 0; ni < 4; ++ni) {
                    int nl = wc * 64 + ni * 16 + c;
                    int cl = wr * 64 + mi * 16 + 4 * h4;
                    bf16x4 pk;
#pragma unroll
                    for (int r = 0; r < 4; ++r) pk[r] = f2b(acc[mi][ni][r] * qscale);
                    *reinterpret_cast<bf16x4*>(&Cs[nl * 136 + cl]) = pk;
                }
            __syncthreads();
#pragma unroll
            for (int l = 0; l < 8; ++l) {
                int u  = tid + l * 256;
                int nl = u >> 4, ch = u & 15;
                *reinterpret_cast<bf16x8*>(&Yqk[((size_t)b * NN + n0 + nl) * 768 + m0 + ch * 8]) =
                    *reinterpret_cast<const bf16x8*>(&Cs[nl * 136 + ch * 8]);
            }
        } else {
            // V: channel-major bf16 out (d, n), columns sigma-permuted per
            // 64-n group so PV A-frag = single b128 LDS read in attention.
            short* Cs = smem;  // [128 ch][136]
#pragma unroll
            for (int mi = 0; mi < 4; ++mi)
#pragma unroll
                for (int ni = 0; ni < 4; ++ni) {
                    int npb = wc * 64 + 32 * (ni >> 1) + 8 * (c >> 2) + 4 * (ni & 1) + (c & 3);
#pragma unroll
                    for (int r = 0; r < 4; ++r) {
                        int ml = wr * 64 + mi * 16 + h4 * 4 + r;
                        Cs[ml * 136 + npb] = f2b(acc[mi][ni][r]);
                    }
                }
            __syncthreads();
            short* Yb = Yv + (size_t)b * Cc * NN;
            const int srow2 = tid >> 1;
            const int cseg  = (tid & 1) * 64;
#pragma unroll
            for (int i = 0; i < 8; ++i)
                *reinterpret_cast<bf16x8*>(&Yb[(size_t)(m0 - 768 + srow2) * NN + n0 + cseg + i * 8]) =
                    *reinterpret_cast<const bf16x8*>(&Cs[srow2 * 136 + cseg + i * 8]);
        }
    } else {
        float* Yb = Yf + (size_t)b * M * NN;
        float* Cf = reinterpret_cast<float*>(smem);
        const int mr2 = tid >> 2;
        const int seg = tid & 3;
#pragma unroll
        for (int half = 0; half < 2; ++half) {
            __syncthreads();
            if (wr == half) {
#pragma unroll
                for (int mi = 0; mi < 4; ++mi)
#pragma unroll
                    for (int ni = 0; ni < 4; ++ni)
#pragma unroll
                        for (int r = 0; r < 4; ++r) {
                            int ml = mi * 16 + h4 * 4 + r;
                            int nl = wc * 64 + ni * 16 + c;
                            Cf[ml * 132 + nl] = acc[mi][ni][r];
                        }
            }
            __syncthreads();
            float bv = bias ? bias[m0 + half * 64 + mr2] : 0.0f;
#pragma unroll
            for (int i = 0; i < 8; ++i) {
                float4 v = *reinterpret_cast<const float4*>(&Cf[mr2 * 132 + seg * 32 + i * 4]);
                v.x += bv; v.y += bv; v.z += bv; v.w += bv;
                *reinterpret_cast<float4*>(&Yb[(size_t)(m0 + half * 64 + mr2) * NN + n0 + seg * 32 + i * 4]) = v;
            }
        }
    }
}

// ---------------------------------------------------------------------------
// Hybrid MFMA flash attention: global_load_lds staging, 2-phase K/V dbuf,
// ones-row lsum, XCD-aware 1D remap, sigma-pre-permuted V (single b128 frags).
// Output: aot (B, N, C) bf16 only (no lo split).
// ---------------------------------------------------------------------------
__global__ __launch_bounds__(256, 4) void attn_mfma(const short* __restrict__ qk_t,
                                                    const short* __restrict__ v_cn,
                                                    short* __restrict__ aot)
{
    // XCD-aware decode: id%8 selects XCD under round-robin dispatch.
    const int id = blockIdx.x;           // 0..1023
    const int rx = id & 7;
    const int kk = id >> 3;              // 0..127
    const int bh = rx * 16 + (kk & 15);  // 0..127, constant per XCD group
    const int qt = kk >> 4;              // 0..7
    const int b  = bh >> 3;
    const int h  = bh & 7;
    const int n0 = qt * 128;

    __shared__ __align__(16) short smem[16384];  // 2 x (Ks 4096 + Vs 4096)

    const int tid  = threadIdx.x;
    const int lane = tid & 63;
    const int wave = tid >> 6;
    const int c    = lane & 15;
    const int h4   = lane >> 4;
    const int qb   = n0 + wave * 32;

    const short* Qb    = qk_t + ((size_t)b * Nn + qb) * 768 + h * HD;
    const short* Kbase = qk_t + (size_t)b * Nn * 768 + 384 + h * HD;
    const short* Vb    = v_cn + ((size_t)b * Cc + h * HD) * Nn;

    const bf16x8 z8 = {};

    // init Vs rows 48..63 in BOTH buffers: row 48 = 1.0, rows 49..63 = 0
    {
        int i0 = tid * 4;                       // 0..1023
        short v = (i0 < 64) ? (short)0x3F80 : (short)0;
        bf16x4 iv = {v, v, v, v};
        *reinterpret_cast<bf16x4*>(&smem[4096 + 3072 + i0]) = iv;
        *reinterpret_cast<bf16x4*>(&smem[12288 + 3072 + i0]) = iv;
    }

    // ---- Q fragments (loop-invariant, 2 sets) ----
    bf16x8 qf0[2], qf1[2];
#pragma unroll
    for (int s = 0; s < 2; ++s) {
        const short* qrow = Qb + (size_t)(s * 16 + c) * 768;
        qf0[s] = *reinterpret_cast<const bf16x8*>(qrow + 8 * h4);
        qf1[s] = (h4 < 2) ? *reinterpret_cast<const bf16x8*>(qrow + 32 + 8 * h4) : z8;
    }

    const int u0 = wave * 64 + lane;
    const int r0 = u0 >> 3;
    const int sc0 = ((u0 & 7) ^ (r0 & 7)) * 8;
    const int u1 = 256 + u0;
    const int r1 = u1 >> 3;
    const int sc1 = ((u1 & 7) ^ (r1 & 7)) * 8;

    const int cs8 = c & 7;
    const int ks0 = (h4 ^ cs8) * 8;            // K/V k-chunk h4
    const int ks1 = ((4 + h4) ^ cs8) * 8;      // K/V k-chunk 4+h4

    f32x4 o[2][3];
#pragma unroll
    for (int s = 0; s < 2; ++s)
#pragma unroll
        for (int jd = 0; jd < 3; ++jd) o[s][jd] = 0.0f;
    f32x4 o3[2];
    o3[0] = 0.0f; o3[1] = 0.0f;

    // ---- prologue: stage tile 0 into buffer 0 ----
    {
        short* Ksb = smem;
        short* Vsb = smem + 4096;
        gload16(Kbase + (size_t)r0 * 768 + sc0, Ksb + wave * 512);
        gload16(Kbase + (size_t)r1 * 768 + sc1, Ksb + 2048 + wave * 512);
        gload16(Vb + (size_t)r0 * Nn + sc0, Vsb + wave * 512);
        if (wave < 2)
            gload16(Vb + (size_t)r1 * Nn + sc1, Vsb + 2048 + wave * 512);
    }
    __syncthreads();

    for (int t = 0; t < 16; ++t) {
        const short* Ks = smem + (t & 1) * 8192;
        const short* Vs = Ks + 4096;

        // prefetch next tile into the other buffer FIRST
        if (t + 1 < 16) {
            short* Ksn = smem + ((t + 1) & 1) * 8192;
            short* Vsn = Ksn + 4096;
            const int mn = (t + 1) * 64;
            gload16(Kbase + (size_t)(mn + r0) * 768 + sc0, Ksn + wave * 512);
            gload16(Kbase + (size_t)(mn + r1) * 768 + sc1, Ksn + 2048 + wave * 512);
            gload16(Vb + (size_t)r0 * Nn + mn + sc0, Vsn + wave * 512);
            if (wave < 2)
                gload16(Vb + (size_t)r1 * Nn + mn + sc1, Vsn + 2048 + wave * 512);
        }

        // ---- QK^T (K frags shared by both sets) ----
        f32x4 s4a[4], s4b[4];
#pragma unroll
        for (int j = 0; j < 4; ++j) { s4a[j] = 0.0f; s4b[j] = 0.0f; }
        __builtin_amdgcn_s_setprio(1);
#pragma unroll
        for (int j = 0; j < 4; ++j) {
            int kr = (16 * j + c) * 64;
            bf16x8 kc0 = *reinterpret_cast<const bf16x8*>(&Ks[kr + ks0]);
            bf16x8 kc1 = *reinterpret_cast<const bf16x8*>(&Ks[kr + ks1]);
            s4a[j] = __builtin_amdgcn_mfma_f32_16x16x32_bf16(kc0, qf0[0], s4a[j], 0, 0, 0);
            s4a[j] = __builtin_amdgcn_mfma_f32_16x16x32_bf16(kc1, qf1[0], s4a[j], 0, 0, 0);
            s4b[j] = __builtin_amdgcn_mfma_f32_16x16x32_bf16(kc0, qf0[1], s4b[j], 0, 0, 0);
            s4b[j] = __builtin_amdgcn_mfma_f32_16x16x32_bf16(kc1, qf1[1], s4b[j], 0, 0, 0);
        }
        __builtin_amdgcn_s_setprio(0);

        // ---- softmax-lite + pack P (sigma order), both sets ----
        bf16x8 pa[2][2];
        {
            float p[4][4];
#pragma unroll
            for (int j = 0; j < 4; ++j)
#pragma unroll
                for (int r = 0; r < 4; ++r)
                    p[j][r] = exp2f(s4a[j][r]);
#pragma unroll
            for (int r = 0; r < 4; ++r) {
                pa[0][0][r]     = f2b(p[0][r]);
                pa[0][0][4 + r] = f2b(p[1][r]);
                pa[0][1][r]     = f2b(p[2][r]);
                pa[0][1][4 + r] = f2b(p[3][r]);
            }
        }
        {
            float p[4][4];
#pragma unroll
            for (int j = 0; j < 4; ++j)
#pragma unroll
                for (int r = 0; r < 4; ++r)
                    p[j][r] = exp2f(s4b[j][r]);
#pragma unroll
            for (int r = 0; r < 4; ++r) {
                pa[1][0][r]     = f2b(p[0][r]);
                pa[1][0][4 + r] = f2b(p[1][r]);
                pa[1][1][r]     = f2b(p[2][r]);
                pa[1][1][4 + r] = f2b(p[3][r]);
            }
        }

        // ---- PV (jd 0..2) + ones-row lsum (jd 3): single b128 V frags ----
        __builtin_amdgcn_s_setprio(1);
#pragma unroll
        for (int jd = 0; jd < 4; ++jd) {
            int vr = (16 * jd + c) * 64;
            bf16x8 vf0 = *reinterpret_cast<const bf16x8*>(&Vs[vr + ks0]);
            bf16x8 vf1 = *reinterpret_cast<const bf16x8*>(&Vs[vr + ks1]);
            if (jd < 3) {
                o[0][jd] = __builtin_amdgcn_mfma_f32_16x16x32_bf16(vf0, pa[0][0], o[0][jd], 0, 0, 0);
                o[0][jd] = __builtin_amdgcn_mfma_f32_16x16x32_bf16(vf1, pa[0][1], o[0][jd], 0, 0, 0);
                o[1][jd] = __builtin_amdgcn_mfma_f32_16x16x32_bf16(vf0, pa[1][0], o[1][jd], 0, 0, 0);
                o[1][jd] = __builtin_amdgcn_mfma_f32_16x16x32_bf16(vf1, pa[1][1], o[1][jd], 0, 0, 0);
            } else {
                o3[0] = __builtin_amdgcn_mfma_f32_16x16x32_bf16(vf0, pa[0][0], o3[0], 0, 0, 0);
                o3[0] = __builtin_amdgcn_mfma_f32_16x16x32_bf16(vf1, pa[0][1], o3[0], 0, 0, 0);
                o3[1] = __builtin_amdgcn_mfma_f32_16x16x32_bf16(vf0, pa[1][0], o3[1], 0, 0, 0);
                o3[1] = __builtin_amdgcn_mfma_f32_16x16x32_bf16(vf1, pa[1][1], o3[1], 0, 0, 0);
            }
        }
        __builtin_amdgcn_s_setprio(0);

        __syncthreads();   // drains prefetch + protects buffer reuse
    }

    // ---- epilogue: lsum broadcast from h4==0 lanes, normalize, bf16 out ----
#pragma unroll
    for (int set = 0; set < 2; ++set) {
        float ls = __shfl(o3[set][0], c);    // lane (c, h4=0) holds Sigma P for q=c
        float linv = 1.0f / ls;
        size_t rowoff = ((size_t)b * Nn + qb + set * 16 + c) * Cc + h * HD;
#pragma unroll
        for (int jd = 0; jd < 3; ++jd) {
            bf16x4 hv;
#pragma unroll
            for (int r = 0; r < 4; ++r)
                hv[r] = f2b(o[set][jd][r] * linv);
            *reinterpret_cast<bf16x4*>(&aot[rowoff + 16 * jd + 4 * h4]) = hv;
        }
    }
}

// ---------------------------------------------------------------------------
extern "C" void kernel_launch(void* const* d_in, const int* in_sizes, int n_in,
                              void* d_out, int out_size, void* d_ws, size_t ws_size,
                              hipStream_t stream)
{
    const float* x      = (const float*)d_in[0];
    const float* w_qkv  = (const float*)d_in[1];
    const float* w_proj = (const float*)d_in[2];
    const float* b_proj = (const float*)d_in[3];
    float* out = (float*)d_out;

    short* ws = (short*)d_ws;
    const size_t XT = (size_t)Bn * Nn * Cc;            // 6291456
    short* xt    = ws;
    short* wq_hi = xt + XT;
    short* wp_hi = wq_hi + (size_t)3 * Cc * Cc;
    short* qk_t  = wp_hi + (size_t)Cc * Cc;            // (B, N, 768)
    short* v_cn  = qk_t + (size_t)Bn * Nn * 768;       // (B, 384, N) sigma-perm
    short* aot   = v_cn + XT;                          // (B, N, C) bf16

    // 0) weight cast (fused) + x transpose/cast
    {
        int n1 = 3 * Cc * Cc, n2 = Cc * Cc;
        int units = (n1 + n2) / 4;
        conv_cast2<<<(units + 255) / 256, 256, 0, stream>>>(
            w_qkv, wq_hi, n1, w_proj, wp_hi, n2);
    }
    prep_xt<<<dim3(Nn / 64, Cc / 64, Bn), 256, 0, stream>>>(x, xt);

    // 1) QKV GEMM (single-pass bf16, 2-phase dbuf) -> qk_t + sigma-permuted v_cn
    gemm_bf16<0><<<dim3(Nn / 128, (3 * Cc) / 128, Bn), 256, 0, stream>>>(
        wq_hi, xt, qk_t, v_cn, nullptr, nullptr, 3 * Cc, Cc, Nn);

    // 2) Hybrid attention (XCD remap, dbuf, ones-row lsum, b128 V frags)
    attn_mfma<<<1024, 256, 0, stream>>>(qk_t, v_cn, aot);

    // 3) Projection GEMM (single-pass bf16, 2-phase dbuf, fp32 out + bias)
    gemm_bf16<1><<<dim3(Nn / 128, Cc / 128, Bn), 256, 0, stream>>>(
        wp_hi, aot, nullptr, nullptr, out, b_proj, Cc, Cc, Nn);
}

// Round 22
// 111.482 us; speedup vs baseline: 1.5041x; 1.0121x over previous
//
#include <hip/hip_runtime.h>
#include <hip/hip_bf16.h>
#include <math.h>

// Problem constants
constexpr int Bn     = 16;    // batch
constexpr int Cc     = 384;   // channels
constexpr int Nn     = 1024;  // tokens (32*32)
constexpr int NHEADS = 8;
constexpr int HD     = 48;    // head dim
constexpr float SCALE = 0.14433756729740643f; // 48^-0.5
constexpr float SCL2  = 0.14433756729740643f * 1.4426950408889634f; // SCALE*log2(e)

using bf16x8 = __attribute__((ext_vector_type(8))) short;
using bf16x4 = __attribute__((ext_vector_type(4))) short;
using f32x4  = __attribute__((ext_vector_type(4))) float;

__device__ inline short f2b(float f) {
    __hip_bfloat16 h = __float2bfloat16(f);
    return *reinterpret_cast<short*>(&h);
}

// async global->LDS, 16B per lane; LDS dest = wave-uniform base + lane*16B
__device__ __forceinline__ void gload16(const short* g, short* l) {
    __builtin_amdgcn_global_load_lds(
        (const __attribute__((address_space(1))) void*)(g),
        (__attribute__((address_space(3))) void*)(l),
        16, 0, 0);
}

// ---------------------------------------------------------------------------
// Fused fp32 -> bf16 cast for BOTH weight tensors.
// ---------------------------------------------------------------------------
__global__ __launch_bounds__(256) void conv_cast2(const float* __restrict__ in1,
                                                  short* __restrict__ hi1, int n1,
                                                  const float* __restrict__ in2,
                                                  short* __restrict__ hi2, int n2)
{
    int u = blockIdx.x * 256 + threadIdx.x;
    const float* in; short* hi; int i;
    if (u * 4 < n1) { in = in1; hi = hi1; i = u * 4; }
    else {
        i = u * 4 - n1;
        if (i >= n2) return;
        in = in2; hi = hi2;
    }
    float4 v = *reinterpret_cast<const float4*>(&in[i]);
    bf16x4 h = { f2b(v.x), f2b(v.y), f2b(v.z), f2b(v.w) };
    *reinterpret_cast<bf16x4*>(&hi[i]) = h;
}

// ---------------------------------------------------------------------------
// x (B, C, N) fp32 -> x^T (B, N, C) bf16.  64x64 tile via LDS.
// ---------------------------------------------------------------------------
__global__ __launch_bounds__(256) void prep_xt(const float* __restrict__ x,
                                               short* __restrict__ xt)
{
    const int b  = blockIdx.z;
    const int c0 = blockIdx.y * 64;
    const int n0 = blockIdx.x * 64;
    __shared__ float T[64 * 68];

    const int tid = threadIdx.x;
    const int r   = tid >> 2;
    const int seg = tid & 3;

    const float* xb = x + ((size_t)b * Cc + c0) * Nn;
#pragma unroll
    for (int i = 0; i < 4; ++i) {
        float4 v = *reinterpret_cast<const float4*>(&xb[(size_t)r * Nn + n0 + seg * 16 + i * 4]);
        *reinterpret_cast<float4*>(&T[r * 68 + seg * 16 + i * 4]) = v;
    }
    __syncthreads();

    short* oh = xt + ((size_t)b * Nn + n0 + r) * Cc + c0;
#pragma unroll
    for (int i = 0; i < 4; ++i) {
        bf16x4 hv;
#pragma unroll
        for (int j = 0; j < 4; ++j)
            hv[j] = f2b(T[(seg * 16 + i * 4 + j) * 68 + r]);
        *reinterpret_cast<bf16x4*>(&oh[seg * 16 + i * 4]) = hv;
    }
}

// ---------------------------------------------------------------------------
// Single-pass bf16 MFMA GEMM, 2-phase LDS dbuf, global_load_lds staging.
// MODE 0 (QKV): m<768 -> Yqk token-major (B,N,768) bf16 (Q pre-scaled SCL2);
//   m>=768 -> Yv (B,384,N) bf16, columns sigma-permuted per 64-n group.
// MODE 1 (PROJ): fp32 out + bias.   (unchanged from R21)
// ---------------------------------------------------------------------------
template <int MODE>
__global__ __launch_bounds__(256) void gemm_bf16(const short* __restrict__ Whi,
                                                 const short* __restrict__ Xh,
                                                 short* __restrict__ Yqk,
                                                 short* __restrict__ Yv,
                                                 float* __restrict__ Yf,
                                                 const float* __restrict__ bias,
                                                 int M, int K, int NN)
{
    const int b  = blockIdx.z;
    const int m0 = blockIdx.y * 128;
    const int n0 = blockIdx.x * 128;
    const short* Xb = Xh + (size_t)b * NN * K;

    constexpr int BUFS = 8192;    // shorts per buffer (2 tiles)
    constexpr int OA = 0;
    constexpr int OB = 4096;
    __shared__ __align__(16) short smem[17408];

    const int tid  = threadIdx.x;
    const int lane = tid & 63;
    const int wave = tid >> 6;
    const int c    = lane & 15;
    const int h4   = lane >> 4;
    const int wr   = wave >> 1;
    const int wc   = wave & 1;

    const int sq   = ((tid & 3) ^ ((tid >> 3) & 3)) * 8;
    const int lds0 = wave * 512;
    const int lds1 = 2048 + wave * 512;

    const short* gW = Whi + (size_t)(m0 + (tid >> 2)) * K + sq;
    const short* gX = Xb + (size_t)(n0 + (tid >> 2)) * K + sq;
    const size_t rowskip = (size_t)64 * K;

    const int sw = (h4 ^ ((c >> 1) & 3)) * 8;

    f32x4 acc[4][4];
#pragma unroll
    for (int mi = 0; mi < 4; ++mi)
#pragma unroll
        for (int ni = 0; ni < 4; ++ni) acc[mi][ni] = 0.0f;

    gload16(gW,           smem + OA + lds0);
    gload16(gW + rowskip, smem + OA + lds1);
    gload16(gX,           smem + OB + lds0);
    gload16(gX + rowskip, smem + OB + lds1);
    __syncthreads();

    const int NT = K >> 5;   // 12
    for (int t = 0; t < NT; ++t) {
        short* cbuf = smem + (t & 1) * BUFS;

        if (t + 1 < NT) {
            short* nbuf = smem + ((t + 1) & 1) * BUFS;
            const int nk = (t + 1) * 32;
            gload16(gW + nk,           nbuf + OA + lds0);
            gload16(gW + rowskip + nk, nbuf + OA + lds1);
            gload16(gX + nk,           nbuf + OB + lds0);
            gload16(gX + rowskip + nk, nbuf + OB + lds1);
        }

        bf16x8 a[4], bb[4];
#pragma unroll
        for (int mi = 0; mi < 4; ++mi) {
            int row = wr * 64 + mi * 16 + c;
            a[mi] = *reinterpret_cast<const bf16x8*>(&cbuf[OA + row * 32 + sw]);
        }
#pragma unroll
        for (int ni = 0; ni < 4; ++ni) {
            int row = wc * 64 + ni * 16 + c;
            bb[ni] = *reinterpret_cast<const bf16x8*>(&cbuf[OB + row * 32 + sw]);
        }
        __builtin_amdgcn_s_setprio(1);
#pragma unroll
        for (int mi = 0; mi < 4; ++mi)
#pragma unroll
            for (int ni = 0; ni < 4; ++ni)
                acc[mi][ni] = __builtin_amdgcn_mfma_f32_16x16x32_bf16(a[mi], bb[ni], acc[mi][ni], 0, 0, 0);
        __builtin_amdgcn_s_setprio(0);

        __syncthreads();
    }

    if (MODE == 0) {
        if (m0 < 768) {
            const float qscale = (m0 < 384) ? SCL2 : 1.0f;
            short* Cs = smem;  // [128 n][136]
#pragma unroll
            for (int mi = 0; mi < 4; ++mi)
#pragma unroll
                for (int ni = 0; ni < 4; ++ni) {
                    int nl = wc * 64 + ni * 16 + c;
                    int cl = wr * 64 + mi * 16 + 4 * h4;
                    bf16x4 pk;
#pragma unroll
                    for (int r = 0; r < 4; ++r) pk[r] = f2b(acc[mi][ni][r] * qscale);
                    *reinterpret_cast<bf16x4*>(&Cs[nl * 136 + cl]) = pk;
                }
            __syncthreads();
#pragma unroll
            for (int l = 0; l < 8; ++l) {
                int u  = tid + l * 256;
                int nl = u >> 4, ch = u & 15;
                *reinterpret_cast<bf16x8*>(&Yqk[((size_t)b * NN + n0 + nl) * 768 + m0 + ch * 8]) =
                    *reinterpret_cast<const bf16x8*>(&Cs[nl * 136 + ch * 8]);
            }
        } else {
            short* Cs = smem;  // [128 ch][136]
#pragma unroll
            for (int mi = 0; mi < 4; ++mi)
#pragma unroll
                for (int ni = 0; ni < 4; ++ni) {
                    int npb = wc * 64 + 32 * (ni >> 1) + 8 * (c >> 2) + 4 * (ni & 1) + (c & 3);
#pragma unroll
                    for (int r = 0; r < 4; ++r) {
                        int ml = wr * 64 + mi * 16 + h4 * 4 + r;
                        Cs[ml * 136 + npb] = f2b(acc[mi][ni][r]);
                    }
                }
            __syncthreads();
            short* Yb = Yv + (size_t)b * Cc * NN;
            const int srow2 = tid >> 1;
            const int cseg  = (tid & 1) * 64;
#pragma unroll
            for (int i = 0; i < 8; ++i)
                *reinterpret_cast<bf16x8*>(&Yb[(size_t)(m0 - 768 + srow2) * NN + n0 + cseg + i * 8]) =
                    *reinterpret_cast<const bf16x8*>(&Cs[srow2 * 136 + cseg + i * 8]);
        }
    } else {
        float* Yb = Yf + (size_t)b * M * NN;
        float* Cf = reinterpret_cast<float*>(smem);
        const int mr2 = tid >> 2;
        const int seg = tid & 3;
#pragma unroll
        for (int half = 0; half < 2; ++half) {
            __syncthreads();
            if (wr == half) {
#pragma unroll
                for (int mi = 0; mi < 4; ++mi)
#pragma unroll
                    for (int ni = 0; ni < 4; ++ni)
#pragma unroll
                        for (int r = 0; r < 4; ++r) {
                            int ml = mi * 16 + h4 * 4 + r;
                            int nl = wc * 64 + ni * 16 + c;
                            Cf[ml * 132 + nl] = acc[mi][ni][r];
                        }
            }
            __syncthreads();
            float bv = bias ? bias[m0 + half * 64 + mr2] : 0.0f;
#pragma unroll
            for (int i = 0; i < 8; ++i) {
                float4 v = *reinterpret_cast<const float4*>(&Cf[mr2 * 132 + seg * 32 + i * 4]);
                v.x += bv; v.y += bv; v.z += bv; v.w += bv;
                *reinterpret_cast<float4*>(&Yb[(size_t)(m0 + half * 64 + mr2) * NN + n0 + seg * 32 + i * 4]) = v;
            }
        }
    }
}

// ---------------------------------------------------------------------------
// Hybrid MFMA flash attention, 4 q-sets/wave (256-q blocks, grid 512):
// per-tile LDS frag reads (16 b128) now serve 4 sets -> per-q LDS cost
// halves; K/V staging per (b,h) halves; barriers per q halve.
// global_load_lds staging, 2-phase K/V dbuf, ones-row lsum, XCD remap,
// sigma-pre-permuted V.  Numerics per q identical to the 2-set version.
// ---------------------------------------------------------------------------
__global__ __launch_bounds__(256, 2) void attn_mfma(const short* __restrict__ qk_t,
                                                    const short* __restrict__ v_cn,
                                                    short* __restrict__ aot)
{
    // XCD-aware decode: id%8 selects XCD; each XCD gets 16 bh x 4 q-tiles.
    const int id = blockIdx.x;           // 0..511
    const int rx = id & 7;
    const int kk = id >> 3;              // 0..63
    const int bh = rx * 16 + (kk & 15);  // 0..127
    const int qt = kk >> 4;              // 0..3
    const int b  = bh >> 3;
    const int h  = bh & 7;
    const int n0 = qt * 256;

    __shared__ __align__(16) short smem[16384];  // 2 x (Ks 4096 + Vs 4096)

    const int tid  = threadIdx.x;
    const int lane = tid & 63;
    const int wave = tid >> 6;
    const int c    = lane & 15;
    const int h4   = lane >> 4;
    const int qb   = n0 + wave * 64;     // wave owns 64 q (4 sets of 16)

    const short* Qb    = qk_t + ((size_t)b * Nn + qb) * 768 + h * HD;
    const short* Kbase = qk_t + (size_t)b * Nn * 768 + 384 + h * HD;
    const short* Vb    = v_cn + ((size_t)b * Cc + h * HD) * Nn;

    const bf16x8 z8 = {};

    // init Vs rows 48..63 in BOTH buffers: row 48 = 1.0, rows 49..63 = 0
    {
        int i0 = tid * 4;
        short v = (i0 < 64) ? (short)0x3F80 : (short)0;
        bf16x4 iv = {v, v, v, v};
        *reinterpret_cast<bf16x4*>(&smem[4096 + 3072 + i0]) = iv;
        *reinterpret_cast<bf16x4*>(&smem[12288 + 3072 + i0]) = iv;
    }

    // ---- Q fragments (loop-invariant, 4 sets) ----
    bf16x8 qf0[4], qf1[4];
#pragma unroll
    for (int s = 0; s < 4; ++s) {
        const short* qrow = Qb + (size_t)(s * 16 + c) * 768;
        qf0[s] = *reinterpret_cast<const bf16x8*>(qrow + 8 * h4);
        qf1[s] = (h4 < 2) ? *reinterpret_cast<const bf16x8*>(qrow + 32 + 8 * h4) : z8;
    }

    const int u0 = wave * 64 + lane;
    const int r0 = u0 >> 3;
    const int sc0 = ((u0 & 7) ^ (r0 & 7)) * 8;
    const int u1 = 256 + u0;
    const int r1 = u1 >> 3;
    const int sc1 = ((u1 & 7) ^ (r1 & 7)) * 8;

    const int cs8 = c & 7;
    const int ks0 = (h4 ^ cs8) * 8;
    const int ks1 = ((4 + h4) ^ cs8) * 8;

    f32x4 o[4][3];
#pragma unroll
    for (int s = 0; s < 4; ++s)
#pragma unroll
        for (int jd = 0; jd < 3; ++jd) o[s][jd] = 0.0f;
    f32x4 o3[4];
#pragma unroll
    for (int s = 0; s < 4; ++s) o3[s] = 0.0f;

    // ---- prologue: stage tile 0 into buffer 0 ----
    {
        short* Ksb = smem;
        short* Vsb = smem + 4096;
        gload16(Kbase + (size_t)r0 * 768 + sc0, Ksb + wave * 512);
        gload16(Kbase + (size_t)r1 * 768 + sc1, Ksb + 2048 + wave * 512);
        gload16(Vb + (size_t)r0 * Nn + sc0, Vsb + wave * 512);
        if (wave < 2)
            gload16(Vb + (size_t)r1 * Nn + sc1, Vsb + 2048 + wave * 512);
    }
    __syncthreads();

    for (int t = 0; t < 16; ++t) {
        const short* Ks = smem + (t & 1) * 8192;
        const short* Vs = Ks + 4096;

        // prefetch next tile into the other buffer FIRST
        if (t + 1 < 16) {
            short* Ksn = smem + ((t + 1) & 1) * 8192;
            short* Vsn = Ksn + 4096;
            const int mn = (t + 1) * 64;
            gload16(Kbase + (size_t)(mn + r0) * 768 + sc0, Ksn + wave * 512);
            gload16(Kbase + (size_t)(mn + r1) * 768 + sc1, Ksn + 2048 + wave * 512);
            gload16(Vb + (size_t)r0 * Nn + mn + sc0, Vsn + wave * 512);
            if (wave < 2)
                gload16(Vb + (size_t)r1 * Nn + mn + sc1, Vsn + 2048 + wave * 512);
        }

        // ---- QK^T: each K frag pair feeds all 4 sets ----
        f32x4 s4[4][4];   // [set][j]
#pragma unroll
        for (int s = 0; s < 4; ++s)
#pragma unroll
            for (int j = 0; j < 4; ++j) s4[s][j] = 0.0f;
        __builtin_amdgcn_s_setprio(1);
#pragma unroll
        for (int j = 0; j < 4; ++j) {
            int kr = (16 * j + c) * 64;
            bf16x8 kc0 = *reinterpret_cast<const bf16x8*>(&Ks[kr + ks0]);
            bf16x8 kc1 = *reinterpret_cast<const bf16x8*>(&Ks[kr + ks1]);
#pragma unroll
            for (int s = 0; s < 4; ++s) {
                s4[s][j] = __builtin_amdgcn_mfma_f32_16x16x32_bf16(kc0, qf0[s], s4[s][j], 0, 0, 0);
                s4[s][j] = __builtin_amdgcn_mfma_f32_16x16x32_bf16(kc1, qf1[s], s4[s][j], 0, 0, 0);
            }
        }
        __builtin_amdgcn_s_setprio(0);

        // ---- softmax-lite + pack P (sigma order), 4 sets ----
        bf16x8 pa[4][2];
#pragma unroll
        for (int s = 0; s < 4; ++s) {
            float p[4][4];
#pragma unroll
            for (int j = 0; j < 4; ++j)
#pragma unroll
                for (int r = 0; r < 4; ++r)
                    p[j][r] = exp2f(s4[s][j][r]);
#pragma unroll
            for (int r = 0; r < 4; ++r) {
                pa[s][0][r]     = f2b(p[0][r]);
                pa[s][0][4 + r] = f2b(p[1][r]);
                pa[s][1][r]     = f2b(p[2][r]);
                pa[s][1][4 + r] = f2b(p[3][r]);
            }
        }

        // ---- PV (jd 0..2) + ones-row lsum (jd 3): V frags feed all sets ----
        __builtin_amdgcn_s_setprio(1);
#pragma unroll
        for (int jd = 0; jd < 4; ++jd) {
            int vr = (16 * jd + c) * 64;
            bf16x8 vf0 = *reinterpret_cast<const bf16x8*>(&Vs[vr + ks0]);
            bf16x8 vf1 = *reinterpret_cast<const bf16x8*>(&Vs[vr + ks1]);
            if (jd < 3) {
#pragma unroll
                for (int s = 0; s < 4; ++s) {
                    o[s][jd] = __builtin_amdgcn_mfma_f32_16x16x32_bf16(vf0, pa[s][0], o[s][jd], 0, 0, 0);
                    o[s][jd] = __builtin_amdgcn_mfma_f32_16x16x32_bf16(vf1, pa[s][1], o[s][jd], 0, 0, 0);
                }
            } else {
#pragma unroll
                for (int s = 0; s < 4; ++s) {
                    o3[s] = __builtin_amdgcn_mfma_f32_16x16x32_bf16(vf0, pa[s][0], o3[s], 0, 0, 0);
                    o3[s] = __builtin_amdgcn_mfma_f32_16x16x32_bf16(vf1, pa[s][1], o3[s], 0, 0, 0);
                }
            }
        }
        __builtin_amdgcn_s_setprio(0);

        __syncthreads();   // drains prefetch + protects buffer reuse
    }

    // ---- epilogue: lsum broadcast from h4==0 lanes, normalize, bf16 out ----
#pragma unroll
    for (int set = 0; set < 4; ++set) {
        float ls = __shfl(o3[set][0], c);
        float linv = 1.0f / ls;
        size_t rowoff = ((size_t)b * Nn + qb + set * 16 + c) * Cc + h * HD;
#pragma unroll
        for (int jd = 0; jd < 3; ++jd) {
            bf16x4 hv;
#pragma unroll
            for (int r = 0; r < 4; ++r)
                hv[r] = f2b(o[set][jd][r] * linv);
            *reinterpret_cast<bf16x4*>(&aot[rowoff + 16 * jd + 4 * h4]) = hv;
        }
    }
}

// ---------------------------------------------------------------------------
extern "C" void kernel_launch(void* const* d_in, const int* in_sizes, int n_in,
                              void* d_out, int out_size, void* d_ws, size_t ws_size,
                              hipStream_t stream)
{
    const float* x      = (const float*)d_in[0];
    const float* w_qkv  = (const float*)d_in[1];
    const float* w_proj = (const float*)d_in[2];
    const float* b_proj = (const float*)d_in[3];
    float* out = (float*)d_out;

    short* ws = (short*)d_ws;
    const size_t XT = (size_t)Bn * Nn * Cc;            // 6291456
    short* xt    = ws;
    short* wq_hi = xt + XT;
    short* wp_hi = wq_hi + (size_t)3 * Cc * Cc;
    short* qk_t  = wp_hi + (size_t)Cc * Cc;            // (B, N, 768)
    short* v_cn  = qk_t + (size_t)Bn * Nn * 768;       // (B, 384, N) sigma-perm
    short* aot   = v_cn + XT;                          // (B, N, C) bf16

    // 0) weight cast (fused) + x transpose/cast
    {
        int n1 = 3 * Cc * Cc, n2 = Cc * Cc;
        int units = (n1 + n2) / 4;
        conv_cast2<<<(units + 255) / 256, 256, 0, stream>>>(
            w_qkv, wq_hi, n1, w_proj, wp_hi, n2);
    }
    prep_xt<<<dim3(Nn / 64, Cc / 64, Bn), 256, 0, stream>>>(x, xt);

    // 1) QKV GEMM (single-pass bf16, 2-phase dbuf) -> qk_t + sigma-permuted v_cn
    gemm_bf16<0><<<dim3(Nn / 128, (3 * Cc) / 128, Bn), 256, 0, stream>>>(
        wq_hi, xt, qk_t, v_cn, nullptr, nullptr, 3 * Cc, Cc, Nn);

    // 2) Hybrid attention (4 sets/wave, 256q blocks, grid 512)
    attn_mfma<<<512, 256, 0, stream>>>(qk_t, v_cn, aot);

    // 3) Projection GEMM (single-pass bf16, 2-phase dbuf, fp32 out + bias)
    gemm_bf16<1><<<dim3(Nn / 128, Cc / 128, Bn), 256, 0, stream>>>(
        wp_hi, aot, nullptr, nullptr, out, b_proj, Cc, Cc, Nn);
}